// Round 2
// baseline (2797.445 us; speedup 1.0000x reference)
//
#include <hip/hip_runtime.h>
#include <math.h>

// ---------------------------------------------------------------------------
// DsDTW pipeline, fp32 (round 2: lane-skewed wavefront soft-DTW).
// B=32, C_IN=12, T=4095, D=128, L=1024, GAMMA=5.0
// ws layout unchanged from round 1 (~252 MB).
// ---------------------------------------------------------------------------

#define L_SEQ 1024
#define DM 128
#define INF_F __builtin_inff()

// ------------------------- conv + pool + relu + mask -----------------------
__global__ __launch_bounds__(128) void conv_k(
    const float* __restrict__ x, const float* __restrict__ w,
    const float* __restrict__ cb, const float* __restrict__ mask,
    float* __restrict__ h)
{
    int b = blockIdx.x;
    int l0 = blockIdx.y * 8;
    int d = threadIdx.x;
    __shared__ float xs[12][36];
    for (int v = d; v < 12 * 35; v += 128) {
        int c = v / 35, off = v % 35;
        int gi = 4 * l0 - 2 + off;
        xs[c][off] = (gi >= 0 && gi < 4095) ? x[((long)b * 12 + c) * 4095 + gi] : 0.f;
    }
    __syncthreads();
    float s[8];
#pragma unroll
    for (int l = 0; l < 8; ++l) s[l] = 0.f;
    for (int c = 0; c < 12; ++c) {
        const float* wp = w + (d * 12 + c) * 4;
        float w0 = wp[0], w1 = wp[1], w2 = wp[2], w3 = wp[3];
        float e0 = w0, e1 = w0 + w1, e2 = w0 + w1 + w2, e3 = w0 + w1 + w2 + w3;
        float e4 = w1 + w2 + w3, e5 = w2 + w3, e6 = w3;
#pragma unroll
        for (int l = 0; l < 8; ++l) {
            int ba = 4 * l;
            s[l] += xs[c][ba] * e0 + xs[c][ba + 1] * e1 + xs[c][ba + 2] * e2 +
                    xs[c][ba + 3] * e3 + xs[c][ba + 4] * e4 + xs[c][ba + 5] * e5 +
                    xs[c][ba + 6] * e6;
        }
    }
    float cbd = cb[d];
#pragma unroll
    for (int l = 0; l < 8; ++l) {
        int gl = l0 + l;
        float val = fmaxf(cbd + 0.25f * s[l], 0.f) * mask[b * L_SEQ + gl];
        h[((long)(b * L_SEQ + gl)) * DM + d] = val;
    }
}

// ------------------------------- row norms ---------------------------------
__global__ __launch_bounds__(128) void norm_k(const float* __restrict__ h,
                                              float* __restrict__ norms)
{
    long row = blockIdx.x;
    int d = threadIdx.x;
    float v = h[row * DM + d];
    __shared__ float red[128];
    red[d] = v * v;
    __syncthreads();
    for (int s = 64; s > 0; s >>= 1) {
        if (d < s) red[d] += red[d + s];
        __syncthreads();
    }
    if (d == 0) norms[row] = red[0];
}

// ------------------------------ tiled GEMM ---------------------------------
enum GMode { M_D2, M_QKV, M_SCORES, M_ATTNV, M_WOUT, M_FF1, M_FF2, M_LIN };

template <int MODE, bool BT>
__global__ __launch_bounds__(256) void gemm_k(
    const float* __restrict__ A, const float* __restrict__ B, float* __restrict__ C,
    int M, int N, int K, int lda, int ldb, int ldc,
    long sA, long sB, long sC,
    const float* __restrict__ e0, const float* __restrict__ e1)
{
    int z = blockIdx.z;
    A += (long)z * sA;
    B += (long)z * sB;
    C += (long)z * sC;
    __shared__ float As[16][65];
    __shared__ float Bs[16][65];
    int tid = threadIdx.x;
    int tx = tid & 15, ty = tid >> 4;
    int m0 = blockIdx.x * 64, n0 = blockIdx.y * 64;
    float acc[4][4] = {};
    int am = tid >> 2;
    int ak = (tid & 3) << 2;
    float rmaxv = 0.f;
    if (MODE == M_ATTNV) rmaxv = e0[(long)z * L_SEQ + m0 + am];

    for (int kk = 0; kk < K; kk += 16) {
        {
            const float4 av =
                *reinterpret_cast<const float4*>(A + (long)(m0 + am) * lda + kk + ak);
            float4 t = av;
            if (MODE == M_ATTNV) {
                t.x = __expf(t.x - rmaxv);
                t.y = __expf(t.y - rmaxv);
                t.z = __expf(t.z - rmaxv);
                t.w = __expf(t.w - rmaxv);
            }
            As[ak + 0][am] = t.x;
            As[ak + 1][am] = t.y;
            As[ak + 2][am] = t.z;
            As[ak + 3][am] = t.w;
        }
        if (BT) {
            int n = n0 + am;
            float4 bv = {0.f, 0.f, 0.f, 0.f};
            if (n < N)
                bv = *reinterpret_cast<const float4*>(B + (long)n * ldb + kk + ak);
            Bs[ak + 0][am] = bv.x;
            Bs[ak + 1][am] = bv.y;
            Bs[ak + 2][am] = bv.z;
            Bs[ak + 3][am] = bv.w;
        } else {
            int bk = tid >> 4;
            int bn = (tid & 15) << 2;
            float4 bv =
                *reinterpret_cast<const float4*>(B + (long)(kk + bk) * ldb + n0 + bn);
            Bs[bk][bn + 0] = bv.x;
            Bs[bk][bn + 1] = bv.y;
            Bs[bk][bn + 2] = bv.z;
            Bs[bk][bn + 3] = bv.w;
        }
        __syncthreads();
#pragma unroll
        for (int kc = 0; kc < 16; ++kc) {
            float a0 = As[kc][ty * 4 + 0], a1 = As[kc][ty * 4 + 1];
            float a2 = As[kc][ty * 4 + 2], a3 = As[kc][ty * 4 + 3];
            float b0 = Bs[kc][tx * 4 + 0], b1 = Bs[kc][tx * 4 + 1];
            float b2 = Bs[kc][tx * 4 + 2], b3 = Bs[kc][tx * 4 + 3];
            acc[0][0] += a0 * b0; acc[0][1] += a0 * b1; acc[0][2] += a0 * b2; acc[0][3] += a0 * b3;
            acc[1][0] += a1 * b0; acc[1][1] += a1 * b1; acc[1][2] += a1 * b2; acc[1][3] += a1 * b3;
            acc[2][0] += a2 * b0; acc[2][1] += a2 * b1; acc[2][2] += a2 * b2; acc[2][3] += a2 * b3;
            acc[3][0] += a3 * b0; acc[3][1] += a3 * b1; acc[3][2] += a3 * b2; acc[3][3] += a3 * b3;
        }
        __syncthreads();
    }

#pragma unroll
    for (int i = 0; i < 4; ++i) {
        int gi = m0 + ty * 4 + i;
#pragma unroll
        for (int j = 0; j < 4; ++j) {
            int gj = n0 + tx * 4 + j;
            float v = acc[i][j];
            long idx = (long)gi * ldc + gj;
            if (MODE == M_D2) {
                C[idx] = e0[gi] + e0[(long)z * L_SEQ + gj] - 2.f * v;
            } else if (MODE == M_QKV) {
                C[idx] = v + e0[gj];
            } else if (MODE == M_SCORES) {
                float mn = e0[2 * z], mx = e0[2 * z + 1];
                float rn = (C[idx] - mn) / (mx - mn) + 1.f;
                float kp = (e1[(long)z * L_SEQ + gj] > 0.f) ? 0.f : -INFINITY;
                C[idx] = v * 0.08838834764831845f + rn + kp;
            } else if (MODE == M_ATTNV) {
                C[idx] = v * e1[(long)z * L_SEQ + gi];
            } else if (MODE == M_WOUT) {
                C[idx] = v + e0[gj] + e1[idx];
            } else if (MODE == M_FF1) {
                C[idx] = fmaxf(v + e0[gj], 0.f);
            } else if (MODE == M_FF2) {
                C[idx] = v + e0[gj] + e1[idx];
            } else if (MODE == M_LIN) {
                if (gj < N) C[idx] = v * e0[gi];
            }
        }
    }
}

// ------------------------------- soft-DTW ----------------------------------
// Lane-skewed wavefront: block = 4 waves; wave w owns rows [256w, 256w+256);
// lane i owns rows 256w+4i..+3 with per-row skew 1: at global step t, the
// cell for row (off0+r) is column j = t - off0 - r. All deps are prev-step:
//   rl = own cur[r]; ru = cur[r-1]; rul = prev[r-1]; r==0 uses shfl_up / LDS
//   ring from the wave above (written >=1 barrier-epoch earlier).
// Chunk C=128 steps; wave w runs chunk c at epoch c+w; 19 epochs, 19 barriers.
// D values prefetched one 4-step group ahead (per-lane sequential columns).
__device__ __forceinline__ float dtw_cell(float d, float rl, float ru, float rul,
                                          int j, float& vmn, float& vmx)
{
    bool valid = ((unsigned)j < 1024u);
    float m = fminf(rul, fminf(ru, rl));
    float s = __expf((m - rul) * 0.2f) + __expf((m - ru) * 0.2f) +
              __expf((m - rl) * 0.2f);
    float v = d + m - 5.0f * __logf(s);
    v = valid ? v : INF_F;
    vmn = valid ? fminf(vmn, v) : vmn;
    vmx = valid ? fmaxf(vmx, v) : vmx;
    return v;
}

__global__ __launch_bounds__(256) void dtw_k(float* Mb, float* minmax)
{
    const int b = blockIdx.x;
    float* R = Mb + (long)b * L_SEQ * L_SEQ;
    const int tid = threadIdx.x;
    const int w = tid >> 6;
    const int lane = tid & 63;
    const bool lane0 = (lane == 0);
    const int off0 = (w << 8) + (lane << 2);   // first row of this lane

    __shared__ float bot[3][512];   // ring: bottom row of wave w -> wave w+1
    __shared__ float rmn[256];
    __shared__ float rmx[256];

    float* row0 = R + (long)(off0 + 0) * L_SEQ;
    float* row1 = R + (long)(off0 + 1) * L_SEQ;
    float* row2 = R + (long)(off0 + 2) * L_SEQ;
    float* row3 = R + (long)(off0 + 3) * L_SEQ;
    float* botw = (w < 3) ? bot[w] : bot[0];       // write target (guarded)
    const float* botp = (w > 0) ? bot[w - 1] : bot[0];  // read source (guarded)

    float cur0 = INF_F, cur1 = INF_F, cur2 = INF_F, cur3 = INF_F;
    float prev0 = INF_F, prev1 = INF_F, prev2 = INF_F, prev3 = INF_F;
    float vmin = INF_F, vmax = -INF_F;
    float dbuf[4][4];   // [step-in-group][r]
    float bb[5];        // bot cols jg-1 .. jg+3 for current group

    const int firstChunk = 2 * w, lastChunk = 2 * w + 9;

    for (int e = 0; e < 19; ++e) {
        const int c = e - w;
        if (c >= firstChunk && c <= lastChunk) {
            const int T0 = c << 7;
            if (c == firstChunk) {      // prime D queue for steps T0..T0+3
#pragma unroll
                for (int s = 0; s < 4; ++s) {
                    int jn = T0 + s - off0;
                    dbuf[s][0] = row0[min(max(jn, 0), 1023)];
                    dbuf[s][1] = row1[min(max(jn - 1, 0), 1023)];
                    dbuf[s][2] = row2[min(max(jn - 2, 0), 1023)];
                    dbuf[s][3] = row3[min(max(jn - 3, 0), 1023)];
                }
            }
            if (w > 0) {                // bot cols for first group of chunk
                const int jb = T0 - (w << 8) - 1;
#pragma unroll
                for (int q = 0; q < 5; ++q) bb[q] = botp[(jb + q) & 511];
            }
            for (int g = 0; g < 32; ++g) {
                const int tg = T0 + (g << 2);
                float dn[4][4];
                {                       // prefetch next group's D values
                    const int tn = tg + 4;
#pragma unroll
                    for (int s = 0; s < 4; ++s) {
                        int jn = tn + s - off0;
                        dn[s][0] = row0[min(max(jn, 0), 1023)];
                        dn[s][1] = row1[min(max(jn - 1, 0), 1023)];
                        dn[s][2] = row2[min(max(jn - 2, 0), 1023)];
                        dn[s][3] = row3[min(max(jn - 3, 0), 1023)];
                    }
                }
                float bn[5] = {0.f, 0.f, 0.f, 0.f, 0.f};
                if (w > 0 && g < 31) {  // prefetch next group's bot cols
                    const int jn = tg + 3 - (w << 8);
#pragma unroll
                    for (int q = 0; q < 5; ++q) bn[q] = botp[(jn + q) & 511];
                }
#pragma unroll
                for (int s = 0; s < 4; ++s) {
                    const int t = tg + s;
                    const int j0 = t - off0;
                    float upc = __shfl_up(cur3, 1);
                    float upp = __shfl_up(prev3, 1);
                    if (lane0) {
                        if (w == 0) {
                            upc = INF_F;
                            upp = (j0 == 0) ? 0.f : INF_F;
                        } else {
                            upc = bb[s + 1];
                            upp = (j0 >= 1) ? bb[s] : INF_F;
                        }
                    }
                    float n0 = dtw_cell(dbuf[s][0], cur0, upc, upp, j0, vmin, vmax);
                    float n1 = dtw_cell(dbuf[s][1], cur1, cur0, prev0, j0 - 1, vmin, vmax);
                    float n2 = dtw_cell(dbuf[s][2], cur2, cur1, prev1, j0 - 2, vmin, vmax);
                    float n3 = dtw_cell(dbuf[s][3], cur3, cur2, prev2, j0 - 3, vmin, vmax);
                    if ((unsigned)j0 < 1024u)       row0[j0] = n0;
                    if ((unsigned)(j0 - 1) < 1024u) row1[j0 - 1] = n1;
                    if ((unsigned)(j0 - 2) < 1024u) row2[j0 - 2] = n2;
                    if ((unsigned)(j0 - 3) < 1024u) row3[j0 - 3] = n3;
                    if (w < 3 && lane == 63 && (unsigned)(j0 - 3) < 1024u)
                        botw[(j0 - 3) & 511] = n3;
                    prev0 = cur0; prev1 = cur1; prev2 = cur2; prev3 = cur3;
                    cur0 = n0; cur1 = n1; cur2 = n2; cur3 = n3;
                }
#pragma unroll
                for (int s = 0; s < 4; ++s)
#pragma unroll
                    for (int r = 0; r < 4; ++r) dbuf[s][r] = dn[s][r];
#pragma unroll
                for (int q = 0; q < 5; ++q) bb[q] = bn[q];
            }
        }
        __syncthreads();
    }

    rmn[tid] = vmin;
    rmx[tid] = vmax;
    __syncthreads();
    for (int s = 128; s > 0; s >>= 1) {
        if (tid < s) {
            rmn[tid] = fminf(rmn[tid], rmn[tid + s]);
            rmx[tid] = fmaxf(rmx[tid], rmx[tid + s]);
        }
        __syncthreads();
    }
    if (tid == 0) {
        minmax[2 * b] = rmn[0];
        minmax[2 * b + 1] = rmx[0];
    }
}

// --------------------------- softmax row stats -----------------------------
__global__ __launch_bounds__(256) void smax_k(const float* __restrict__ S,
                                              float* __restrict__ rmax,
                                              float* __restrict__ rsuminv)
{
    long row = blockIdx.x;
    const float4 v = reinterpret_cast<const float4*>(S + row * L_SEQ)[threadIdx.x];
    int t = threadIdx.x;
    __shared__ float red[256];
    red[t] = fmaxf(fmaxf(v.x, v.y), fmaxf(v.z, v.w));
    __syncthreads();
    for (int s = 128; s > 0; s >>= 1) {
        if (t < s) red[t] = fmaxf(red[t], red[t + s]);
        __syncthreads();
    }
    float mx = red[0];
    __syncthreads();
    red[t] = __expf(v.x - mx) + __expf(v.y - mx) + __expf(v.z - mx) + __expf(v.w - mx);
    __syncthreads();
    for (int s = 128; s > 0; s >>= 1) {
        if (t < s) red[t] += red[t + s];
        __syncthreads();
    }
    if (t == 0) {
        rmax[row] = mx;
        rsuminv[row] = 1.f / red[0];
    }
}

// ------------------------------- layernorm ---------------------------------
__global__ __launch_bounds__(128) void ln_k(float* __restrict__ X,
                                            const float* __restrict__ g,
                                            const float* __restrict__ b)
{
    long row = blockIdx.x;
    int d = threadIdx.x;
    float x = X[row * DM + d];
    __shared__ float s1[128];
    __shared__ float s2[128];
    s1[d] = x;
    s2[d] = x * x;
    __syncthreads();
    for (int s = 64; s > 0; s >>= 1) {
        if (d < s) { s1[d] += s1[d + s]; s2[d] += s2[d + s]; }
        __syncthreads();
    }
    float mean = s1[0] * (1.f / 128.f);
    float var = s2[0] * (1.f / 128.f) - mean * mean;
    X[row * DM + d] = (x - mean) * rsqrtf(var + 1e-5f) * g[d] + b[d];
}

// -------------------------------- lengths ----------------------------------
__global__ __launch_bounds__(256) void len_k(const float* __restrict__ mask,
                                             float* __restrict__ out)
{
    int b = blockIdx.x;
    int t = threadIdx.x;
    const float4 v = reinterpret_cast<const float4*>(mask + b * L_SEQ)[t];
    __shared__ float red[256];
    red[t] = v.x + v.y + v.z + v.w;
    __syncthreads();
    for (int s = 128; s > 0; s >>= 1) {
        if (t < s) red[t] += red[t + s];
        __syncthreads();
    }
    if (t == 0) out[b] = red[0];
}

// ------------------------------- launcher ----------------------------------
extern "C" void kernel_launch(void* const* d_in, const int* in_sizes, int n_in,
                              void* d_out, int out_size, void* d_ws, size_t ws_size,
                              hipStream_t stream)
{
    const float* x      = (const float*)d_in[0];
    const float* mask   = (const float*)d_in[1];
    const float* conv_w = (const float*)d_in[2];
    const float* conv_b = (const float*)d_in[3];
    const float* w_in   = (const float*)d_in[4];
    const float* b_in   = (const float*)d_in[5];
    const float* w_out  = (const float*)d_in[6];
    const float* b_out  = (const float*)d_in[7];
    const float* w_ff1  = (const float*)d_in[8];
    const float* b_ff1  = (const float*)d_in[9];
    const float* w_ff2  = (const float*)d_in[10];
    const float* b_ff2  = (const float*)d_in[11];
    const float* ln1_g  = (const float*)d_in[12];
    const float* ln1_b  = (const float*)d_in[13];
    const float* ln2_g  = (const float*)d_in[14];
    const float* ln2_b  = (const float*)d_in[15];
    const float* w_lin  = (const float*)d_in[16];
    float* out = (float*)d_out;

    float* ws    = (float*)d_ws;
    float* h     = ws;
    float* qkv   = ws + 4194304L;
    float* t0    = ws + 16777216L;
    float* t1    = ws + 20971520L;
    float* t2    = ws + 25165824L;
    float* norms = ws + 29360128L;
    float* rmax  = ws + 29392896L;
    float* rsum  = ws + 29425664L;
    float* mnmx  = ws + 29458432L;
    float* Mb    = ws + 29458496L;

    conv_k<<<dim3(32, 128), 128, 0, stream>>>(x, conv_w, conv_b, mask, h);
    norm_k<<<32768, 128, 0, stream>>>(h, norms);
    gemm_k<M_D2, true><<<dim3(16, 16, 32), 256, 0, stream>>>(
        h, h, Mb, 1024, 1024, 128, 128, 128, 1024,
        0L, 131072L, 1048576L, norms, nullptr);
    dtw_k<<<32, 256, 0, stream>>>(Mb, mnmx);
    gemm_k<M_QKV, true><<<dim3(512, 6, 1), 256, 0, stream>>>(
        h, w_in, qkv, 32768, 384, 128, 128, 128, 384,
        0L, 0L, 0L, b_in, nullptr);
    gemm_k<M_SCORES, true><<<dim3(16, 16, 32), 256, 0, stream>>>(
        qkv, qkv + 128, Mb, 1024, 1024, 128, 384, 384, 1024,
        393216L, 393216L, 1048576L, mnmx, mask);
    smax_k<<<32768, 256, 0, stream>>>(Mb, rmax, rsum);
    gemm_k<M_ATTNV, false><<<dim3(16, 2, 32), 256, 0, stream>>>(
        Mb, qkv + 256, t0, 1024, 128, 1024, 1024, 384, 128,
        1048576L, 393216L, 131072L, rmax, rsum);
    gemm_k<M_WOUT, true><<<dim3(512, 2, 1), 256, 0, stream>>>(
        t0, w_out, t1, 32768, 128, 128, 128, 128, 128,
        0L, 0L, 0L, b_out, h);
    ln_k<<<32768, 128, 0, stream>>>(t1, ln1_g, ln1_b);
    gemm_k<M_FF1, true><<<dim3(512, 2, 1), 256, 0, stream>>>(
        t1, w_ff1, t2, 32768, 128, 128, 128, 128, 128,
        0L, 0L, 0L, b_ff1, nullptr);
    gemm_k<M_FF2, true><<<dim3(512, 2, 1), 256, 0, stream>>>(
        t2, w_ff2, t0, 32768, 128, 128, 128, 128, 128,
        0L, 0L, 0L, b_ff2, t1);
    ln_k<<<32768, 128, 0, stream>>>(t0, ln2_g, ln2_b);
    gemm_k<M_LIN, true><<<dim3(512, 1, 1), 256, 0, stream>>>(
        t0, w_lin, out, 32768, 16, 128, 128, 128, 16,
        0L, 0L, 0L, mask, nullptr);
    len_k<<<32, 256, 0, stream>>>(mask, out + 32768L * 16);
}

// Round 3
// 2054.754 us; speedup vs baseline: 1.3614x; 1.3614x over previous
//
#include <hip/hip_runtime.h>
#include <math.h>

// ---------------------------------------------------------------------------
// DsDTW pipeline (round 3): anti-diagonal (skewed) bf16 storage for D/R so the
// soft-DTW wavefront reads/writes are coalesced; bf16 scores.
// B=32, C_IN=12, T=4095, D=128, L=1024, GAMMA=5.0
//
// ws layout (float offsets):
//   h      @ 0          4,194,304   [32,1024,128]
//   qkv    @ 4194304   12,582,912   [32,1024,384]
//   t0     @ 16777216   4,194,304
//   t1     @ 20971520   4,194,304
//   t2     @ 25165824   4,194,304
//   norms  @ 29360128      32,768
//   rmax   @ 29392896      32,768
//   rsum   @ 29425664      32,768
//   mnmx   @ 29458432          64
//   Db/Rb  @ 29458496  (bf16, 33,554,432 elems) skewed D -> R in place
//   Sb     @ 46235712  (bf16, 33,554,432 elems) scores, standard layout
// total ~252 MB (unchanged)
// ---------------------------------------------------------------------------

#define L_SEQ 1024
#define DM 128
#define INF_F __builtin_inff()

__device__ __forceinline__ float b2f(unsigned short u) {
    return __uint_as_float(((unsigned)u) << 16);
}
__device__ __forceinline__ unsigned short f2b(float f) {  // RNE
    unsigned u = __float_as_uint(f);
    return (unsigned short)((u + 0x7FFFu + ((u >> 16) & 1u)) >> 16);
}
__device__ __forceinline__ unsigned short f2bt(float f) {  // truncate (cheap)
    return (unsigned short)(__float_as_uint(f) >> 16);
}

// ------------------------- conv + pool + relu + mask -----------------------
__global__ __launch_bounds__(128) void conv_k(
    const float* __restrict__ x, const float* __restrict__ w,
    const float* __restrict__ cb, const float* __restrict__ mask,
    float* __restrict__ h)
{
    int b = blockIdx.x;
    int l0 = blockIdx.y * 8;
    int d = threadIdx.x;
    __shared__ float xs[12][36];
    for (int v = d; v < 12 * 35; v += 128) {
        int c = v / 35, off = v % 35;
        int gi = 4 * l0 - 2 + off;
        xs[c][off] = (gi >= 0 && gi < 4095) ? x[((long)b * 12 + c) * 4095 + gi] : 0.f;
    }
    __syncthreads();
    float s[8];
#pragma unroll
    for (int l = 0; l < 8; ++l) s[l] = 0.f;
    for (int c = 0; c < 12; ++c) {
        const float* wp = w + (d * 12 + c) * 4;
        float w0 = wp[0], w1 = wp[1], w2 = wp[2], w3 = wp[3];
        float e0 = w0, e1 = w0 + w1, e2 = w0 + w1 + w2, e3 = w0 + w1 + w2 + w3;
        float e4 = w1 + w2 + w3, e5 = w2 + w3, e6 = w3;
#pragma unroll
        for (int l = 0; l < 8; ++l) {
            int ba = 4 * l;
            s[l] += xs[c][ba] * e0 + xs[c][ba + 1] * e1 + xs[c][ba + 2] * e2 +
                    xs[c][ba + 3] * e3 + xs[c][ba + 4] * e4 + xs[c][ba + 5] * e5 +
                    xs[c][ba + 6] * e6;
        }
    }
    float cbd = cb[d];
#pragma unroll
    for (int l = 0; l < 8; ++l) {
        int gl = l0 + l;
        float val = fmaxf(cbd + 0.25f * s[l], 0.f) * mask[b * L_SEQ + gl];
        h[((long)(b * L_SEQ + gl)) * DM + d] = val;
    }
}

// ------------------------------- row norms ---------------------------------
__global__ __launch_bounds__(128) void norm_k(const float* __restrict__ h,
                                              float* __restrict__ norms)
{
    long row = blockIdx.x;
    int d = threadIdx.x;
    float v = h[row * DM + d];
    __shared__ float red[128];
    red[d] = v * v;
    __syncthreads();
    for (int s = 64; s > 0; s >>= 1) {
        if (d < s) red[d] += red[d + s];
        __syncthreads();
    }
    if (d == 0) norms[row] = red[0];
}

// ------------------------------ tiled GEMM ---------------------------------
enum GMode { M_D2, M_QKV, M_SCORES, M_ATTNV, M_WOUT, M_FF1, M_FF2, M_LIN };

template <int MODE, bool BT>
__global__ __launch_bounds__(256) void gemm_k(
    const void* Av, const void* Bv, void* Cv,
    int M, int N, int K, int lda, int ldb, int ldc,
    long sA, long sB, long sC,
    const float* __restrict__ e0, const float* __restrict__ e1,
    const void* auxv)
{
    const int z = blockIdx.z;
    const float* A = (const float*)Av + (long)z * sA;
    const unsigned short* Au = (const unsigned short*)Av + (long)z * sA;
    const float* B = (const float*)Bv + (long)z * sB;
    float* C = (float*)Cv + (long)z * sC;
    unsigned short* Cu = (unsigned short*)Cv + (long)z * sC;
    const unsigned short* Rz = (const unsigned short*)auxv + (long)z * 1048576L;

    __shared__ float As[16][65];
    __shared__ float Bs[16][65];
    int tid = threadIdx.x;
    int tx = tid & 15, ty = tid >> 4;
    int m0 = blockIdx.x * 64, n0 = blockIdx.y * 64;
    float acc[4][4] = {};
    int am = tid >> 2;
    int ak = (tid & 3) << 2;
    float rmaxv = 0.f;
    if (MODE == M_ATTNV) rmaxv = e0[(long)z * L_SEQ + m0 + am];

    for (int kk = 0; kk < K; kk += 16) {
        {
            float4 t;
            if (MODE == M_ATTNV) {
                const ushort4 av = *reinterpret_cast<const ushort4*>(
                    Au + (long)(m0 + am) * lda + kk + ak);
                t.x = __expf(b2f(av.x) - rmaxv);
                t.y = __expf(b2f(av.y) - rmaxv);
                t.z = __expf(b2f(av.z) - rmaxv);
                t.w = __expf(b2f(av.w) - rmaxv);
            } else {
                t = *reinterpret_cast<const float4*>(A + (long)(m0 + am) * lda + kk + ak);
            }
            As[ak + 0][am] = t.x;
            As[ak + 1][am] = t.y;
            As[ak + 2][am] = t.z;
            As[ak + 3][am] = t.w;
        }
        if (BT) {
            int n = n0 + am;
            float4 bv = {0.f, 0.f, 0.f, 0.f};
            if (n < N)
                bv = *reinterpret_cast<const float4*>(B + (long)n * ldb + kk + ak);
            Bs[ak + 0][am] = bv.x;
            Bs[ak + 1][am] = bv.y;
            Bs[ak + 2][am] = bv.z;
            Bs[ak + 3][am] = bv.w;
        } else {
            int bk = tid >> 4;
            int bn = (tid & 15) << 2;
            float4 bv =
                *reinterpret_cast<const float4*>(B + (long)(kk + bk) * ldb + n0 + bn);
            Bs[bk][bn + 0] = bv.x;
            Bs[bk][bn + 1] = bv.y;
            Bs[bk][bn + 2] = bv.z;
            Bs[bk][bn + 3] = bv.w;
        }
        __syncthreads();
#pragma unroll
        for (int kc = 0; kc < 16; ++kc) {
            float a0 = As[kc][ty * 4 + 0], a1 = As[kc][ty * 4 + 1];
            float a2 = As[kc][ty * 4 + 2], a3 = As[kc][ty * 4 + 3];
            float b0 = Bs[kc][tx * 4 + 0], b1 = Bs[kc][tx * 4 + 1];
            float b2 = Bs[kc][tx * 4 + 2], b3 = Bs[kc][tx * 4 + 3];
            acc[0][0] += a0 * b0; acc[0][1] += a0 * b1; acc[0][2] += a0 * b2; acc[0][3] += a0 * b3;
            acc[1][0] += a1 * b0; acc[1][1] += a1 * b1; acc[1][2] += a1 * b2; acc[1][3] += a1 * b3;
            acc[2][0] += a2 * b0; acc[2][1] += a2 * b1; acc[2][2] += a2 * b2; acc[2][3] += a2 * b3;
            acc[3][0] += a3 * b0; acc[3][1] += a3 * b1; acc[3][2] += a3 * b2; acc[3][3] += a3 * b3;
        }
        __syncthreads();
    }

    if (MODE == M_D2) {
        // D[i][j] -> bf16 skewed slot [(i+j)&1023][i], via LDS + coalesced runs
        __shared__ float Cs[64][66];
#pragma unroll
        for (int i = 0; i < 4; ++i) {
            int gi = m0 + ty * 4 + i;
#pragma unroll
            for (int j = 0; j < 4; ++j) {
                int gj = n0 + tx * 4 + j;
                Cs[ty * 4 + i][tx * 4 + j] =
                    e0[gi] + e0[(long)z * L_SEQ + gj] - 2.f * acc[i][j];
            }
        }
        __syncthreads();
        int wv = tid >> 6, ln = tid & 63;
        for (int q = 0; q < 32; ++q) {
            int dd = wv * 32 + q;
            if (dd < 127) {
                int d = m0 + n0 + dd;
                int ilo = max(m0, d - n0 - 63);
                int ihi = min(m0 + 63, d - n0);
                int i = ilo + ln;
                if (i <= ihi)
                    Cu[(long)(((d & 1023) << 10) + i)] = f2b(Cs[i - m0][d - n0 - i]);
            }
        }
        return;
    }
    if (MODE == M_SCORES) {
        // stage R (bf16 skewed) into LDS via coalesced anti-diagonal runs
        __shared__ float Rs[64][66];
        int wv = tid >> 6, ln = tid & 63;
        for (int q = 0; q < 32; ++q) {
            int dd = wv * 32 + q;
            if (dd < 127) {
                int d = m0 + n0 + dd;
                int ilo = max(m0, d - n0 - 63);
                int ihi = min(m0 + 63, d - n0);
                int i = ilo + ln;
                if (i <= ihi)
                    Rs[i - m0][d - n0 - i] = b2f(Rz[(long)(((d & 1023) << 10) + i)]);
            }
        }
        __syncthreads();
        float mn = e0[2 * z];
        float inv = 1.f / (e0[2 * z + 1] - mn);
#pragma unroll
        for (int i = 0; i < 4; ++i) {
            int gi = m0 + ty * 4 + i;
            ushort4 sv;
            unsigned short* svp = &sv.x;
#pragma unroll
            for (int j = 0; j < 4; ++j) {
                int gj = n0 + tx * 4 + j;
                float rn = (Rs[ty * 4 + i][tx * 4 + j] - mn) * inv + 1.f;
                float kp = (e1[(long)z * L_SEQ + gj] > 0.f) ? 0.f : -INF_F;
                svp[j] = f2b(acc[i][j] * 0.08838834764831845f + rn + kp);
            }
            *reinterpret_cast<ushort4*>(Cu + (long)gi * ldc + n0 + tx * 4) = sv;
        }
        return;
    }

#pragma unroll
    for (int i = 0; i < 4; ++i) {
        int gi = m0 + ty * 4 + i;
#pragma unroll
        for (int j = 0; j < 4; ++j) {
            int gj = n0 + tx * 4 + j;
            float v = acc[i][j];
            long idx = (long)gi * ldc + gj;
            if (MODE == M_QKV) {
                C[idx] = v + e0[gj];
            } else if (MODE == M_ATTNV) {
                C[idx] = v * e1[(long)z * L_SEQ + gi];
            } else if (MODE == M_WOUT) {
                C[idx] = v + e0[gj] + e1[idx];
            } else if (MODE == M_FF1) {
                C[idx] = fmaxf(v + e0[gj], 0.f);
            } else if (MODE == M_FF2) {
                C[idx] = v + e0[gj] + e1[idx];
            } else if (MODE == M_LIN) {
                if (gj < N) C[idx] = v * e0[gi];
            }
        }
    }
}

// ------------------------------- soft-DTW ----------------------------------
// Same lane-skewed wavefront schedule as round 2 (verified correct); only the
// D/R addressing changed: cell (i,j) lives at bf16 slot [(i+j)&1023][i], so a
// wave's per-step load/store is 256 contiguous bf16 (coalesced, 8 lines).
// Recurrence chain (cur/prev/shfl/LDS ring) stays fp32.
__device__ __forceinline__ float dtw_cell(float d, float rl, float ru, float rul,
                                          int j, float& vmn, float& vmx)
{
    bool valid = ((unsigned)j < 1024u);
    float m = fminf(rul, fminf(ru, rl));
    float s = __expf((m - rul) * 0.2f) + __expf((m - ru) * 0.2f) +
              __expf((m - rl) * 0.2f);
    float v = d + m - 5.0f * __logf(s);
    v = valid ? v : INF_F;
    vmn = valid ? fminf(vmn, v) : vmn;
    vmx = valid ? fmaxf(vmx, v) : vmx;
    return v;
}

__global__ __launch_bounds__(256) void dtw_k(unsigned short* __restrict__ Rb,
                                             float* __restrict__ minmax)
{
    const int b = blockIdx.x;
    unsigned short* R = Rb + (long)b * (1024L * 1024L);
    const int tid = threadIdx.x;
    const int w = tid >> 6;
    const int lane = tid & 63;
    const bool lane0 = (lane == 0);
    const int off0 = (w << 8) + (lane << 2);

    __shared__ float bot[3][512];
    __shared__ float rmn[256];
    __shared__ float rmx[256];

    float* botw = (w < 3) ? bot[w] : bot[0];
    const float* botp = (w > 0) ? bot[w - 1] : bot[0];

    float cur0 = INF_F, cur1 = INF_F, cur2 = INF_F, cur3 = INF_F;
    float prev0 = INF_F, prev1 = INF_F, prev2 = INF_F, prev3 = INF_F;
    float vmin = INF_F, vmax = -INF_F;
    float dbuf[4][4];
    float bb[5] = {0.f, 0.f, 0.f, 0.f, 0.f};

    const int firstChunk = 2 * w, lastChunk = 2 * w + 9;

    for (int e = 0; e < 19; ++e) {
        const int c = e - w;
        if (c >= firstChunk && c <= lastChunk) {
            const int T0 = c << 7;
            if (c == firstChunk) {
#pragma unroll
                for (int s = 0; s < 4; ++s) {
                    const ushort4 dv = *reinterpret_cast<const ushort4*>(
                        R + (long)((((T0 + s) & 1023) << 10) + off0));
                    dbuf[s][0] = b2f(dv.x); dbuf[s][1] = b2f(dv.y);
                    dbuf[s][2] = b2f(dv.z); dbuf[s][3] = b2f(dv.w);
                }
            }
            if (w > 0) {
                const int jb = T0 - (w << 8) - 1;
#pragma unroll
                for (int q = 0; q < 5; ++q) bb[q] = botp[(jb + q) & 511];
            }
            for (int g = 0; g < 32; ++g) {
                const int tg = T0 + (g << 2);
                float dn[4][4];
#pragma unroll
                for (int s = 0; s < 4; ++s) {  // prefetch next group's D
                    const ushort4 dv = *reinterpret_cast<const ushort4*>(
                        R + (long)((((tg + 4 + s) & 1023) << 10) + off0));
                    dn[s][0] = b2f(dv.x); dn[s][1] = b2f(dv.y);
                    dn[s][2] = b2f(dv.z); dn[s][3] = b2f(dv.w);
                }
                float bn[5] = {0.f, 0.f, 0.f, 0.f, 0.f};
                if (w > 0 && g < 31) {
                    const int jn = tg + 3 - (w << 8);
#pragma unroll
                    for (int q = 0; q < 5; ++q) bn[q] = botp[(jn + q) & 511];
                }
#pragma unroll
                for (int s = 0; s < 4; ++s) {
                    const int t = tg + s;
                    const int j0 = t - off0;
                    float upc = __shfl_up(cur3, 1);
                    float upp = __shfl_up(prev3, 1);
                    if (lane0) {
                        if (w == 0) {
                            upc = INF_F;
                            upp = (j0 == 0) ? 0.f : INF_F;
                        } else {
                            upc = bb[s + 1];
                            upp = (j0 >= 1) ? bb[s] : INF_F;
                        }
                    }
                    float n0 = dtw_cell(dbuf[s][0], cur0, upc, upp, j0, vmin, vmax);
                    float n1 = dtw_cell(dbuf[s][1], cur1, cur0, prev0, j0 - 1, vmin, vmax);
                    float n2 = dtw_cell(dbuf[s][2], cur2, cur1, prev1, j0 - 2, vmin, vmax);
                    float n3 = dtw_cell(dbuf[s][3], cur3, cur2, prev2, j0 - 3, vmin, vmax);
                    {
                        const long sa = (long)(((t & 1023) << 10) + off0);
                        if (j0 >= 3 && j0 <= 1023) {
                            ushort4 sv;
                            sv.x = f2bt(n0); sv.y = f2bt(n1);
                            sv.z = f2bt(n2); sv.w = f2bt(n3);
                            *reinterpret_cast<ushort4*>(R + sa) = sv;
                        } else {
                            if ((unsigned)j0 < 1024u)        R[sa + 0] = f2bt(n0);
                            if ((unsigned)(j0 - 1) < 1024u)  R[sa + 1] = f2bt(n1);
                            if ((unsigned)(j0 - 2) < 1024u)  R[sa + 2] = f2bt(n2);
                            if ((unsigned)(j0 - 3) < 1024u)  R[sa + 3] = f2bt(n3);
                        }
                    }
                    if (w < 3 && lane == 63 && (unsigned)(j0 - 3) < 1024u)
                        botw[(j0 - 3) & 511] = n3;
                    prev0 = cur0; prev1 = cur1; prev2 = cur2; prev3 = cur3;
                    cur0 = n0; cur1 = n1; cur2 = n2; cur3 = n3;
                }
#pragma unroll
                for (int s = 0; s < 4; ++s)
#pragma unroll
                    for (int r = 0; r < 4; ++r) dbuf[s][r] = dn[s][r];
#pragma unroll
                for (int q = 0; q < 5; ++q) bb[q] = bn[q];
            }
        }
        __syncthreads();
    }

    rmn[tid] = vmin;
    rmx[tid] = vmax;
    __syncthreads();
    for (int s2 = 128; s2 > 0; s2 >>= 1) {
        if (tid < s2) {
            rmn[tid] = fminf(rmn[tid], rmn[tid + s2]);
            rmx[tid] = fmaxf(rmx[tid], rmx[tid + s2]);
        }
        __syncthreads();
    }
    if (tid == 0) {
        minmax[2 * b] = rmn[0];
        minmax[2 * b + 1] = rmx[0];
    }
}

// --------------------------- softmax row stats -----------------------------
__global__ __launch_bounds__(256) void smax_k(const unsigned short* __restrict__ S,
                                              float* __restrict__ rmax,
                                              float* __restrict__ rsuminv)
{
    long row = blockIdx.x;
    const ushort4 v4 =
        reinterpret_cast<const ushort4*>(S + row * L_SEQ)[threadIdx.x];
    float a = b2f(v4.x), b = b2f(v4.y), c = b2f(v4.z), d = b2f(v4.w);
    int t = threadIdx.x;
    __shared__ float red[256];
    red[t] = fmaxf(fmaxf(a, b), fmaxf(c, d));
    __syncthreads();
    for (int s = 128; s > 0; s >>= 1) {
        if (t < s) red[t] = fmaxf(red[t], red[t + s]);
        __syncthreads();
    }
    float mx = red[0];
    __syncthreads();
    red[t] = __expf(a - mx) + __expf(b - mx) + __expf(c - mx) + __expf(d - mx);
    __syncthreads();
    for (int s = 128; s > 0; s >>= 1) {
        if (t < s) red[t] += red[t + s];
        __syncthreads();
    }
    if (t == 0) {
        rmax[row] = mx;
        rsuminv[row] = 1.f / red[0];
    }
}

// ------------------------------- layernorm ---------------------------------
__global__ __launch_bounds__(128) void ln_k(float* __restrict__ X,
                                            const float* __restrict__ g,
                                            const float* __restrict__ b)
{
    long row = blockIdx.x;
    int d = threadIdx.x;
    float x = X[row * DM + d];
    __shared__ float s1[128];
    __shared__ float s2[128];
    s1[d] = x;
    s2[d] = x * x;
    __syncthreads();
    for (int s = 64; s > 0; s >>= 1) {
        if (d < s) { s1[d] += s1[d + s]; s2[d] += s2[d + s]; }
        __syncthreads();
    }
    float mean = s1[0] * (1.f / 128.f);
    float var = s2[0] * (1.f / 128.f) - mean * mean;
    X[row * DM + d] = (x - mean) * rsqrtf(var + 1e-5f) * g[d] + b[d];
}

// -------------------------------- lengths ----------------------------------
__global__ __launch_bounds__(256) void len_k(const float* __restrict__ mask,
                                             float* __restrict__ out)
{
    int b = blockIdx.x;
    int t = threadIdx.x;
    const float4 v = reinterpret_cast<const float4*>(mask + b * L_SEQ)[t];
    __shared__ float red[256];
    red[t] = v.x + v.y + v.z + v.w;
    __syncthreads();
    for (int s = 128; s > 0; s >>= 1) {
        if (t < s) red[t] += red[t + s];
        __syncthreads();
    }
    if (t == 0) out[b] = red[0];
}

// ------------------------------- launcher ----------------------------------
extern "C" void kernel_launch(void* const* d_in, const int* in_sizes, int n_in,
                              void* d_out, int out_size, void* d_ws, size_t ws_size,
                              hipStream_t stream)
{
    const float* x      = (const float*)d_in[0];
    const float* mask   = (const float*)d_in[1];
    const float* conv_w = (const float*)d_in[2];
    const float* conv_b = (const float*)d_in[3];
    const float* w_in   = (const float*)d_in[4];
    const float* b_in   = (const float*)d_in[5];
    const float* w_out  = (const float*)d_in[6];
    const float* b_out  = (const float*)d_in[7];
    const float* w_ff1  = (const float*)d_in[8];
    const float* b_ff1  = (const float*)d_in[9];
    const float* w_ff2  = (const float*)d_in[10];
    const float* b_ff2  = (const float*)d_in[11];
    const float* ln1_g  = (const float*)d_in[12];
    const float* ln1_b  = (const float*)d_in[13];
    const float* ln2_g  = (const float*)d_in[14];
    const float* ln2_b  = (const float*)d_in[15];
    const float* w_lin  = (const float*)d_in[16];
    float* out = (float*)d_out;

    float* ws    = (float*)d_ws;
    float* h     = ws;
    float* qkv   = ws + 4194304L;
    float* t0    = ws + 16777216L;
    float* t1    = ws + 20971520L;
    float* t2    = ws + 25165824L;
    float* norms = ws + 29360128L;
    float* rmax  = ws + 29392896L;
    float* rsum  = ws + 29425664L;
    float* mnmx  = ws + 29458432L;
    unsigned short* Db = (unsigned short*)(ws + 29458496L);  // skewed D/R bf16
    unsigned short* Sb = (unsigned short*)(ws + 46235712L);  // scores bf16 std

    conv_k<<<dim3(32, 128), 128, 0, stream>>>(x, conv_w, conv_b, mask, h);
    norm_k<<<32768, 128, 0, stream>>>(h, norms);
    // D2 -> bf16 skewed
    gemm_k<M_D2, true><<<dim3(16, 16, 32), 256, 0, stream>>>(
        h, h, Db, 1024, 1024, 128, 128, 128, 1024,
        0L, 131072L, 1048576L, norms, nullptr, nullptr);
    // soft-DTW in place over skewed bf16
    dtw_k<<<32, 256, 0, stream>>>(Db, mnmx);
    gemm_k<M_QKV, true><<<dim3(512, 6, 1), 256, 0, stream>>>(
        h, w_in, qkv, 32768, 384, 128, 128, 128, 384,
        0L, 0L, 0L, b_in, nullptr, nullptr);
    // scores = qk/sqrt(d) + norm(R) + keypad -> bf16 standard
    gemm_k<M_SCORES, true><<<dim3(16, 16, 32), 256, 0, stream>>>(
        qkv, qkv + 128, Sb, 1024, 1024, 128, 384, 384, 1024,
        393216L, 393216L, 1048576L, mnmx, mask, Db);
    smax_k<<<32768, 256, 0, stream>>>(Sb, rmax, rsum);
    gemm_k<M_ATTNV, false><<<dim3(16, 2, 32), 256, 0, stream>>>(
        Sb, qkv + 256, t0, 1024, 128, 1024, 1024, 384, 128,
        1048576L, 393216L, 131072L, rmax, rsum, nullptr);
    gemm_k<M_WOUT, true><<<dim3(512, 2, 1), 256, 0, stream>>>(
        t0, w_out, t1, 32768, 128, 128, 128, 128, 128,
        0L, 0L, 0L, b_out, h, nullptr);
    ln_k<<<32768, 128, 0, stream>>>(t1, ln1_g, ln1_b);
    gemm_k<M_FF1, true><<<dim3(512, 2, 1), 256, 0, stream>>>(
        t1, w_ff1, t2, 32768, 128, 128, 128, 128, 128,
        0L, 0L, 0L, b_ff1, nullptr, nullptr);
    gemm_k<M_FF2, true><<<dim3(512, 2, 1), 256, 0, stream>>>(
        t2, w_ff2, t0, 32768, 128, 128, 128, 128, 128,
        0L, 0L, 0L, b_ff2, t1, nullptr);
    ln_k<<<32768, 128, 0, stream>>>(t0, ln2_g, ln2_b);
    gemm_k<M_LIN, true><<<dim3(512, 1, 1), 256, 0, stream>>>(
        t0, w_lin, out, 32768, 16, 128, 128, 128, 16,
        0L, 0L, 0L, mask, nullptr, nullptr);
    len_k<<<32, 256, 0, stream>>>(mask, out + 32768L * 16);
}

// Round 5
// 1857.010 us; speedup vs baseline: 1.5064x; 1.1065x over previous
//
#include <hip/hip_runtime.h>
#include <math.h>

// ---------------------------------------------------------------------------
// DsDTW pipeline (round 4 resubmit — infra failure last round, no measurement).
// soft-DTW with 8 waves x 2 rows/lane (512 thr) for 2 waves/SIMD latency
// hiding; med3-based 2-exp softmin. Skewed bf16 D/R.
// B=32, C_IN=12, T=4095, D=128, L=1024, GAMMA=5.0
//
// ws layout (float offsets):
//   h      @ 0          4,194,304   [32,1024,128]
//   qkv    @ 4194304   12,582,912   [32,1024,384]
//   t0     @ 16777216   4,194,304
//   t1     @ 20971520   4,194,304
//   t2     @ 25165824   4,194,304
//   norms  @ 29360128      32,768
//   rmax   @ 29392896      32,768
//   rsum   @ 29425664      32,768
//   mnmx   @ 29458432          64
//   Db/Rb  @ 29458496  (bf16) skewed D -> R in place
//   Sb     @ 46235712  (bf16) scores, standard layout
// ---------------------------------------------------------------------------

#define L_SEQ 1024
#define DM 128
#define INF_F __builtin_inff()

__device__ __forceinline__ float b2f(unsigned short u) {
    return __uint_as_float(((unsigned)u) << 16);
}
__device__ __forceinline__ unsigned short f2b(float f) {  // RNE
    unsigned u = __float_as_uint(f);
    return (unsigned short)((u + 0x7FFFu + ((u >> 16) & 1u)) >> 16);
}
__device__ __forceinline__ unsigned short f2bt(float f) {  // truncate (cheap)
    return (unsigned short)(__float_as_uint(f) >> 16);
}

// ------------------------- conv + pool + relu + mask -----------------------
__global__ __launch_bounds__(128) void conv_k(
    const float* __restrict__ x, const float* __restrict__ w,
    const float* __restrict__ cb, const float* __restrict__ mask,
    float* __restrict__ h)
{
    int b = blockIdx.x;
    int l0 = blockIdx.y * 8;
    int d = threadIdx.x;
    __shared__ float xs[12][36];
    for (int v = d; v < 12 * 35; v += 128) {
        int c = v / 35, off = v % 35;
        int gi = 4 * l0 - 2 + off;
        xs[c][off] = (gi >= 0 && gi < 4095) ? x[((long)b * 12 + c) * 4095 + gi] : 0.f;
    }
    __syncthreads();
    float s[8];
#pragma unroll
    for (int l = 0; l < 8; ++l) s[l] = 0.f;
    for (int c = 0; c < 12; ++c) {
        const float* wp = w + (d * 12 + c) * 4;
        float w0 = wp[0], w1 = wp[1], w2 = wp[2], w3 = wp[3];
        float e0 = w0, e1 = w0 + w1, e2 = w0 + w1 + w2, e3 = w0 + w1 + w2 + w3;
        float e4 = w1 + w2 + w3, e5 = w2 + w3, e6 = w3;
#pragma unroll
        for (int l = 0; l < 8; ++l) {
            int ba = 4 * l;
            s[l] += xs[c][ba] * e0 + xs[c][ba + 1] * e1 + xs[c][ba + 2] * e2 +
                    xs[c][ba + 3] * e3 + xs[c][ba + 4] * e4 + xs[c][ba + 5] * e5 +
                    xs[c][ba + 6] * e6;
        }
    }
    float cbd = cb[d];
#pragma unroll
    for (int l = 0; l < 8; ++l) {
        int gl = l0 + l;
        float val = fmaxf(cbd + 0.25f * s[l], 0.f) * mask[b * L_SEQ + gl];
        h[((long)(b * L_SEQ + gl)) * DM + d] = val;
    }
}

// ------------------------------- row norms ---------------------------------
__global__ __launch_bounds__(128) void norm_k(const float* __restrict__ h,
                                              float* __restrict__ norms)
{
    long row = blockIdx.x;
    int d = threadIdx.x;
    float v = h[row * DM + d];
    __shared__ float red[128];
    red[d] = v * v;
    __syncthreads();
    for (int s = 64; s > 0; s >>= 1) {
        if (d < s) red[d] += red[d + s];
        __syncthreads();
    }
    if (d == 0) norms[row] = red[0];
}

// ------------------------------ tiled GEMM ---------------------------------
enum GMode { M_D2, M_QKV, M_SCORES, M_ATTNV, M_WOUT, M_FF1, M_FF2, M_LIN };

template <int MODE, bool BT>
__global__ __launch_bounds__(256) void gemm_k(
    const void* Av, const void* Bv, void* Cv,
    int M, int N, int K, int lda, int ldb, int ldc,
    long sA, long sB, long sC,
    const float* __restrict__ e0, const float* __restrict__ e1,
    const void* auxv)
{
    const int z = blockIdx.z;
    const float* A = (const float*)Av + (long)z * sA;
    const unsigned short* Au = (const unsigned short*)Av + (long)z * sA;
    const float* B = (const float*)Bv + (long)z * sB;
    float* C = (float*)Cv + (long)z * sC;
    unsigned short* Cu = (unsigned short*)Cv + (long)z * sC;
    const unsigned short* Rz = (const unsigned short*)auxv + (long)z * 1048576L;

    __shared__ float As[16][65];
    __shared__ float Bs[16][65];
    int tid = threadIdx.x;
    int tx = tid & 15, ty = tid >> 4;
    int m0 = blockIdx.x * 64, n0 = blockIdx.y * 64;
    float acc[4][4] = {};
    int am = tid >> 2;
    int ak = (tid & 3) << 2;
    float rmaxv = 0.f;
    if (MODE == M_ATTNV) rmaxv = e0[(long)z * L_SEQ + m0 + am];

    for (int kk = 0; kk < K; kk += 16) {
        {
            float4 t;
            if (MODE == M_ATTNV) {
                const ushort4 av = *reinterpret_cast<const ushort4*>(
                    Au + (long)(m0 + am) * lda + kk + ak);
                t.x = __expf(b2f(av.x) - rmaxv);
                t.y = __expf(b2f(av.y) - rmaxv);
                t.z = __expf(b2f(av.z) - rmaxv);
                t.w = __expf(b2f(av.w) - rmaxv);
            } else {
                t = *reinterpret_cast<const float4*>(A + (long)(m0 + am) * lda + kk + ak);
            }
            As[ak + 0][am] = t.x;
            As[ak + 1][am] = t.y;
            As[ak + 2][am] = t.z;
            As[ak + 3][am] = t.w;
        }
        if (BT) {
            int n = n0 + am;
            float4 bv = {0.f, 0.f, 0.f, 0.f};
            if (n < N)
                bv = *reinterpret_cast<const float4*>(B + (long)n * ldb + kk + ak);
            Bs[ak + 0][am] = bv.x;
            Bs[ak + 1][am] = bv.y;
            Bs[ak + 2][am] = bv.z;
            Bs[ak + 3][am] = bv.w;
        } else {
            int bk = tid >> 4;
            int bn = (tid & 15) << 2;
            float4 bv =
                *reinterpret_cast<const float4*>(B + (long)(kk + bk) * ldb + n0 + bn);
            Bs[bk][bn + 0] = bv.x;
            Bs[bk][bn + 1] = bv.y;
            Bs[bk][bn + 2] = bv.z;
            Bs[bk][bn + 3] = bv.w;
        }
        __syncthreads();
#pragma unroll
        for (int kc = 0; kc < 16; ++kc) {
            float a0 = As[kc][ty * 4 + 0], a1 = As[kc][ty * 4 + 1];
            float a2 = As[kc][ty * 4 + 2], a3 = As[kc][ty * 4 + 3];
            float b0 = Bs[kc][tx * 4 + 0], b1 = Bs[kc][tx * 4 + 1];
            float b2 = Bs[kc][tx * 4 + 2], b3 = Bs[kc][tx * 4 + 3];
            acc[0][0] += a0 * b0; acc[0][1] += a0 * b1; acc[0][2] += a0 * b2; acc[0][3] += a0 * b3;
            acc[1][0] += a1 * b0; acc[1][1] += a1 * b1; acc[1][2] += a1 * b2; acc[1][3] += a1 * b3;
            acc[2][0] += a2 * b0; acc[2][1] += a2 * b1; acc[2][2] += a2 * b2; acc[2][3] += a2 * b3;
            acc[3][0] += a3 * b0; acc[3][1] += a3 * b1; acc[3][2] += a3 * b2; acc[3][3] += a3 * b3;
        }
        __syncthreads();
    }

    if (MODE == M_D2) {
        // D[i][j] -> bf16 skewed slot [(i+j)&1023][i], via LDS + coalesced runs
        __shared__ float Cs[64][66];
#pragma unroll
        for (int i = 0; i < 4; ++i) {
            int gi = m0 + ty * 4 + i;
#pragma unroll
            for (int j = 0; j < 4; ++j) {
                int gj = n0 + tx * 4 + j;
                Cs[ty * 4 + i][tx * 4 + j] =
                    e0[gi] + e0[(long)z * L_SEQ + gj] - 2.f * acc[i][j];
            }
        }
        __syncthreads();
        int wv = tid >> 6, ln = tid & 63;
        for (int q = 0; q < 32; ++q) {
            int dd = wv * 32 + q;
            if (dd < 127) {
                int d = m0 + n0 + dd;
                int ilo = max(m0, d - n0 - 63);
                int ihi = min(m0 + 63, d - n0);
                int i = ilo + ln;
                if (i <= ihi)
                    Cu[(long)(((d & 1023) << 10) + i)] = f2b(Cs[i - m0][d - n0 - i]);
            }
        }
        return;
    }
    if (MODE == M_SCORES) {
        // stage R (bf16 skewed) into LDS via coalesced anti-diagonal runs
        __shared__ float Rs[64][66];
        int wv = tid >> 6, ln = tid & 63;
        for (int q = 0; q < 32; ++q) {
            int dd = wv * 32 + q;
            if (dd < 127) {
                int d = m0 + n0 + dd;
                int ilo = max(m0, d - n0 - 63);
                int ihi = min(m0 + 63, d - n0);
                int i = ilo + ln;
                if (i <= ihi)
                    Rs[i - m0][d - n0 - i] = b2f(Rz[(long)(((d & 1023) << 10) + i)]);
            }
        }
        __syncthreads();
        float mn = e0[2 * z];
        float inv = 1.f / (e0[2 * z + 1] - mn);
#pragma unroll
        for (int i = 0; i < 4; ++i) {
            int gi = m0 + ty * 4 + i;
            ushort4 sv;
            unsigned short* svp = &sv.x;
#pragma unroll
            for (int j = 0; j < 4; ++j) {
                int gj = n0 + tx * 4 + j;
                float rn = (Rs[ty * 4 + i][tx * 4 + j] - mn) * inv + 1.f;
                float kp = (e1[(long)z * L_SEQ + gj] > 0.f) ? 0.f : -INF_F;
                svp[j] = f2b(acc[i][j] * 0.08838834764831845f + rn + kp);
            }
            *reinterpret_cast<ushort4*>(Cu + (long)gi * ldc + n0 + tx * 4) = sv;
        }
        return;
    }

#pragma unroll
    for (int i = 0; i < 4; ++i) {
        int gi = m0 + ty * 4 + i;
#pragma unroll
        for (int j = 0; j < 4; ++j) {
            int gj = n0 + tx * 4 + j;
            float v = acc[i][j];
            long idx = (long)gi * ldc + gj;
            if (MODE == M_QKV) {
                C[idx] = v + e0[gj];
            } else if (MODE == M_ATTNV) {
                C[idx] = v * e1[(long)z * L_SEQ + gi];
            } else if (MODE == M_WOUT) {
                C[idx] = v + e0[gj] + e1[idx];
            } else if (MODE == M_FF1) {
                C[idx] = fmaxf(v + e0[gj], 0.f);
            } else if (MODE == M_FF2) {
                C[idx] = v + e0[gj] + e1[idx];
            } else if (MODE == M_LIN) {
                if (gj < N) C[idx] = v * e0[gi];
            }
        }
    }
}

// ------------------------------- soft-DTW ----------------------------------
// 8 waves x 64 lanes x 2 rows/lane = 1024 rows. Wave w owns rows
// [128w, 128w+128); lane i owns rows 128w+2i, 128w+2i+1 with skew 1.
// At step t, row r computes column j = t - r. Deps all prev-step:
//   rl = own cur; ru = cur of row-1; rul = prev of row-1;
//   row-1 across lanes -> shfl_up; across waves -> LDS ring bot[w-1]
//   (wave w runs chunk c at epoch c+w, writer is >=1 epoch ahead).
// Chunk = 128 steps; epochs 0..22; 23 barriers total.
// Softmin via min3/med3/max3 + 2 exp (exact: exp(0)=1 term folded).
__device__ __forceinline__ float dtw_cell(float d, float rl, float ru, float rul,
                                          int j, float& vmn, float& vmx)
{
    bool valid = ((unsigned)j < 1024u);
    float mn = fminf(rul, fminf(ru, rl));               // v_min3
    float md = fmaxf(fminf(rul, ru), fminf(fmaxf(rul, ru), rl));  // v_med3
    float mx = fmaxf(rul, fmaxf(ru, rl));               // v_max3
    float s = 1.f + __expf((mn - md) * 0.2f) + __expf((mn - mx) * 0.2f);
    float v = d + mn - 5.0f * __logf(s);
    v = valid ? v : INF_F;
    vmn = valid ? fminf(vmn, v) : vmn;
    vmx = valid ? fmaxf(vmx, v) : vmx;
    return v;
}

__global__ __launch_bounds__(512) void dtw_k(unsigned short* __restrict__ Rb,
                                             float* __restrict__ minmax)
{
    const int b = blockIdx.x;
    unsigned short* R = Rb + (long)b * (1024L * 1024L);
    const int tid = threadIdx.x;
    const int w = tid >> 6;
    const int lane = tid & 63;
    const bool lane0 = (lane == 0);
    const int off0 = (w << 7) + (lane << 1);   // first row of this lane

    __shared__ float bot[7][512];   // ring: bottom row of wave w -> wave w+1
    __shared__ float rmn[512];
    __shared__ float rmx[512];

    float* botw = (w < 7) ? bot[w] : bot[0];            // write (guarded)
    const float* botp = (w > 0) ? bot[w - 1] : bot[0];  // read (guarded)

    float cur0 = INF_F, cur1 = INF_F;
    float prev0 = INF_F, prev1 = INF_F;
    float vmin = INF_F, vmax = -INF_F;
    float dbuf[4][2];
    float bb[5] = {0.f, 0.f, 0.f, 0.f, 0.f};

    const int firstChunk = w, lastChunk = w + 8;

    for (int e = 0; e < 23; ++e) {
        const int c = e - w;
        if (c >= firstChunk && c <= lastChunk) {
            const int T0 = c << 7;
            if (c == firstChunk) {      // prime D queue for steps T0..T0+3
#pragma unroll
                for (int s = 0; s < 4; ++s) {
                    const ushort2 dv = *reinterpret_cast<const ushort2*>(
                        R + (long)((((T0 + s) & 1023) << 10) + off0));
                    dbuf[s][0] = b2f(dv.x);
                    dbuf[s][1] = b2f(dv.y);
                }
            }
            if (w > 0) {                // bot cols for first group of chunk
                const int jb = T0 - (w << 7) - 1;
#pragma unroll
                for (int q = 0; q < 5; ++q) bb[q] = botp[(jb + q) & 511];
            }
            for (int g = 0; g < 32; ++g) {
                const int tg = T0 + (g << 2);
                float dn[4][2];
#pragma unroll
                for (int s = 0; s < 4; ++s) {  // prefetch next group's D
                    const ushort2 dv = *reinterpret_cast<const ushort2*>(
                        R + (long)((((tg + 4 + s) & 1023) << 10) + off0));
                    dn[s][0] = b2f(dv.x);
                    dn[s][1] = b2f(dv.y);
                }
                float bn[5] = {0.f, 0.f, 0.f, 0.f, 0.f};
                if (w > 0 && g < 31) {  // prefetch next group's bot cols
                    const int jn = tg + 4 - (w << 7) - 1;
#pragma unroll
                    for (int q = 0; q < 5; ++q) bn[q] = botp[(jn + q) & 511];
                }
#pragma unroll
                for (int s = 0; s < 4; ++s) {
                    const int t = tg + s;
                    const int j0 = t - off0;
                    float upc = __shfl_up(cur1, 1);
                    float upp = __shfl_up(prev1, 1);
                    if (lane0) {
                        if (w == 0) {
                            upc = INF_F;
                            upp = (j0 == 0) ? 0.f : INF_F;
                        } else {
                            upc = bb[s + 1];
                            upp = (j0 >= 1) ? bb[s] : INF_F;
                        }
                    }
                    float n0 = dtw_cell(dbuf[s][0], cur0, upc, upp, j0, vmin, vmax);
                    float n1 = dtw_cell(dbuf[s][1], cur1, cur0, prev0, j0 - 1, vmin, vmax);
                    {
                        const long sa = (long)(((t & 1023) << 10) + off0);
                        if (j0 >= 1 && j0 <= 1023) {
                            ushort2 sv;
                            sv.x = f2bt(n0);
                            sv.y = f2bt(n1);
                            *reinterpret_cast<ushort2*>(R + sa) = sv;
                        } else {
                            if ((unsigned)j0 < 1024u)       R[sa + 0] = f2bt(n0);
                            if ((unsigned)(j0 - 1) < 1024u) R[sa + 1] = f2bt(n1);
                        }
                    }
                    if (w < 7 && lane == 63 && (unsigned)(j0 - 1) < 1024u)
                        botw[(j0 - 1) & 511] = n1;
                    prev0 = cur0; prev1 = cur1;
                    cur0 = n0; cur1 = n1;
                }
#pragma unroll
                for (int s = 0; s < 4; ++s) {
                    dbuf[s][0] = dn[s][0];
                    dbuf[s][1] = dn[s][1];
                }
#pragma unroll
                for (int q = 0; q < 5; ++q) bb[q] = bn[q];
            }
        }
        __syncthreads();
    }

    rmn[tid] = vmin;
    rmx[tid] = vmax;
    __syncthreads();
    for (int s2 = 256; s2 > 0; s2 >>= 1) {
        if (tid < s2) {
            rmn[tid] = fminf(rmn[tid], rmn[tid + s2]);
            rmx[tid] = fmaxf(rmx[tid], rmx[tid + s2]);
        }
        __syncthreads();
    }
    if (tid == 0) {
        minmax[2 * b] = rmn[0];
        minmax[2 * b + 1] = rmx[0];
    }
}

// --------------------------- softmax row stats -----------------------------
__global__ __launch_bounds__(256) void smax_k(const unsigned short* __restrict__ S,
                                              float* __restrict__ rmax,
                                              float* __restrict__ rsuminv)
{
    long row = blockIdx.x;
    const ushort4 v4 =
        reinterpret_cast<const ushort4*>(S + row * L_SEQ)[threadIdx.x];
    float a = b2f(v4.x), b = b2f(v4.y), c = b2f(v4.z), d = b2f(v4.w);
    int t = threadIdx.x;
    __shared__ float red[256];
    red[t] = fmaxf(fmaxf(a, b), fmaxf(c, d));
    __syncthreads();
    for (int s = 128; s > 0; s >>= 1) {
        if (t < s) red[t] = fmaxf(red[t], red[t + s]);
        __syncthreads();
    }
    float mx = red[0];
    __syncthreads();
    red[t] = __expf(a - mx) + __expf(b - mx) + __expf(c - mx) + __expf(d - mx);
    __syncthreads();
    for (int s = 128; s > 0; s >>= 1) {
        if (t < s) red[t] += red[t + s];
        __syncthreads();
    }
    if (t == 0) {
        rmax[row] = mx;
        rsuminv[row] = 1.f / red[0];
    }
}

// ------------------------------- layernorm ---------------------------------
__global__ __launch_bounds__(128) void ln_k(float* __restrict__ X,
                                            const float* __restrict__ g,
                                            const float* __restrict__ b)
{
    long row = blockIdx.x;
    int d = threadIdx.x;
    float x = X[row * DM + d];
    __shared__ float s1[128];
    __shared__ float s2[128];
    s1[d] = x;
    s2[d] = x * x;
    __syncthreads();
    for (int s = 64; s > 0; s >>= 1) {
        if (d < s) { s1[d] += s1[d + s]; s2[d] += s2[d + s]; }
        __syncthreads();
    }
    float mean = s1[0] * (1.f / 128.f);
    float var = s2[0] * (1.f / 128.f) - mean * mean;
    X[row * DM + d] = (x - mean) * rsqrtf(var + 1e-5f) * g[d] + b[d];
}

// -------------------------------- lengths ----------------------------------
__global__ __launch_bounds__(256) void len_k(const float* __restrict__ mask,
                                             float* __restrict__ out)
{
    int b = blockIdx.x;
    int t = threadIdx.x;
    const float4 v = reinterpret_cast<const float4*>(mask + b * L_SEQ)[t];
    __shared__ float red[256];
    red[t] = v.x + v.y + v.z + v.w;
    __syncthreads();
    for (int s = 128; s > 0; s >>= 1) {
        if (t < s) red[t] += red[t + s];
        __syncthreads();
    }
    if (t == 0) out[b] = red[0];
}

// ------------------------------- launcher ----------------------------------
extern "C" void kernel_launch(void* const* d_in, const int* in_sizes, int n_in,
                              void* d_out, int out_size, void* d_ws, size_t ws_size,
                              hipStream_t stream)
{
    const float* x      = (const float*)d_in[0];
    const float* mask   = (const float*)d_in[1];
    const float* conv_w = (const float*)d_in[2];
    const float* conv_b = (const float*)d_in[3];
    const float* w_in   = (const float*)d_in[4];
    const float* b_in   = (const float*)d_in[5];
    const float* w_out  = (const float*)d_in[6];
    const float* b_out  = (const float*)d_in[7];
    const float* w_ff1  = (const float*)d_in[8];
    const float* b_ff1  = (const float*)d_in[9];
    const float* w_ff2  = (const float*)d_in[10];
    const float* b_ff2  = (const float*)d_in[11];
    const float* ln1_g  = (const float*)d_in[12];
    const float* ln1_b  = (const float*)d_in[13];
    const float* ln2_g  = (const float*)d_in[14];
    const float* ln2_b  = (const float*)d_in[15];
    const float* w_lin  = (const float*)d_in[16];
    float* out = (float*)d_out;

    float* ws    = (float*)d_ws;
    float* h     = ws;
    float* qkv   = ws + 4194304L;
    float* t0    = ws + 16777216L;
    float* t1    = ws + 20971520L;
    float* t2    = ws + 25165824L;
    float* norms = ws + 29360128L;
    float* rmax  = ws + 29392896L;
    float* rsum  = ws + 29425664L;
    float* mnmx  = ws + 29458432L;
    unsigned short* Db = (unsigned short*)(ws + 29458496L);  // skewed D/R bf16
    unsigned short* Sb = (unsigned short*)(ws + 46235712L);  // scores bf16 std

    conv_k<<<dim3(32, 128), 128, 0, stream>>>(x, conv_w, conv_b, mask, h);
    norm_k<<<32768, 128, 0, stream>>>(h, norms);
    gemm_k<M_D2, true><<<dim3(16, 16, 32), 256, 0, stream>>>(
        h, h, Db, 1024, 1024, 128, 128, 128, 1024,
        0L, 131072L, 1048576L, norms, nullptr, nullptr);
    dtw_k<<<32, 512, 0, stream>>>(Db, mnmx);
    gemm_k<M_QKV, true><<<dim3(512, 6, 1), 256, 0, stream>>>(
        h, w_in, qkv, 32768, 384, 128, 128, 128, 384,
        0L, 0L, 0L, b_in, nullptr, nullptr);
    gemm_k<M_SCORES, true><<<dim3(16, 16, 32), 256, 0, stream>>>(
        qkv, qkv + 128, Sb, 1024, 1024, 128, 384, 384, 1024,
        393216L, 393216L, 1048576L, mnmx, mask, Db);
    smax_k<<<32768, 256, 0, stream>>>(Sb, rmax, rsum);
    gemm_k<M_ATTNV, false><<<dim3(16, 2, 32), 256, 0, stream>>>(
        Sb, qkv + 256, t0, 1024, 128, 1024, 1024, 384, 128,
        1048576L, 393216L, 131072L, rmax, rsum, nullptr);
    gemm_k<M_WOUT, true><<<dim3(512, 2, 1), 256, 0, stream>>>(
        t0, w_out, t1, 32768, 128, 128, 128, 128, 128,
        0L, 0L, 0L, b_out, h, nullptr);
    ln_k<<<32768, 128, 0, stream>>>(t1, ln1_g, ln1_b);
    gemm_k<M_FF1, true><<<dim3(512, 2, 1), 256, 0, stream>>>(
        t1, w_ff1, t2, 32768, 128, 128, 128, 128, 128,
        0L, 0L, 0L, b_ff1, nullptr, nullptr);
    gemm_k<M_FF2, true><<<dim3(512, 2, 1), 256, 0, stream>>>(
        t2, w_ff2, t0, 32768, 128, 128, 128, 128, 128,
        0L, 0L, 0L, b_ff2, t1, nullptr);
    ln_k<<<32768, 128, 0, stream>>>(t0, ln2_g, ln2_b);
    gemm_k<M_LIN, true><<<dim3(512, 1, 1), 256, 0, stream>>>(
        t0, w_lin, out, 32768, 16, 128, 128, 128, 16,
        0L, 0L, 0L, mask, nullptr, nullptr);
    len_k<<<32, 256, 0, stream>>>(mask, out + 32768L * 16);
}

// Round 7
// 1483.288 us; speedup vs baseline: 1.8860x; 1.2520x over previous
//
#include <hip/hip_runtime.h>
#include <math.h>

// ---------------------------------------------------------------------------
// DsDTW pipeline (round 7 = round 6 with __exp2f/__log2f -> __expf/__logf fix).
// MFMA bf16 for the three 1024x1024 GEMM families (D2 / SCORES / ATTNV) +
// leaner soft-DTW (MID/EDGE chunk split, incremental addressing).
// B=32, C_IN=12, T=4095, D=128, L=1024, GAMMA=5.
//
// ws layout (float offsets):
//   h      @ 0          4,194,304   [32,1024,128] fp32
//   qkvb   @ 4194304    qb/kb/vb/vt bf16, 4x 4,194,304 ushorts (8.4M floats)
//   t0     @ 16777216   4,194,304
//   t1     @ 20971520   4,194,304
//   t2     @ 25165824   4,194,304   (first half doubles as hbf bf16 pre-FF1)
//   norms  @ 29360128      32,768
//   rsum   @ 29425664      32,768
//   mnmx   @ 29458432          64
//   Db/Rb  @ 29458496  (bf16) skewed D -> R in place
//   Sb     @ 46235712  (bf16) scores -> P (exp'd in smax_k), standard layout
// ---------------------------------------------------------------------------

#define L_SEQ 1024
#define DM 128
#define INF_F __builtin_inff()

typedef short s16x8 __attribute__((ext_vector_type(8)));
typedef float f32x4 __attribute__((ext_vector_type(4)));
typedef unsigned short u16;

__device__ __forceinline__ float b2f(u16 u) {
    return __uint_as_float(((unsigned)u) << 16);
}
__device__ __forceinline__ u16 f2b(float f) {  // RNE
    unsigned u = __float_as_uint(f);
    return (u16)((u + 0x7FFFu + ((u >> 16) & 1u)) >> 16);
}
__device__ __forceinline__ u16 f2bt(float f) {  // truncate (cheap)
    return (u16)(__float_as_uint(f) >> 16);
}

// ------------------------- conv + pool + relu + mask -----------------------
__global__ __launch_bounds__(128) void conv_k(
    const float* __restrict__ x, const float* __restrict__ w,
    const float* __restrict__ cb, const float* __restrict__ mask,
    float* __restrict__ h, u16* __restrict__ hbf)
{
    int b = blockIdx.x;
    int l0 = blockIdx.y * 8;
    int d = threadIdx.x;
    __shared__ float xs[12][36];
    for (int v = d; v < 12 * 35; v += 128) {
        int c = v / 35, off = v % 35;
        int gi = 4 * l0 - 2 + off;
        xs[c][off] = (gi >= 0 && gi < 4095) ? x[((long)b * 12 + c) * 4095 + gi] : 0.f;
    }
    __syncthreads();
    float s[8];
#pragma unroll
    for (int l = 0; l < 8; ++l) s[l] = 0.f;
    for (int c = 0; c < 12; ++c) {
        const float* wp = w + (d * 12 + c) * 4;
        float w0 = wp[0], w1 = wp[1], w2 = wp[2], w3 = wp[3];
        float e0 = w0, e1 = w0 + w1, e2 = w0 + w1 + w2, e3 = w0 + w1 + w2 + w3;
        float e4 = w1 + w2 + w3, e5 = w2 + w3, e6 = w3;
#pragma unroll
        for (int l = 0; l < 8; ++l) {
            int ba = 4 * l;
            s[l] += xs[c][ba] * e0 + xs[c][ba + 1] * e1 + xs[c][ba + 2] * e2 +
                    xs[c][ba + 3] * e3 + xs[c][ba + 4] * e4 + xs[c][ba + 5] * e5 +
                    xs[c][ba + 6] * e6;
        }
    }
    float cbd = cb[d];
#pragma unroll
    for (int l = 0; l < 8; ++l) {
        int gl = l0 + l;
        float val = fmaxf(cbd + 0.25f * s[l], 0.f) * mask[b * L_SEQ + gl];
        long idx = ((long)(b * L_SEQ + gl)) * DM + d;
        h[idx] = val;
        hbf[idx] = f2b(val);
    }
}

// ------------------------------- row norms ---------------------------------
__global__ __launch_bounds__(128) void norm_k(const float* __restrict__ h,
                                              float* __restrict__ norms)
{
    long row = blockIdx.x;
    int d = threadIdx.x;
    float v = h[row * DM + d];
    __shared__ float red[128];
    red[d] = v * v;
    __syncthreads();
    for (int s = 64; s > 0; s >>= 1) {
        if (d < s) red[d] += red[d + s];
        __syncthreads();
    }
    if (d == 0) norms[row] = red[0];
}

// --------------------------- MFMA bf16 GEMMs -------------------------------
// C = A.B^T, A/B row-major [rows, K] bf16. mfma_f32_16x16x32_bf16:
//   A frag: m = lane&15, k = (lane>>4)*8 + j  (8 contiguous)
//   B frag: n = lane&15, k = (lane>>4)*8 + j  (8 contiguous, B row-major [N,K])
//   C/D:    col = lane&15, row = (lane>>4)*4 + reg
// Block 256 thr = 4 waves; wave w owns rows [m0+16w, +16), 4 n-tiles of 16.
enum MGMode { G_D2, G_SC, G_AV };

template <int MODE>
__global__ __launch_bounds__(256) void mgemm_k(
    const u16* __restrict__ A0, const u16* __restrict__ B0, void* __restrict__ C0,
    const float* __restrict__ e0, const float* __restrict__ e1,
    const u16* __restrict__ R0, const float* __restrict__ rsum)
{
    constexpr int LDK = (MODE == G_AV) ? 1024 : 128;   // K == LDK
    constexpr int KK = LDK / 32;
    const int z = blockIdx.z;
    const u16* A = A0 + (MODE == G_D2 ? 0L
                                      : (long)z * (MODE == G_AV ? 1048576L : 131072L));
    const u16* B = B0 + (long)z * 131072L;
    const int tid = threadIdx.x, wv = tid >> 6, lane = tid & 63;
    const int m0 = blockIdx.x * 64, n0 = blockIdx.y * 64;
    const int co = lane & 15;
    const int q8 = (lane >> 4) << 3;
    const int mrow = m0 + 16 * wv + co;

    f32x4 acc[4];
#pragma unroll
    for (int tn = 0; tn < 4; ++tn) acc[tn] = 0.f;

    for (int kk = 0; kk < KK; ++kk) {
        const int k0 = kk * 32 + q8;
        const s16x8 a = *reinterpret_cast<const s16x8*>(A + (long)mrow * LDK + k0);
#pragma unroll
        for (int tn = 0; tn < 4; ++tn) {
            const s16x8 b = *reinterpret_cast<const s16x8*>(
                B + (long)(n0 + 16 * tn + co) * LDK + k0);
            acc[tn] = __builtin_amdgcn_mfma_f32_16x16x32_bf16(a, b, acc[tn], 0, 0, 0);
        }
    }

    const int li0 = 16 * wv + ((lane >> 4) << 2);   // local row base (+reg)

    if (MODE == G_D2) {
        // D[i][j] = |h0_i|^2 + |hz_j|^2 - 2 dot -> bf16 skewed [(i+j)&1023][i]
        __shared__ float Cs[64][66];
        float ni[4];
#pragma unroll
        for (int r = 0; r < 4; ++r) ni[r] = e0[m0 + li0 + r];
#pragma unroll
        for (int tn = 0; tn < 4; ++tn) {
            float nj = e0[(long)z * L_SEQ + n0 + 16 * tn + co];
#pragma unroll
            for (int r = 0; r < 4; ++r)
                Cs[li0 + r][16 * tn + co] = ni[r] + nj - 2.f * acc[tn][r];
        }
        __syncthreads();
        u16* Cu = (u16*)C0 + (long)z * 1048576L;
        int ln = lane;
        for (int q = 0; q < 32; ++q) {
            int dd = wv * 32 + q;
            if (dd < 127) {
                int d = m0 + n0 + dd;
                int ilo = max(m0, d - n0 - 63);
                int ihi = min(m0 + 63, d - n0);
                int i = ilo + ln;
                if (i <= ihi)
                    Cu[(long)(((d & 1023) << 10) + i)] = f2b(Cs[i - m0][d - n0 - i]);
            }
        }
        return;
    }
    if (MODE == G_SC) {
        // scores = qk*scale + norm(R) + keypad -> bf16 standard layout
        __shared__ float Rs[64][66];
        const u16* Rz = R0 + (long)z * 1048576L;
        int ln = lane;
        for (int q = 0; q < 32; ++q) {
            int dd = wv * 32 + q;
            if (dd < 127) {
                int d = m0 + n0 + dd;
                int ilo = max(m0, d - n0 - 63);
                int ihi = min(m0 + 63, d - n0);
                int i = ilo + ln;
                if (i <= ihi)
                    Rs[i - m0][d - n0 - i] = b2f(Rz[(long)(((d & 1023) << 10) + i)]);
            }
        }
        __syncthreads();
        float mn = e0[2 * z];
        float inv = 1.f / (e0[2 * z + 1] - mn);
        u16* Cu = (u16*)C0 + (long)z * 1048576L;
#pragma unroll
        for (int tn = 0; tn < 4; ++tn) {
            int gj = n0 + 16 * tn + co;
            float kp = (e1[(long)z * L_SEQ + gj] > 0.f) ? 0.f : -INF_F;
#pragma unroll
            for (int r = 0; r < 4; ++r) {
                float val = acc[tn][r] * 0.08838834764831845f +
                            (Rs[li0 + r][16 * tn + co] - mn) * inv + 1.f + kp;
                Cu[(long)(m0 + li0 + r) * 1024 + gj] = f2b(val);
            }
        }
        return;
    }
    // G_AV: out = (P . V) * rsuminv[row], fp32
    {
        float* Cf = (float*)C0 + (long)z * 131072L;
        float rsv[4];
#pragma unroll
        for (int r = 0; r < 4; ++r) rsv[r] = rsum[(long)z * L_SEQ + m0 + li0 + r];
#pragma unroll
        for (int tn = 0; tn < 4; ++tn)
#pragma unroll
            for (int r = 0; r < 4; ++r)
                Cf[(long)(m0 + li0 + r) * 128 + n0 + 16 * tn + co] =
                    acc[tn][r] * rsv[r];
    }
}

// --------------------------- V transpose (bf16) ----------------------------
__global__ __launch_bounds__(256) void transpose_v(const u16* __restrict__ vb,
                                                   u16* __restrict__ vt)
{
    const int z = blockIdx.z;
    const int l0 = blockIdx.x * 64, d0 = blockIdx.y * 64;
    const u16* src = vb + (long)z * 131072L;
    u16* dst = vt + (long)z * 131072L;
    __shared__ u16 T[64][65];
    int tid = threadIdx.x;
#pragma unroll
    for (int i = 0; i < 16; ++i) {
        int idx = tid + 256 * i;
        int li = idx >> 6, dj = idx & 63;
        T[dj][li] = src[(long)(l0 + li) * 128 + d0 + dj];
    }
    __syncthreads();
#pragma unroll
    for (int i = 0; i < 16; ++i) {
        int idx = tid + 256 * i;
        int dj = idx >> 6, li = idx & 63;
        dst[(long)(d0 + dj) * 1024 + l0 + li] = T[dj][li];
    }
}

// ------------------------------ fp32 GEMMs ---------------------------------
enum GMode { M_QKVB, M_WOUT, M_FF1, M_FF2, M_LIN };

template <int MODE>
__global__ __launch_bounds__(256) void gemm_k(
    const float* __restrict__ A, const float* __restrict__ B, void* __restrict__ Cv,
    int M, int N, int K, int lda, int ldb, int ldc,
    const float* __restrict__ e0, const float* __restrict__ e1)
{
    __shared__ float As[16][65];
    __shared__ float Bs[16][65];
    int tid = threadIdx.x;
    int tx = tid & 15, ty = tid >> 4;
    int m0 = blockIdx.x * 64, n0 = blockIdx.y * 64;
    float acc[4][4] = {};
    int am = tid >> 2;
    int ak = (tid & 3) << 2;

    for (int kk = 0; kk < K; kk += 16) {
        {
            const float4 av =
                *reinterpret_cast<const float4*>(A + (long)(m0 + am) * lda + kk + ak);
            As[ak + 0][am] = av.x;
            As[ak + 1][am] = av.y;
            As[ak + 2][am] = av.z;
            As[ak + 3][am] = av.w;
        }
        {
            int n = n0 + am;
            float4 bv = {0.f, 0.f, 0.f, 0.f};
            if (n < N)
                bv = *reinterpret_cast<const float4*>(B + (long)n * ldb + kk + ak);
            Bs[ak + 0][am] = bv.x;
            Bs[ak + 1][am] = bv.y;
            Bs[ak + 2][am] = bv.z;
            Bs[ak + 3][am] = bv.w;
        }
        __syncthreads();
#pragma unroll
        for (int kc = 0; kc < 16; ++kc) {
            float a0 = As[kc][ty * 4 + 0], a1 = As[kc][ty * 4 + 1];
            float a2 = As[kc][ty * 4 + 2], a3 = As[kc][ty * 4 + 3];
            float b0 = Bs[kc][tx * 4 + 0], b1 = Bs[kc][tx * 4 + 1];
            float b2 = Bs[kc][tx * 4 + 2], b3 = Bs[kc][tx * 4 + 3];
            acc[0][0] += a0 * b0; acc[0][1] += a0 * b1; acc[0][2] += a0 * b2; acc[0][3] += a0 * b3;
            acc[1][0] += a1 * b0; acc[1][1] += a1 * b1; acc[1][2] += a1 * b2; acc[1][3] += a1 * b3;
            acc[2][0] += a2 * b0; acc[2][1] += a2 * b1; acc[2][2] += a2 * b2; acc[2][3] += a2 * b3;
            acc[3][0] += a3 * b0; acc[3][1] += a3 * b1; acc[3][2] += a3 * b2; acc[3][3] += a3 * b3;
        }
        __syncthreads();
    }

    if (MODE == M_QKVB) {
        // write bf16 q/k/v: segment = n0>>7 (block's 64-col window is within one)
        u16* Cu = (u16*)Cv + ((long)(n0 >> 7)) * 4194304L;
        int cb = (n0 & 127) + tx * 4;
#pragma unroll
        for (int i = 0; i < 4; ++i) {
            int gi = m0 + ty * 4 + i;
            ushort4 sv;
            u16* svp = &sv.x;
#pragma unroll
            for (int j = 0; j < 4; ++j)
                svp[j] = f2b(acc[i][j] + e0[n0 + tx * 4 + j]);
            *reinterpret_cast<ushort4*>(Cu + (long)gi * 128 + cb) = sv;
        }
        return;
    }
    float* C = (float*)Cv;
#pragma unroll
    for (int i = 0; i < 4; ++i) {
        int gi = m0 + ty * 4 + i;
#pragma unroll
        for (int j = 0; j < 4; ++j) {
            int gj = n0 + tx * 4 + j;
            float v = acc[i][j];
            long idx = (long)gi * ldc + gj;
            if (MODE == M_WOUT) {
                C[idx] = v + e0[gj] + e1[idx];
            } else if (MODE == M_FF1) {
                C[idx] = fmaxf(v + e0[gj], 0.f);
            } else if (MODE == M_FF2) {
                C[idx] = v + e0[gj] + e1[idx];
            } else if (MODE == M_LIN) {
                if (gj < N) C[idx] = v * e0[gi];
            }
        }
    }
}

// ------------------------------- soft-DTW ----------------------------------
// 8 waves x 64 lanes x 2 rows/lane = 1024 rows (verified schedule, round 5).
// Chunks c in [w, w+8]; c==w and c==w+8 are EDGE (boundary cells), the 7
// middle chunks compile with no validity checks / unconditional packed stores.
__device__ __forceinline__ float softmin3(float d, float rl, float ru, float rul)
{
    float mn = fminf(rul, fminf(ru, rl));
    float md = fmaxf(fminf(rul, ru), fminf(fmaxf(rul, ru), rl));  // med3
    float mx = fmaxf(rul, fmaxf(ru, rl));
    float s = 1.f + __expf((mn - md) * 0.2f) + __expf((mn - mx) * 0.2f);
    return d + mn - 5.0f * __logf(s);
}

template <bool EDGE>
__device__ __forceinline__ void dtw_chunk(
    u16* __restrict__ R, const float* __restrict__ botp, float* __restrict__ botw,
    int w, int lane, bool lane0, int off0, int T0,
    float& cur0, float& cur1, float& prev0, float& prev1,
    float& vmin, float& vmax, float (&dbuf)[4][2], float (&bb)[5])
{
    u16* rp = R + (((T0 & 1023) << 10) + off0);
    for (int g = 0; g < 32; ++g) {
        const int tg = T0 + (g << 2);
        float dn[4][2];
#pragma unroll
        for (int s = 0; s < 4; ++s) {  // prefetch next group's D/R inputs
            const ushort2 dv = *reinterpret_cast<const ushort2*>(
                R + ((((tg + 4 + s) & 1023) << 10) + off0));
            dn[s][0] = b2f(dv.x);
            dn[s][1] = b2f(dv.y);
        }
        float bn[5] = {0.f, 0.f, 0.f, 0.f, 0.f};
        if (w > 0 && g < 31) {
            const int jn = tg + 3 - (w << 7);
#pragma unroll
            for (int q = 0; q < 5; ++q) bn[q] = botp[(jn + q) & 511];
        }
#pragma unroll
        for (int s = 0; s < 4; ++s) {
            const int j0 = tg + s - off0;
            float upc = __shfl_up(cur1, 1);
            float upp = __shfl_up(prev1, 1);
            if (lane0) {
                if (w == 0) {
                    upc = INF_F;
                    upp = (EDGE && j0 == 0) ? 0.f : INF_F;
                } else {
                    upc = bb[s + 1];
                    upp = (!EDGE || j0 >= 1) ? bb[s] : INF_F;
                }
            }
            float n0v = softmin3(dbuf[s][0], cur0, upc, upp);
            float n1v = softmin3(dbuf[s][1], cur1, cur0, prev0);
            if (EDGE) {
                bool v0 = ((unsigned)j0 < 1024u);
                bool v1 = ((unsigned)(j0 - 1) < 1024u);
                n0v = v0 ? n0v : INF_F;
                n1v = v1 ? n1v : INF_F;
                vmin = fminf(vmin, fminf(n0v, n1v));
                vmax = v0 ? fmaxf(vmax, n0v) : vmax;
                vmax = v1 ? fmaxf(vmax, n1v) : vmax;
                if (j0 >= 1 && j0 <= 1023) {
                    ushort2 sv;
                    sv.x = f2bt(n0v);
                    sv.y = f2bt(n1v);
                    *reinterpret_cast<ushort2*>(rp) = sv;
                } else {
                    if (v0) rp[0] = f2bt(n0v);
                    if (v1) rp[1] = f2bt(n1v);
                }
                if (w < 7 && lane == 63 && v1) botw[(j0 - 1) & 511] = n1v;
            } else {
                vmin = fminf(vmin, fminf(n0v, n1v));
                vmax = fmaxf(vmax, fmaxf(n0v, n1v));
                ushort2 sv;
                sv.x = f2bt(n0v);
                sv.y = f2bt(n1v);
                *reinterpret_cast<ushort2*>(rp) = sv;
                if (w < 7 && lane == 63) botw[(j0 - 1) & 511] = n1v;
            }
            prev0 = cur0; prev1 = cur1;
            cur0 = n0v; cur1 = n1v;
            rp += 1024;
        }
#pragma unroll
        for (int s = 0; s < 4; ++s) { dbuf[s][0] = dn[s][0]; dbuf[s][1] = dn[s][1]; }
#pragma unroll
        for (int q = 0; q < 5; ++q) bb[q] = bn[q];
    }
}

__global__ __launch_bounds__(512) void dtw_k(u16* __restrict__ Rb,
                                             float* __restrict__ minmax)
{
    const int b = blockIdx.x;
    u16* R = Rb + (long)b * (1024L * 1024L);
    const int tid = threadIdx.x;
    const int w = tid >> 6;
    const int lane = tid & 63;
    const bool lane0 = (lane == 0);
    const int off0 = (w << 7) + (lane << 1);

    __shared__ float bot[7][512];
    __shared__ float rmn[512];
    __shared__ float rmx[512];

    float* botw = (w < 7) ? bot[w] : bot[0];
    const float* botp = (w > 0) ? bot[w - 1] : bot[0];

    float cur0 = INF_F, cur1 = INF_F;
    float prev0 = INF_F, prev1 = INF_F;
    float vmin = INF_F, vmax = -INF_F;
    float dbuf[4][2];
    float bb[5] = {0.f, 0.f, 0.f, 0.f, 0.f};

    for (int e = 0; e < 23; ++e) {
        const int c = e - w;
        if (c >= w && c <= w + 8) {
            const int T0 = c << 7;
            if (c == w) {   // prime D queue
#pragma unroll
                for (int s = 0; s < 4; ++s) {
                    const ushort2 dv = *reinterpret_cast<const ushort2*>(
                        R + ((((T0 + s) & 1023) << 10) + off0));
                    dbuf[s][0] = b2f(dv.x);
                    dbuf[s][1] = b2f(dv.y);
                }
            }
            if (w > 0) {
                const int jb = T0 - (w << 7) - 1;
#pragma unroll
                for (int q = 0; q < 5; ++q) bb[q] = botp[(jb + q) & 511];
            }
            if (c == w || c == w + 8)
                dtw_chunk<true>(R, botp, botw, w, lane, lane0, off0, T0,
                                cur0, cur1, prev0, prev1, vmin, vmax, dbuf, bb);
            else
                dtw_chunk<false>(R, botp, botw, w, lane, lane0, off0, T0,
                                 cur0, cur1, prev0, prev1, vmin, vmax, dbuf, bb);
        }
        __syncthreads();
    }

    rmn[tid] = vmin;
    rmx[tid] = vmax;
    __syncthreads();
    for (int s2 = 256; s2 > 0; s2 >>= 1) {
        if (tid < s2) {
            rmn[tid] = fminf(rmn[tid], rmn[tid + s2]);
            rmx[tid] = fmaxf(rmx[tid], rmx[tid + s2]);
        }
        __syncthreads();
    }
    if (tid == 0) {
        minmax[2 * b] = rmn[0];
        minmax[2 * b + 1] = rmx[0];
    }
}

// ---------------- softmax row stats + in-place P = exp(s-max) --------------
__global__ __launch_bounds__(256) void smax_k(u16* __restrict__ S,
                                              float* __restrict__ rsuminv)
{
    long row = blockIdx.x;
    u16* rowp = S + row * L_SEQ;
    const ushort4 v4 = reinterpret_cast<const ushort4*>(rowp)[threadIdx.x];
    float a = b2f(v4.x), b = b2f(v4.y), c = b2f(v4.z), d = b2f(v4.w);
    int t = threadIdx.x;
    __shared__ float red[256];
    red[t] = fmaxf(fmaxf(a, b), fmaxf(c, d));
    __syncthreads();
    for (int s = 128; s > 0; s >>= 1) {
        if (t < s) red[t] = fmaxf(red[t], red[t + s]);
        __syncthreads();
    }
    float mx = red[0];
    __syncthreads();
    float ea = __expf(a - mx), eb = __expf(b - mx);
    float ec = __expf(c - mx), ed = __expf(d - mx);
    ushort4 pv;
    pv.x = f2b(ea); pv.y = f2b(eb); pv.z = f2b(ec); pv.w = f2b(ed);
    reinterpret_cast<ushort4*>(rowp)[t] = pv;
    red[t] = ea + eb + ec + ed;
    __syncthreads();
    for (int s = 128; s > 0; s >>= 1) {
        if (t < s) red[t] += red[t + s];
        __syncthreads();
    }
    if (t == 0) rsuminv[row] = 1.f / red[0];
}

// ------------------------------- layernorm ---------------------------------
__global__ __launch_bounds__(128) void ln_k(float* __restrict__ X,
                                            const float* __restrict__ g,
                                            const float* __restrict__ b)
{
    long row = blockIdx.x;
    int d = threadIdx.x;
    float x = X[row * DM + d];
    __shared__ float s1[128];
    __shared__ float s2[128];
    s1[d] = x;
    s2[d] = x * x;
    __syncthreads();
    for (int s = 64; s > 0; s >>= 1) {
        if (d < s) { s1[d] += s1[d + s]; s2[d] += s2[d + s]; }
        __syncthreads();
    }
    float mean = s1[0] * (1.f / 128.f);
    float var = s2[0] * (1.f / 128.f) - mean * mean;
    X[row * DM + d] = (x - mean) * rsqrtf(var + 1e-5f) * g[d] + b[d];
}

// -------------------------------- lengths ----------------------------------
__global__ __launch_bounds__(256) void len_k(const float* __restrict__ mask,
                                             float* __restrict__ out)
{
    int b = blockIdx.x;
    int t = threadIdx.x;
    const float4 v = reinterpret_cast<const float4*>(mask + b * L_SEQ)[t];
    __shared__ float red[256];
    red[t] = v.x + v.y + v.z + v.w;
    __syncthreads();
    for (int s = 128; s > 0; s >>= 1) {
        if (t < s) red[t] += red[t + s];
        __syncthreads();
    }
    if (t == 0) out[b] = red[0];
}

// ------------------------------- launcher ----------------------------------
extern "C" void kernel_launch(void* const* d_in, const int* in_sizes, int n_in,
                              void* d_out, int out_size, void* d_ws, size_t ws_size,
                              hipStream_t stream)
{
    const float* x      = (const float*)d_in[0];
    const float* mask   = (const float*)d_in[1];
    const float* conv_w = (const float*)d_in[2];
    const float* conv_b = (const float*)d_in[3];
    const float* w_in   = (const float*)d_in[4];
    const float* b_in   = (const float*)d_in[5];
    const float* w_out  = (const float*)d_in[6];
    const float* b_out  = (const float*)d_in[7];
    const float* w_ff1  = (const float*)d_in[8];
    const float* b_ff1  = (const float*)d_in[9];
    const float* w_ff2  = (const float*)d_in[10];
    const float* b_ff2  = (const float*)d_in[11];
    const float* ln1_g  = (const float*)d_in[12];
    const float* ln1_b  = (const float*)d_in[13];
    const float* ln2_g  = (const float*)d_in[14];
    const float* ln2_b  = (const float*)d_in[15];
    const float* w_lin  = (const float*)d_in[16];
    float* out = (float*)d_out;

    float* ws    = (float*)d_ws;
    float* h     = ws;
    u16*   qb    = (u16*)(ws + 4194304L);
    u16*   kb    = qb + 4194304L;
    u16*   vb    = qb + 8388608L;
    u16*   vt    = qb + 12582912L;
    float* t0    = ws + 16777216L;
    float* t1    = ws + 20971520L;
    float* t2    = ws + 25165824L;
    u16*   hbf   = (u16*)t2;                 // free until FF1
    float* norms = ws + 29360128L;
    float* rsum  = ws + 29425664L;
    float* mnmx  = ws + 29458432L;
    u16*   Db    = (u16*)(ws + 29458496L);   // skewed D/R bf16
    u16*   Sb    = (u16*)(ws + 46235712L);   // scores -> P bf16, std layout

    conv_k<<<dim3(32, 128), 128, 0, stream>>>(x, conv_w, conv_b, mask, h, hbf);
    norm_k<<<32768, 128, 0, stream>>>(h, norms);
    mgemm_k<G_D2><<<dim3(16, 16, 32), 256, 0, stream>>>(
        hbf, hbf, Db, norms, nullptr, nullptr, nullptr);
    dtw_k<<<32, 512, 0, stream>>>(Db, mnmx);
    gemm_k<M_QKVB><<<dim3(512, 6, 1), 256, 0, stream>>>(
        h, w_in, qb, 32768, 384, 128, 128, 128, 0, b_in, nullptr);
    transpose_v<<<dim3(16, 2, 32), 256, 0, stream>>>(vb, vt);
    mgemm_k<G_SC><<<dim3(16, 16, 32), 256, 0, stream>>>(
        qb, kb, Sb, mnmx, mask, Db, nullptr);
    smax_k<<<32768, 256, 0, stream>>>(Sb, rsum);
    mgemm_k<G_AV><<<dim3(16, 2, 32), 256, 0, stream>>>(
        Sb, vt, t0, nullptr, nullptr, nullptr, rsum);
    gemm_k<M_WOUT><<<dim3(512, 2, 1), 256, 0, stream>>>(
        t0, w_out, t1, 32768, 128, 128, 128, 128, 128, b_out, h);
    ln_k<<<32768, 128, 0, stream>>>(t1, ln1_g, ln1_b);
    gemm_k<M_FF1><<<dim3(512, 2, 1), 256, 0, stream>>>(
        t1, w_ff1, t2, 32768, 128, 128, 128, 128, 128, b_ff1, nullptr);
    gemm_k<M_FF2><<<dim3(512, 2, 1), 256, 0, stream>>>(
        t2, w_ff2, t0, 32768, 128, 128, 128, 128, 128, b_ff2, t1);
    ln_k<<<32768, 128, 0, stream>>>(t0, ln2_g, ln2_b);
    gemm_k<M_LIN><<<dim3(512, 1, 1), 256, 0, stream>>>(
        t0, w_lin, out, 32768, 16, 128, 128, 128, 16, mask, nullptr);
    len_k<<<32, 256, 0, stream>>>(mask, out + 32768L * 16);
}

// Round 8
// 1434.926 us; speedup vs baseline: 1.9495x; 1.0337x over previous
//
#include <hip/hip_runtime.h>
#include <math.h>

// ---------------------------------------------------------------------------
// DsDTW pipeline (round 8): dtw chain trim — single-shfl carry trick (upp =
// previous step's upc) + 8-step-deep D prefetch. MFMA GEMMs as round 7.
// B=32, C_IN=12, T=4095, D=128, L=1024, GAMMA=5.
//
// ws layout (float offsets):
//   h      @ 0          4,194,304   [32,1024,128] fp32
//   qkvb   @ 4194304    qb/kb/vb/vt bf16, 4x 4,194,304 ushorts (8.4M floats)
//   t0     @ 16777216   4,194,304
//   t1     @ 20971520   4,194,304
//   t2     @ 25165824   4,194,304   (first half doubles as hbf bf16 pre-FF1)
//   norms  @ 29360128      32,768
//   rsum   @ 29425664      32,768
//   mnmx   @ 29458432          64
//   Db/Rb  @ 29458496  (bf16) skewed D -> R in place
//   Sb     @ 46235712  (bf16) scores -> P (exp'd in smax_k), standard layout
// ---------------------------------------------------------------------------

#define L_SEQ 1024
#define DM 128
#define INF_F __builtin_inff()

typedef short s16x8 __attribute__((ext_vector_type(8)));
typedef float f32x4 __attribute__((ext_vector_type(4)));
typedef unsigned short u16;

__device__ __forceinline__ float b2f(u16 u) {
    return __uint_as_float(((unsigned)u) << 16);
}
__device__ __forceinline__ u16 f2b(float f) {  // RNE
    unsigned u = __float_as_uint(f);
    return (u16)((u + 0x7FFFu + ((u >> 16) & 1u)) >> 16);
}
__device__ __forceinline__ u16 f2bt(float f) {  // truncate (cheap)
    return (u16)(__float_as_uint(f) >> 16);
}

// ------------------------- conv + pool + relu + mask -----------------------
__global__ __launch_bounds__(128) void conv_k(
    const float* __restrict__ x, const float* __restrict__ w,
    const float* __restrict__ cb, const float* __restrict__ mask,
    float* __restrict__ h, u16* __restrict__ hbf)
{
    int b = blockIdx.x;
    int l0 = blockIdx.y * 8;
    int d = threadIdx.x;
    __shared__ float xs[12][36];
    for (int v = d; v < 12 * 35; v += 128) {
        int c = v / 35, off = v % 35;
        int gi = 4 * l0 - 2 + off;
        xs[c][off] = (gi >= 0 && gi < 4095) ? x[((long)b * 12 + c) * 4095 + gi] : 0.f;
    }
    __syncthreads();
    float s[8];
#pragma unroll
    for (int l = 0; l < 8; ++l) s[l] = 0.f;
    for (int c = 0; c < 12; ++c) {
        const float* wp = w + (d * 12 + c) * 4;
        float w0 = wp[0], w1 = wp[1], w2 = wp[2], w3 = wp[3];
        float e0 = w0, e1 = w0 + w1, e2 = w0 + w1 + w2, e3 = w0 + w1 + w2 + w3;
        float e4 = w1 + w2 + w3, e5 = w2 + w3, e6 = w3;
#pragma unroll
        for (int l = 0; l < 8; ++l) {
            int ba = 4 * l;
            s[l] += xs[c][ba] * e0 + xs[c][ba + 1] * e1 + xs[c][ba + 2] * e2 +
                    xs[c][ba + 3] * e3 + xs[c][ba + 4] * e4 + xs[c][ba + 5] * e5 +
                    xs[c][ba + 6] * e6;
        }
    }
    float cbd = cb[d];
#pragma unroll
    for (int l = 0; l < 8; ++l) {
        int gl = l0 + l;
        float val = fmaxf(cbd + 0.25f * s[l], 0.f) * mask[b * L_SEQ + gl];
        long idx = ((long)(b * L_SEQ + gl)) * DM + d;
        h[idx] = val;
        hbf[idx] = f2b(val);
    }
}

// ------------------------------- row norms ---------------------------------
__global__ __launch_bounds__(128) void norm_k(const float* __restrict__ h,
                                              float* __restrict__ norms)
{
    long row = blockIdx.x;
    int d = threadIdx.x;
    float v = h[row * DM + d];
    __shared__ float red[128];
    red[d] = v * v;
    __syncthreads();
    for (int s = 64; s > 0; s >>= 1) {
        if (d < s) red[d] += red[d + s];
        __syncthreads();
    }
    if (d == 0) norms[row] = red[0];
}

// --------------------------- MFMA bf16 GEMMs -------------------------------
enum MGMode { G_D2, G_SC, G_AV };

template <int MODE>
__global__ __launch_bounds__(256) void mgemm_k(
    const u16* __restrict__ A0, const u16* __restrict__ B0, void* __restrict__ C0,
    const float* __restrict__ e0, const float* __restrict__ e1,
    const u16* __restrict__ R0, const float* __restrict__ rsum)
{
    constexpr int LDK = (MODE == G_AV) ? 1024 : 128;   // K == LDK
    constexpr int KK = LDK / 32;
    const int z = blockIdx.z;
    const u16* A = A0 + (MODE == G_D2 ? 0L
                                      : (long)z * (MODE == G_AV ? 1048576L : 131072L));
    const u16* B = B0 + (long)z * 131072L;
    const int tid = threadIdx.x, wv = tid >> 6, lane = tid & 63;
    const int m0 = blockIdx.x * 64, n0 = blockIdx.y * 64;
    const int co = lane & 15;
    const int q8 = (lane >> 4) << 3;
    const int mrow = m0 + 16 * wv + co;

    f32x4 acc[4];
#pragma unroll
    for (int tn = 0; tn < 4; ++tn) acc[tn] = 0.f;

    for (int kk = 0; kk < KK; ++kk) {
        const int k0 = kk * 32 + q8;
        const s16x8 a = *reinterpret_cast<const s16x8*>(A + (long)mrow * LDK + k0);
#pragma unroll
        for (int tn = 0; tn < 4; ++tn) {
            const s16x8 b = *reinterpret_cast<const s16x8*>(
                B + (long)(n0 + 16 * tn + co) * LDK + k0);
            acc[tn] = __builtin_amdgcn_mfma_f32_16x16x32_bf16(a, b, acc[tn], 0, 0, 0);
        }
    }

    const int li0 = 16 * wv + ((lane >> 4) << 2);   // local row base (+reg)

    if (MODE == G_D2) {
        __shared__ float Cs[64][66];
        float ni[4];
#pragma unroll
        for (int r = 0; r < 4; ++r) ni[r] = e0[m0 + li0 + r];
#pragma unroll
        for (int tn = 0; tn < 4; ++tn) {
            float nj = e0[(long)z * L_SEQ + n0 + 16 * tn + co];
#pragma unroll
            for (int r = 0; r < 4; ++r)
                Cs[li0 + r][16 * tn + co] = ni[r] + nj - 2.f * acc[tn][r];
        }
        __syncthreads();
        u16* Cu = (u16*)C0 + (long)z * 1048576L;
        int ln = lane;
        for (int q = 0; q < 32; ++q) {
            int dd = wv * 32 + q;
            if (dd < 127) {
                int d = m0 + n0 + dd;
                int ilo = max(m0, d - n0 - 63);
                int ihi = min(m0 + 63, d - n0);
                int i = ilo + ln;
                if (i <= ihi)
                    Cu[(long)(((d & 1023) << 10) + i)] = f2b(Cs[i - m0][d - n0 - i]);
            }
        }
        return;
    }
    if (MODE == G_SC) {
        __shared__ float Rs[64][66];
        const u16* Rz = R0 + (long)z * 1048576L;
        int ln = lane;
        for (int q = 0; q < 32; ++q) {
            int dd = wv * 32 + q;
            if (dd < 127) {
                int d = m0 + n0 + dd;
                int ilo = max(m0, d - n0 - 63);
                int ihi = min(m0 + 63, d - n0);
                int i = ilo + ln;
                if (i <= ihi)
                    Rs[i - m0][d - n0 - i] = b2f(Rz[(long)(((d & 1023) << 10) + i)]);
            }
        }
        __syncthreads();
        float mn = e0[2 * z];
        float inv = 1.f / (e0[2 * z + 1] - mn);
        u16* Cu = (u16*)C0 + (long)z * 1048576L;
#pragma unroll
        for (int tn = 0; tn < 4; ++tn) {
            int gj = n0 + 16 * tn + co;
            float kp = (e1[(long)z * L_SEQ + gj] > 0.f) ? 0.f : -INF_F;
#pragma unroll
            for (int r = 0; r < 4; ++r) {
                float val = acc[tn][r] * 0.08838834764831845f +
                            (Rs[li0 + r][16 * tn + co] - mn) * inv + 1.f + kp;
                Cu[(long)(m0 + li0 + r) * 1024 + gj] = f2b(val);
            }
        }
        return;
    }
    // G_AV: out = (P . V) * rsuminv[row], fp32
    {
        float* Cf = (float*)C0 + (long)z * 131072L;
        float rsv[4];
#pragma unroll
        for (int r = 0; r < 4; ++r) rsv[r] = rsum[(long)z * L_SEQ + m0 + li0 + r];
#pragma unroll
        for (int tn = 0; tn < 4; ++tn)
#pragma unroll
            for (int r = 0; r < 4; ++r)
                Cf[(long)(m0 + li0 + r) * 128 + n0 + 16 * tn + co] =
                    acc[tn][r] * rsv[r];
    }
}

// --------------------------- V transpose (bf16) ----------------------------
__global__ __launch_bounds__(256) void transpose_v(const u16* __restrict__ vb,
                                                   u16* __restrict__ vt)
{
    const int z = blockIdx.z;
    const int l0 = blockIdx.x * 64, d0 = blockIdx.y * 64;
    const u16* src = vb + (long)z * 131072L;
    u16* dst = vt + (long)z * 131072L;
    __shared__ u16 T[64][65];
    int tid = threadIdx.x;
#pragma unroll
    for (int i = 0; i < 16; ++i) {
        int idx = tid + 256 * i;
        int li = idx >> 6, dj = idx & 63;
        T[dj][li] = src[(long)(l0 + li) * 128 + d0 + dj];
    }
    __syncthreads();
#pragma unroll
    for (int i = 0; i < 16; ++i) {
        int idx = tid + 256 * i;
        int dj = idx >> 6, li = idx & 63;
        dst[(long)(d0 + dj) * 1024 + l0 + li] = T[dj][li];
    }
}

// ------------------------------ fp32 GEMMs ---------------------------------
enum GMode { M_QKVB, M_WOUT, M_FF1, M_FF2, M_LIN };

template <int MODE>
__global__ __launch_bounds__(256) void gemm_k(
    const float* __restrict__ A, const float* __restrict__ B, void* __restrict__ Cv,
    int M, int N, int K, int lda, int ldb, int ldc,
    const float* __restrict__ e0, const float* __restrict__ e1)
{
    __shared__ float As[16][65];
    __shared__ float Bs[16][65];
    int tid = threadIdx.x;
    int tx = tid & 15, ty = tid >> 4;
    int m0 = blockIdx.x * 64, n0 = blockIdx.y * 64;
    float acc[4][4] = {};
    int am = tid >> 2;
    int ak = (tid & 3) << 2;

    for (int kk = 0; kk < K; kk += 16) {
        {
            const float4 av =
                *reinterpret_cast<const float4*>(A + (long)(m0 + am) * lda + kk + ak);
            As[ak + 0][am] = av.x;
            As[ak + 1][am] = av.y;
            As[ak + 2][am] = av.z;
            As[ak + 3][am] = av.w;
        }
        {
            int n = n0 + am;
            float4 bv = {0.f, 0.f, 0.f, 0.f};
            if (n < N)
                bv = *reinterpret_cast<const float4*>(B + (long)n * ldb + kk + ak);
            Bs[ak + 0][am] = bv.x;
            Bs[ak + 1][am] = bv.y;
            Bs[ak + 2][am] = bv.z;
            Bs[ak + 3][am] = bv.w;
        }
        __syncthreads();
#pragma unroll
        for (int kc = 0; kc < 16; ++kc) {
            float a0 = As[kc][ty * 4 + 0], a1 = As[kc][ty * 4 + 1];
            float a2 = As[kc][ty * 4 + 2], a3 = As[kc][ty * 4 + 3];
            float b0 = Bs[kc][tx * 4 + 0], b1 = Bs[kc][tx * 4 + 1];
            float b2 = Bs[kc][tx * 4 + 2], b3 = Bs[kc][tx * 4 + 3];
            acc[0][0] += a0 * b0; acc[0][1] += a0 * b1; acc[0][2] += a0 * b2; acc[0][3] += a0 * b3;
            acc[1][0] += a1 * b0; acc[1][1] += a1 * b1; acc[1][2] += a1 * b2; acc[1][3] += a1 * b3;
            acc[2][0] += a2 * b0; acc[2][1] += a2 * b1; acc[2][2] += a2 * b2; acc[2][3] += a2 * b3;
            acc[3][0] += a3 * b0; acc[3][1] += a3 * b1; acc[3][2] += a3 * b2; acc[3][3] += a3 * b3;
        }
        __syncthreads();
    }

    if (MODE == M_QKVB) {
        u16* Cu = (u16*)Cv + ((long)(n0 >> 7)) * 4194304L;
        int cb = (n0 & 127) + tx * 4;
#pragma unroll
        for (int i = 0; i < 4; ++i) {
            int gi = m0 + ty * 4 + i;
            ushort4 sv;
            u16* svp = &sv.x;
#pragma unroll
            for (int j = 0; j < 4; ++j)
                svp[j] = f2b(acc[i][j] + e0[n0 + tx * 4 + j]);
            *reinterpret_cast<ushort4*>(Cu + (long)gi * 128 + cb) = sv;
        }
        return;
    }
    float* C = (float*)Cv;
#pragma unroll
    for (int i = 0; i < 4; ++i) {
        int gi = m0 + ty * 4 + i;
#pragma unroll
        for (int j = 0; j < 4; ++j) {
            int gj = n0 + tx * 4 + j;
            float v = acc[i][j];
            long idx = (long)gi * ldc + gj;
            if (MODE == M_WOUT) {
                C[idx] = v + e0[gj] + e1[idx];
            } else if (MODE == M_FF1) {
                C[idx] = fmaxf(v + e0[gj], 0.f);
            } else if (MODE == M_FF2) {
                C[idx] = v + e0[gj] + e1[idx];
            } else if (MODE == M_LIN) {
                if (gj < N) C[idx] = v * e0[gi];
            }
        }
    }
}

// ------------------------------- soft-DTW ----------------------------------
// 8 waves x 64 lanes x 2 rows/lane (verified schedule, rounds 5/7). Round 8:
// (1) carry trick: upp(s) = upc(s-1), so ONE shfl per step instead of two;
// (2) 8-step-deep D prefetch (dbuf[8][2]) to cover ~900cy HBM-miss latency.
__device__ __forceinline__ float softmin3(float d, float rl, float ru, float rul)
{
    float mn = fminf(rul, fminf(ru, rl));
    float md = fmaxf(fminf(rul, ru), fminf(fmaxf(rul, ru), rl));  // med3
    float mx = fmaxf(rul, fmaxf(ru, rl));
    float s = 1.f + __expf((mn - md) * 0.2f) + __expf((mn - mx) * 0.2f);
    return d + mn - 5.0f * __logf(s);
}

template <bool EDGE>
__device__ __forceinline__ void dtw_chunk(
    u16* __restrict__ R, const float* __restrict__ botp, float* __restrict__ botw,
    int w, int lane, bool lane0, int off0, int T0,
    float& cur0, float& cur1, float& prev0, float& prev1,
    float& upc, float& upp,
    float& vmin, float& vmax, float (&dbuf)[8][2], float (&bb)[9])
{
    u16* rp = R + (((T0 & 1023) << 10) + off0);
    for (int g = 0; g < 16; ++g) {
        const int tg = T0 + (g << 3);
        float dn[8][2];
#pragma unroll
        for (int s = 0; s < 8; ++s) {  // prefetch next group's D/R inputs
            const ushort2 dv = *reinterpret_cast<const ushort2*>(
                R + ((((tg + 8 + s) & 1023) << 10) + off0));
            dn[s][0] = b2f(dv.x);
            dn[s][1] = b2f(dv.y);
        }
        float bn[9];
        if (w > 0 && g < 15) {  // prefetch next group's bot-ring columns
            const int jn = tg + 7 - (w << 7);
#pragma unroll
            for (int q = 0; q < 9; ++q) bn[q] = botp[(jn + q) & 511];
        }
#pragma unroll
        for (int s = 0; s < 8; ++s) {
            const int j0 = tg + s - off0;
            float ru0 = upc, rul0 = upp;
            if (lane0) {
                if (w == 0) {
                    ru0 = INF_F;
                    rul0 = (EDGE && j0 == 0) ? 0.f : INF_F;
                } else {
                    ru0 = bb[s + 1];
                    if (EDGE && j0 < 1) rul0 = INF_F;
                    // else rul0 = carried upp == bot column j0-1
                }
            }
            float n0v = softmin3(dbuf[s][0], cur0, ru0, rul0);
            float n1v = softmin3(dbuf[s][1], cur1, cur0, prev0);
            if (EDGE) {
                bool v0 = ((unsigned)j0 < 1024u);
                bool v1 = ((unsigned)(j0 - 1) < 1024u);
                n0v = v0 ? n0v : INF_F;
                n1v = v1 ? n1v : INF_F;
                vmin = fminf(vmin, fminf(n0v, n1v));
                vmax = v0 ? fmaxf(vmax, n0v) : vmax;
                vmax = v1 ? fmaxf(vmax, n1v) : vmax;
                if (j0 >= 1 && j0 <= 1023) {
                    ushort2 sv;
                    sv.x = f2bt(n0v);
                    sv.y = f2bt(n1v);
                    *reinterpret_cast<ushort2*>(rp) = sv;
                } else {
                    if (v0) rp[0] = f2bt(n0v);
                    if (v1) rp[1] = f2bt(n1v);
                }
                if (w < 7 && lane == 63 && v1) botw[(j0 - 1) & 511] = n1v;
            } else {
                vmin = fminf(vmin, fminf(n0v, n1v));
                vmax = fmaxf(vmax, fmaxf(n0v, n1v));
                ushort2 sv;
                sv.x = f2bt(n0v);
                sv.y = f2bt(n1v);
                *reinterpret_cast<ushort2*>(rp) = sv;
                if (w < 7 && lane == 63) botw[(j0 - 1) & 511] = n1v;
            }
            prev0 = cur0; prev1 = cur1;
            cur0 = n0v; cur1 = n1v;
            upp = ru0;                    // carry: next step's rul
            upc = __shfl_up(n1v, 1);      // single shfl per step
            rp += 1024;
        }
#pragma unroll
        for (int s = 0; s < 8; ++s) { dbuf[s][0] = dn[s][0]; dbuf[s][1] = dn[s][1]; }
        if (w > 0 && g < 15) {
#pragma unroll
            for (int q = 0; q < 9; ++q) bb[q] = bn[q];
        }
    }
}

__global__ __launch_bounds__(512) void dtw_k(u16* __restrict__ Rb,
                                             float* __restrict__ minmax)
{
    const int b = blockIdx.x;
    u16* R = Rb + (long)b * (1024L * 1024L);
    const int tid = threadIdx.x;
    const int w = tid >> 6;
    const int lane = tid & 63;
    const bool lane0 = (lane == 0);
    const int off0 = (w << 7) + (lane << 1);

    __shared__ float bot[7][512];
    __shared__ float rmn[512];
    __shared__ float rmx[512];

    float* botw = (w < 7) ? bot[w] : bot[0];
    const float* botp = (w > 0) ? bot[w - 1] : bot[0];

    float cur0 = INF_F, cur1 = INF_F;
    float prev0 = INF_F, prev1 = INF_F;
    float upc = INF_F, upp = INF_F;
    float vmin = INF_F, vmax = -INF_F;
    float dbuf[8][2];
    float bb[9];
#pragma unroll
    for (int q = 0; q < 9; ++q) bb[q] = 0.f;

    for (int e = 0; e < 23; ++e) {
        const int c = e - w;
        if (c >= w && c <= w + 8) {
            const int T0 = c << 7;
            if (c == w) {   // prime D queue (8 steps)
#pragma unroll
                for (int s = 0; s < 8; ++s) {
                    const ushort2 dv = *reinterpret_cast<const ushort2*>(
                        R + ((((T0 + s) & 1023) << 10) + off0));
                    dbuf[s][0] = b2f(dv.x);
                    dbuf[s][1] = b2f(dv.y);
                }
            }
            if (w > 0) {    // bot columns for the chunk's first group
                const int jb = T0 - (w << 7) - 1;
#pragma unroll
                for (int q = 0; q < 9; ++q) bb[q] = botp[(jb + q) & 511];
            }
            if (c == w || c == w + 8)
                dtw_chunk<true>(R, botp, botw, w, lane, lane0, off0, T0,
                                cur0, cur1, prev0, prev1, upc, upp,
                                vmin, vmax, dbuf, bb);
            else
                dtw_chunk<false>(R, botp, botw, w, lane, lane0, off0, T0,
                                 cur0, cur1, prev0, prev1, upc, upp,
                                 vmin, vmax, dbuf, bb);
        }
        __syncthreads();
    }

    rmn[tid] = vmin;
    rmx[tid] = vmax;
    __syncthreads();
    for (int s2 = 256; s2 > 0; s2 >>= 1) {
        if (tid < s2) {
            rmn[tid] = fminf(rmn[tid], rmn[tid + s2]);
            rmx[tid] = fmaxf(rmx[tid], rmx[tid + s2]);
        }
        __syncthreads();
    }
    if (tid == 0) {
        minmax[2 * b] = rmn[0];
        minmax[2 * b + 1] = rmx[0];
    }
}

// ---------------- softmax row stats + in-place P = exp(s-max) --------------
__global__ __launch_bounds__(256) void smax_k(u16* __restrict__ S,
                                              float* __restrict__ rsuminv)
{
    long row = blockIdx.x;
    u16* rowp = S + row * L_SEQ;
    const ushort4 v4 = reinterpret_cast<const ushort4*>(rowp)[threadIdx.x];
    float a = b2f(v4.x), b = b2f(v4.y), c = b2f(v4.z), d = b2f(v4.w);
    int t = threadIdx.x;
    __shared__ float red[256];
    red[t] = fmaxf(fmaxf(a, b), fmaxf(c, d));
    __syncthreads();
    for (int s = 128; s > 0; s >>= 1) {
        if (t < s) red[t] = fmaxf(red[t], red[t + s]);
        __syncthreads();
    }
    float mx = red[0];
    __syncthreads();
    float ea = __expf(a - mx), eb = __expf(b - mx);
    float ec = __expf(c - mx), ed = __expf(d - mx);
    ushort4 pv;
    pv.x = f2b(ea); pv.y = f2b(eb); pv.z = f2b(ec); pv.w = f2b(ed);
    reinterpret_cast<ushort4*>(rowp)[t] = pv;
    red[t] = ea + eb + ec + ed;
    __syncthreads();
    for (int s = 128; s > 0; s >>= 1) {
        if (t < s) red[t] += red[t + s];
        __syncthreads();
    }
    if (t == 0) rsuminv[row] = 1.f / red[0];
}

// ------------------------------- layernorm ---------------------------------
__global__ __launch_bounds__(128) void ln_k(float* __restrict__ X,
                                            const float* __restrict__ g,
                                            const float* __restrict__ b)
{
    long row = blockIdx.x;
    int d = threadIdx.x;
    float x = X[row * DM + d];
    __shared__ float s1[128];
    __shared__ float s2[128];
    s1[d] = x;
    s2[d] = x * x;
    __syncthreads();
    for (int s = 64; s > 0; s >>= 1) {
        if (d < s) { s1[d] += s1[d + s]; s2[d] += s2[d + s]; }
        __syncthreads();
    }
    float mean = s1[0] * (1.f / 128.f);
    float var = s2[0] * (1.f / 128.f) - mean * mean;
    X[row * DM + d] = (x - mean) * rsqrtf(var + 1e-5f) * g[d] + b[d];
}

// -------------------------------- lengths ----------------------------------
__global__ __launch_bounds__(256) void len_k(const float* __restrict__ mask,
                                             float* __restrict__ out)
{
    int b = blockIdx.x;
    int t = threadIdx.x;
    const float4 v = reinterpret_cast<const float4*>(mask + b * L_SEQ)[t];
    __shared__ float red[256];
    red[t] = v.x + v.y + v.z + v.w;
    __syncthreads();
    for (int s = 128; s > 0; s >>= 1) {
        if (t < s) red[t] += red[t + s];
        __syncthreads();
    }
    if (t == 0) out[b] = red[0];
}

// ------------------------------- launcher ----------------------------------
extern "C" void kernel_launch(void* const* d_in, const int* in_sizes, int n_in,
                              void* d_out, int out_size, void* d_ws, size_t ws_size,
                              hipStream_t stream)
{
    const float* x      = (const float*)d_in[0];
    const float* mask   = (const float*)d_in[1];
    const float* conv_w = (const float*)d_in[2];
    const float* conv_b = (const float*)d_in[3];
    const float* w_in   = (const float*)d_in[4];
    const float* b_in   = (const float*)d_in[5];
    const float* w_out  = (const float*)d_in[6];
    const float* b_out  = (const float*)d_in[7];
    const float* w_ff1  = (const float*)d_in[8];
    const float* b_ff1  = (const float*)d_in[9];
    const float* w_ff2  = (const float*)d_in[10];
    const float* b_ff2  = (const float*)d_in[11];
    const float* ln1_g  = (const float*)d_in[12];
    const float* ln1_b  = (const float*)d_in[13];
    const float* ln2_g  = (const float*)d_in[14];
    const float* ln2_b  = (const float*)d_in[15];
    const float* w_lin  = (const float*)d_in[16];
    float* out = (float*)d_out;

    float* ws    = (float*)d_ws;
    float* h     = ws;
    u16*   qb    = (u16*)(ws + 4194304L);
    u16*   kb    = qb + 4194304L;
    u16*   vb    = qb + 8388608L;
    u16*   vt    = qb + 12582912L;
    float* t0    = ws + 16777216L;
    float* t1    = ws + 20971520L;
    float* t2    = ws + 25165824L;
    u16*   hbf   = (u16*)t2;                 // free until FF1
    float* norms = ws + 29360128L;
    float* rsum  = ws + 29425664L;
    float* mnmx  = ws + 29458432L;
    u16*   Db    = (u16*)(ws + 29458496L);   // skewed D/R bf16
    u16*   Sb    = (u16*)(ws + 46235712L);   // scores -> P bf16, std layout

    conv_k<<<dim3(32, 128), 128, 0, stream>>>(x, conv_w, conv_b, mask, h, hbf);
    norm_k<<<32768, 128, 0, stream>>>(h, norms);
    mgemm_k<G_D2><<<dim3(16, 16, 32), 256, 0, stream>>>(
        hbf, hbf, Db, norms, nullptr, nullptr, nullptr);
    dtw_k<<<32, 512, 0, stream>>>(Db, mnmx);
    gemm_k<M_QKVB><<<dim3(512, 6, 1), 256, 0, stream>>>(
        h, w_in, qb, 32768, 384, 128, 128, 128, 0, b_in, nullptr);
    transpose_v<<<dim3(16, 2, 32), 256, 0, stream>>>(vb, vt);
    mgemm_k<G_SC><<<dim3(16, 16, 32), 256, 0, stream>>>(
        qb, kb, Sb, mnmx, mask, Db, nullptr);
    smax_k<<<32768, 256, 0, stream>>>(Sb, rsum);
    mgemm_k<G_AV><<<dim3(16, 2, 32), 256, 0, stream>>>(
        Sb, vt, t0, nullptr, nullptr, nullptr, rsum);
    gemm_k<M_WOUT><<<dim3(512, 2, 1), 256, 0, stream>>>(
        t0, w_out, t1, 32768, 128, 128, 128, 128, 128, b_out, h);
    ln_k<<<32768, 128, 0, stream>>>(t1, ln1_g, ln1_b);
    gemm_k<M_FF1><<<dim3(512, 2, 1), 256, 0, stream>>>(
        t1, w_ff1, t2, 32768, 128, 128, 128, 128, 128, b_ff1, nullptr);
    gemm_k<M_FF2><<<dim3(512, 2, 1), 256, 0, stream>>>(
        t2, w_ff2, t0, 32768, 128, 128, 128, 128, 128, b_ff2, t1);
    ln_k<<<32768, 128, 0, stream>>>(t0, ln2_g, ln2_b);
    gemm_k<M_LIN><<<dim3(512, 1, 1), 256, 0, stream>>>(
        t0, w_lin, out, 32768, 16, 128, 128, 128, 16, mask, nullptr);
    len_k<<<32, 256, 0, stream>>>(mask, out + 32768L * 16);
}

// Round 9
// 1331.264 us; speedup vs baseline: 2.1013x; 1.0779x over previous
//
#include <hip/hip_runtime.h>
#include <math.h>

// ---------------------------------------------------------------------------
// DsDTW pipeline (round 9): dtw chunk 128->32 (pipeline fill/drain 2944->2272
// step-slots), QKV GEMM backfilled into the dtw dispatch (idle 224 CUs),
// transpose_v folded into SC launch, norms fused into conv, shfl LayerNorm.
// B=32, C_IN=12, T=4095, D=128, L=1024, GAMMA=5.
//
// ws layout (float offsets):
//   h      @ 0          4,194,304   [32,1024,128] fp32
//   qkvb   @ 4194304    qb/kb/vb/vt bf16, 4x 4,194,304 ushorts
//   t0     @ 16777216   4,194,304
//   t1     @ 20971520   4,194,304
//   t2     @ 25165824   4,194,304   (first half doubles as hbf bf16 pre-FF1)
//   norms  @ 29360128      32,768
//   rsum   @ 29425664      32,768
//   mnmx   @ 29458432          64
//   Db/Rb  @ 29458496  (bf16) skewed D -> R in place
//   Sb     @ 46235712  (bf16) scores -> P (exp'd in smax_k), standard layout
// ---------------------------------------------------------------------------

#define L_SEQ 1024
#define DM 128
#define INF_F __builtin_inff()

typedef short s16x8 __attribute__((ext_vector_type(8)));
typedef float f32x4 __attribute__((ext_vector_type(4)));
typedef unsigned short u16;

__device__ __forceinline__ float b2f(u16 u) {
    return __uint_as_float(((unsigned)u) << 16);
}
__device__ __forceinline__ u16 f2b(float f) {  // RNE
    unsigned u = __float_as_uint(f);
    return (u16)((u + 0x7FFFu + ((u >> 16) & 1u)) >> 16);
}
__device__ __forceinline__ u16 f2bt(float f) {  // truncate (cheap)
    return (u16)(__float_as_uint(f) >> 16);
}

// ---------------- conv + pool + relu + mask + row norms --------------------
__global__ __launch_bounds__(128) void conv_k(
    const float* __restrict__ x, const float* __restrict__ w,
    const float* __restrict__ cb, const float* __restrict__ mask,
    float* __restrict__ h, u16* __restrict__ hbf, float* __restrict__ norms)
{
    int b = blockIdx.x;
    int l0 = blockIdx.y * 8;
    int d = threadIdx.x;
    __shared__ float xs[12][36];
    __shared__ float red2[8][2];
    for (int v = d; v < 12 * 35; v += 128) {
        int c = v / 35, off = v % 35;
        int gi = 4 * l0 - 2 + off;
        xs[c][off] = (gi >= 0 && gi < 4095) ? x[((long)b * 12 + c) * 4095 + gi] : 0.f;
    }
    __syncthreads();
    float s[8];
#pragma unroll
    for (int l = 0; l < 8; ++l) s[l] = 0.f;
    for (int c = 0; c < 12; ++c) {
        const float* wp = w + (d * 12 + c) * 4;
        float w0 = wp[0], w1 = wp[1], w2 = wp[2], w3 = wp[3];
        float e0 = w0, e1 = w0 + w1, e2 = w0 + w1 + w2, e3 = w0 + w1 + w2 + w3;
        float e4 = w1 + w2 + w3, e5 = w2 + w3, e6 = w3;
#pragma unroll
        for (int l = 0; l < 8; ++l) {
            int ba = 4 * l;
            s[l] += xs[c][ba] * e0 + xs[c][ba + 1] * e1 + xs[c][ba + 2] * e2 +
                    xs[c][ba + 3] * e3 + xs[c][ba + 4] * e4 + xs[c][ba + 5] * e5 +
                    xs[c][ba + 6] * e6;
        }
    }
    float cbd = cb[d];
#pragma unroll
    for (int l = 0; l < 8; ++l) {
        int gl = l0 + l;
        float val = fmaxf(cbd + 0.25f * s[l], 0.f) * mask[b * L_SEQ + gl];
        long idx = ((long)(b * L_SEQ + gl)) * DM + d;
        h[idx] = val;
        hbf[idx] = f2b(val);
        float vsq = val * val;   // row-norm reduction (fused norm_k)
#pragma unroll
        for (int m = 1; m < 64; m <<= 1) vsq += __shfl_xor(vsq, m);
        if ((d & 63) == 0) red2[l][d >> 6] = vsq;
    }
    __syncthreads();
    if (d < 8) norms[(long)b * L_SEQ + l0 + d] = red2[d][0] + red2[d][1];
}

// --------------------------- MFMA bf16 GEMMs -------------------------------
// C = A.B^T, A/B row-major [rows,K] bf16; mfma_f32_16x16x32_bf16 layouts per §3.
enum MGMode { G_D2, G_AV };

template <int MODE>
__global__ __launch_bounds__(256) void mgemm_k(
    const u16* __restrict__ A0, const u16* __restrict__ B0, void* __restrict__ C0,
    const float* __restrict__ e0, const float* __restrict__ rsum)
{
    constexpr int LDK = (MODE == G_AV) ? 1024 : 128;
    constexpr int KK = LDK / 32;
    const int z = blockIdx.z;
    const u16* A = A0 + (MODE == G_D2 ? 0L : (long)z * 1048576L);
    const u16* B = B0 + (long)z * 131072L;
    const int tid = threadIdx.x, wv = tid >> 6, lane = tid & 63;
    const int m0 = blockIdx.x * 64, n0 = blockIdx.y * 64;
    const int co = lane & 15;
    const int q8 = (lane >> 4) << 3;
    const int mrow = m0 + 16 * wv + co;

    f32x4 acc[4];
#pragma unroll
    for (int tn = 0; tn < 4; ++tn) acc[tn] = 0.f;

    for (int kk = 0; kk < KK; ++kk) {
        const int k0 = kk * 32 + q8;
        const s16x8 a = *reinterpret_cast<const s16x8*>(A + (long)mrow * LDK + k0);
#pragma unroll
        for (int tn = 0; tn < 4; ++tn) {
            const s16x8 b = *reinterpret_cast<const s16x8*>(
                B + (long)(n0 + 16 * tn + co) * LDK + k0);
            acc[tn] = __builtin_amdgcn_mfma_f32_16x16x32_bf16(a, b, acc[tn], 0, 0, 0);
        }
    }

    const int li0 = 16 * wv + ((lane >> 4) << 2);

    if (MODE == G_D2) {
        __shared__ float Cs[64][66];
        float ni[4];
#pragma unroll
        for (int r = 0; r < 4; ++r) ni[r] = e0[m0 + li0 + r];
#pragma unroll
        for (int tn = 0; tn < 4; ++tn) {
            float nj = e0[(long)z * L_SEQ + n0 + 16 * tn + co];
#pragma unroll
            for (int r = 0; r < 4; ++r)
                Cs[li0 + r][16 * tn + co] = ni[r] + nj - 2.f * acc[tn][r];
        }
        __syncthreads();
        u16* Cu = (u16*)C0 + (long)z * 1048576L;
        for (int q = 0; q < 32; ++q) {
            int dd = wv * 32 + q;
            if (dd < 127) {
                int d = m0 + n0 + dd;
                int ilo = max(m0, d - n0 - 63);
                int ihi = min(m0 + 63, d - n0);
                int i = ilo + lane;
                if (i <= ihi)
                    Cu[(long)(((d & 1023) << 10) + i)] = f2b(Cs[i - m0][d - n0 - i]);
            }
        }
        return;
    }
    // G_AV: out = (P . V) * rsuminv[row], fp32
    {
        float* Cf = (float*)C0 + (long)z * 131072L;
        float rsv[4];
#pragma unroll
        for (int r = 0; r < 4; ++r) rsv[r] = rsum[(long)z * L_SEQ + m0 + li0 + r];
#pragma unroll
        for (int tn = 0; tn < 4; ++tn)
#pragma unroll
            for (int r = 0; r < 4; ++r)
                Cf[(long)(m0 + li0 + r) * 128 + n0 + 16 * tn + co] =
                    acc[tn][r] * rsv[r];
    }
}

// ---------------- SC (MFMA scores) + V-transpose, one launch ---------------
__global__ __launch_bounds__(256) void sc_tr_k(
    const u16* __restrict__ qb, const u16* __restrict__ kb, u16* __restrict__ Sb,
    const float* __restrict__ mnmx, const float* __restrict__ mask,
    const u16* __restrict__ Rb, const u16* __restrict__ vb, u16* __restrict__ vt)
{
    const int bid = blockIdx.x;
    const int tid = threadIdx.x;
    __shared__ float Rs[64][66];

    if (bid < 1024) {    // V transpose: vb [l,128] -> vt [d,1024]
        const int z = bid >> 5;
        const int l0 = (bid & 15) * 64, d0 = ((bid >> 4) & 1) * 64;
        const u16* src = vb + (long)z * 131072L;
        u16* dst = vt + (long)z * 131072L;
        u16* T = (u16*)Rs;   // reuse LDS, 64*65 u16 needed < 64*66*4 B
#pragma unroll
        for (int i = 0; i < 16; ++i) {
            int idx = tid + 256 * i;
            int li = idx >> 6, dj = idx & 63;
            T[dj * 65 + li] = src[(long)(l0 + li) * 128 + d0 + dj];
        }
        __syncthreads();
#pragma unroll
        for (int i = 0; i < 16; ++i) {
            int idx = tid + 256 * i;
            int dj = idx >> 6, li = idx & 63;
            dst[(long)(d0 + dj) * 1024 + l0 + li] = T[dj * 65 + li];
        }
        return;
    }
    // SC tile
    const int s = bid - 1024;
    const int z = s >> 8;
    const int m0 = (s & 15) * 64, n0 = ((s >> 4) & 15) * 64;
    const u16* A = qb + (long)z * 131072L;
    const u16* B = kb + (long)z * 131072L;
    const int wv = tid >> 6, lane = tid & 63;
    const int co = lane & 15;
    const int q8 = (lane >> 4) << 3;
    const int mrow = m0 + 16 * wv + co;

    f32x4 acc[4];
#pragma unroll
    for (int tn = 0; tn < 4; ++tn) acc[tn] = 0.f;
    for (int kk = 0; kk < 4; ++kk) {
        const int k0 = kk * 32 + q8;
        const s16x8 a = *reinterpret_cast<const s16x8*>(A + (long)mrow * 128 + k0);
#pragma unroll
        for (int tn = 0; tn < 4; ++tn) {
            const s16x8 b = *reinterpret_cast<const s16x8*>(
                B + (long)(n0 + 16 * tn + co) * 128 + k0);
            acc[tn] = __builtin_amdgcn_mfma_f32_16x16x32_bf16(a, b, acc[tn], 0, 0, 0);
        }
    }
    const int li0 = 16 * wv + ((lane >> 4) << 2);
    const u16* Rz = Rb + (long)z * 1048576L;
    for (int q = 0; q < 32; ++q) {   // destage skewed R -> LDS
        int dd = wv * 32 + q;
        if (dd < 127) {
            int d = m0 + n0 + dd;
            int ilo = max(m0, d - n0 - 63);
            int ihi = min(m0 + 63, d - n0);
            int i = ilo + lane;
            if (i <= ihi)
                Rs[i - m0][d - n0 - i] = b2f(Rz[(long)(((d & 1023) << 10) + i)]);
        }
    }
    __syncthreads();
    float mn = mnmx[2 * z];
    float inv = 1.f / (mnmx[2 * z + 1] - mn);
    u16* Cu = Sb + (long)z * 1048576L;
#pragma unroll
    for (int tn = 0; tn < 4; ++tn) {
        int gj = n0 + 16 * tn + co;
        float kp = (mask[(long)z * L_SEQ + gj] > 0.f) ? 0.f : -INF_F;
#pragma unroll
        for (int r = 0; r < 4; ++r) {
            float val = acc[tn][r] * 0.08838834764831845f +
                        (Rs[li0 + r][16 * tn + co] - mn) * inv + 1.f + kp;
            Cu[(long)(m0 + li0 + r) * 1024 + gj] = f2b(val);
        }
    }
}

// ------------------------------ fp32 GEMMs ---------------------------------
enum GMode { M_WOUT, M_FF1, M_FF2, M_LIN };

template <int MODE>
__global__ __launch_bounds__(256) void gemm_k(
    const float* __restrict__ A, const float* __restrict__ B, float* __restrict__ C,
    int N, int ldc,
    const float* __restrict__ e0, const float* __restrict__ e1)
{
    __shared__ float As[16][65];
    __shared__ float Bs[16][65];
    int tid = threadIdx.x;
    int tx = tid & 15, ty = tid >> 4;
    int m0 = blockIdx.x * 64, n0 = blockIdx.y * 64;
    float acc[4][4] = {};
    int am = tid >> 2;
    int ak = (tid & 3) << 2;

    for (int kk = 0; kk < 128; kk += 16) {
        {
            const float4 av =
                *reinterpret_cast<const float4*>(A + (long)(m0 + am) * 128 + kk + ak);
            As[ak + 0][am] = av.x;
            As[ak + 1][am] = av.y;
            As[ak + 2][am] = av.z;
            As[ak + 3][am] = av.w;
        }
        {
            int n = n0 + am;
            float4 bv = {0.f, 0.f, 0.f, 0.f};
            if (n < N)
                bv = *reinterpret_cast<const float4*>(B + (long)n * 128 + kk + ak);
            Bs[ak + 0][am] = bv.x;
            Bs[ak + 1][am] = bv.y;
            Bs[ak + 2][am] = bv.z;
            Bs[ak + 3][am] = bv.w;
        }
        __syncthreads();
#pragma unroll
        for (int kc = 0; kc < 16; ++kc) {
            float a0 = As[kc][ty * 4 + 0], a1 = As[kc][ty * 4 + 1];
            float a2 = As[kc][ty * 4 + 2], a3 = As[kc][ty * 4 + 3];
            float b0 = Bs[kc][tx * 4 + 0], b1 = Bs[kc][tx * 4 + 1];
            float b2 = Bs[kc][tx * 4 + 2], b3 = Bs[kc][tx * 4 + 3];
            acc[0][0] += a0 * b0; acc[0][1] += a0 * b1; acc[0][2] += a0 * b2; acc[0][3] += a0 * b3;
            acc[1][0] += a1 * b0; acc[1][1] += a1 * b1; acc[1][2] += a1 * b2; acc[1][3] += a1 * b3;
            acc[2][0] += a2 * b0; acc[2][1] += a2 * b1; acc[2][2] += a2 * b2; acc[2][3] += a2 * b3;
            acc[3][0] += a3 * b0; acc[3][1] += a3 * b1; acc[3][2] += a3 * b2; acc[3][3] += a3 * b3;
        }
        __syncthreads();
    }

#pragma unroll
    for (int i = 0; i < 4; ++i) {
        int gi = m0 + ty * 4 + i;
#pragma unroll
        for (int j = 0; j < 4; ++j) {
            int gj = n0 + tx * 4 + j;
            float v = acc[i][j];
            long idx = (long)gi * ldc + gj;
            if (MODE == M_WOUT) {
                C[idx] = v + e0[gj] + e1[idx];
            } else if (MODE == M_FF1) {
                C[idx] = fmaxf(v + e0[gj], 0.f);
            } else if (MODE == M_FF2) {
                C[idx] = v + e0[gj] + e1[idx];
            } else if (MODE == M_LIN) {
                if (gj < N) C[idx] = v * e0[gi];
            }
        }
    }
}

// ------------------------------- soft-DTW ----------------------------------
// 8 waves x 64 lanes x 2 rows/lane (schedule verified r5/r7/r8). Round 9:
// chunk 128 -> 32 steps: step-slots 2944 -> 2272 (pipeline fill/drain cut);
// QKV GEMM backfilled as blocks >= 32 of the same dispatch.
__device__ __forceinline__ float softmin3(float d, float rl, float ru, float rul)
{
    float mn = fminf(rul, fminf(ru, rl));
    float md = fmaxf(fminf(rul, ru), fminf(fmaxf(rul, ru), rl));  // med3
    float mx = fmaxf(rul, fmaxf(ru, rl));
    float s = 1.f + __expf((mn - md) * 0.2f) + __expf((mn - mx) * 0.2f);
    return d + mn - 5.0f * __logf(s);
}

template <bool EDGE>
__device__ __forceinline__ void dtw_chunk(
    u16* __restrict__ R, const float* __restrict__ botp, float* __restrict__ botw,
    int w, int lane, bool lane0, int off0, int T0,
    float& cur0, float& cur1, float& prev0, float& prev1,
    float& upc, float& upp,
    float& vmin, float& vmax, float (&dbuf)[8][2], float (&bb)[9])
{
    u16* rp = R + (((T0 & 1023) << 10) + off0);
    for (int g = 0; g < 4; ++g) {            // 4 groups of 8 steps = 32
        const int tg = T0 + (g << 3);
        float dn[8][2];
#pragma unroll
        for (int s = 0; s < 8; ++s) {        // prefetch next group's D/R inputs
            const ushort2 dv = *reinterpret_cast<const ushort2*>(
                R + ((((tg + 8 + s) & 1023) << 10) + off0));
            dn[s][0] = b2f(dv.x);
            dn[s][1] = b2f(dv.y);
        }
        float bn[9];
        if (w > 0 && g < 3) {                // prefetch next group's bot cols
            const int jn = tg + 7 - (w << 7);
#pragma unroll
            for (int q = 0; q < 9; ++q) bn[q] = botp[(jn + q) & 511];
        }
#pragma unroll
        for (int s = 0; s < 8; ++s) {
            const int j0 = tg + s - off0;
            float ru0 = upc, rul0 = upp;
            if (lane0) {
                if (w == 0) {
                    ru0 = INF_F;
                    rul0 = (EDGE && j0 == 0) ? 0.f : INF_F;
                } else {
                    ru0 = bb[s + 1];
                    if (EDGE && j0 < 1) rul0 = INF_F;
                }
            }
            float n0v = softmin3(dbuf[s][0], cur0, ru0, rul0);
            float n1v = softmin3(dbuf[s][1], cur1, cur0, prev0);
            if (EDGE) {
                bool v0 = ((unsigned)j0 < 1024u);
                bool v1 = ((unsigned)(j0 - 1) < 1024u);
                n0v = v0 ? n0v : INF_F;
                n1v = v1 ? n1v : INF_F;
                vmin = fminf(vmin, fminf(n0v, n1v));
                vmax = v0 ? fmaxf(vmax, n0v) : vmax;
                vmax = v1 ? fmaxf(vmax, n1v) : vmax;
                if (j0 >= 1 && j0 <= 1023) {
                    ushort2 sv;
                    sv.x = f2bt(n0v);
                    sv.y = f2bt(n1v);
                    *reinterpret_cast<ushort2*>(rp) = sv;
                } else {
                    if (v0) rp[0] = f2bt(n0v);
                    if (v1) rp[1] = f2bt(n1v);
                }
                if (w < 7 && lane == 63 && v1) botw[(j0 - 1) & 511] = n1v;
            } else {
                vmin = fminf(vmin, fminf(n0v, n1v));
                vmax = fmaxf(vmax, fmaxf(n0v, n1v));
                ushort2 sv;
                sv.x = f2bt(n0v);
                sv.y = f2bt(n1v);
                *reinterpret_cast<ushort2*>(rp) = sv;
                if (w < 7 && lane == 63) botw[(j0 - 1) & 511] = n1v;
            }
            prev0 = cur0; prev1 = cur1;
            cur0 = n0v; cur1 = n1v;
            upp = ru0;
            upc = __shfl_up(n1v, 1);
            rp += 1024;
        }
#pragma unroll
        for (int s = 0; s < 8; ++s) { dbuf[s][0] = dn[s][0]; dbuf[s][1] = dn[s][1]; }
        if (w > 0 && g < 3) {
#pragma unroll
            for (int q = 0; q < 9; ++q) bb[q] = bn[q];
        }
    }
}

// dtw (blocks 0..31) + QKV GEMM backfill (blocks 32..1567, two tiles/block)
__global__ __launch_bounds__(512) void dtw_qkv_k(
    u16* __restrict__ Rb, float* __restrict__ minmax,
    const float* __restrict__ h, const float* __restrict__ w_in,
    const float* __restrict__ b_in, u16* __restrict__ qb)
{
    __shared__ float bot[7][512];
    __shared__ float rmn[512];
    __shared__ float rmx[512];
    __shared__ float As[2][16][65];
    __shared__ float Bs[2][16][65];

    if (blockIdx.x >= 32) {
        // ---- QKV backfill: two 64x64 tiles (one per 256-thread half) ----
        const int half = threadIdx.x >> 8;
        const int tid = threadIdx.x & 255;
        const int t = ((blockIdx.x - 32) << 1) + half;   // 0..3071
        const int m0 = (t & 511) << 6;
        const int n0 = (t >> 9) << 6;
        int tx = tid & 15, ty = tid >> 4;
        float acc[4][4] = {};
        int am = tid >> 2;
        int ak = (tid & 3) << 2;
        for (int kk = 0; kk < 128; kk += 16) {
            {
                const float4 av = *reinterpret_cast<const float4*>(
                    h + (long)(m0 + am) * 128 + kk + ak);
                As[half][ak + 0][am] = av.x;
                As[half][ak + 1][am] = av.y;
                As[half][ak + 2][am] = av.z;
                As[half][ak + 3][am] = av.w;
            }
            {
                const float4 bv = *reinterpret_cast<const float4*>(
                    w_in + (long)(n0 + am) * 128 + kk + ak);
                Bs[half][ak + 0][am] = bv.x;
                Bs[half][ak + 1][am] = bv.y;
                Bs[half][ak + 2][am] = bv.z;
                Bs[half][ak + 3][am] = bv.w;
            }
            __syncthreads();
#pragma unroll
            for (int kc = 0; kc < 16; ++kc) {
                float a0 = As[half][kc][ty * 4 + 0], a1 = As[half][kc][ty * 4 + 1];
                float a2 = As[half][kc][ty * 4 + 2], a3 = As[half][kc][ty * 4 + 3];
                float b0 = Bs[half][kc][tx * 4 + 0], b1 = Bs[half][kc][tx * 4 + 1];
                float b2 = Bs[half][kc][tx * 4 + 2], b3 = Bs[half][kc][tx * 4 + 3];
                acc[0][0] += a0 * b0; acc[0][1] += a0 * b1; acc[0][2] += a0 * b2; acc[0][3] += a0 * b3;
                acc[1][0] += a1 * b0; acc[1][1] += a1 * b1; acc[1][2] += a1 * b2; acc[1][3] += a1 * b3;
                acc[2][0] += a2 * b0; acc[2][1] += a2 * b1; acc[2][2] += a2 * b2; acc[2][3] += a2 * b3;
                acc[3][0] += a3 * b0; acc[3][1] += a3 * b1; acc[3][2] += a3 * b2; acc[3][3] += a3 * b3;
            }
            __syncthreads();
        }
        u16* Cu = qb + ((long)(n0 >> 7)) * 4194304L;
        int cb = (n0 & 127) + tx * 4;
#pragma unroll
        for (int i = 0; i < 4; ++i) {
            int gi = m0 + ty * 4 + i;
            ushort4 sv;
            u16* svp = &sv.x;
#pragma unroll
            for (int j = 0; j < 4; ++j)
                svp[j] = f2b(acc[i][j] + b_in[n0 + tx * 4 + j]);
            *reinterpret_cast<ushort4*>(Cu + (long)gi * 128 + cb) = sv;
        }
        return;
    }

    // ------------------------------- dtw ---------------------------------
    const int b = blockIdx.x;
    u16* R = Rb + (long)b * (1024L * 1024L);
    const int tid = threadIdx.x;
    const int w = tid >> 6;
    const int lane = tid & 63;
    const bool lane0 = (lane == 0);
    const int off0 = (w << 7) + (lane << 1);

    float* botw = (w < 7) ? bot[w] : bot[0];
    const float* botp = (w > 0) ? bot[w - 1] : bot[0];

    float cur0 = INF_F, cur1 = INF_F;
    float prev0 = INF_F, prev1 = INF_F;
    float upc = INF_F, upp = INF_F;
    float vmin = INF_F, vmax = -INF_F;
    float dbuf[8][2];
    float bb[9];
#pragma unroll
    for (int q = 0; q < 9; ++q) bb[q] = 0.f;

    const int firstChunk = 4 * w;       // chunk = 32 steps; 36 chunks per wave
    for (int e = 0; e < 71; ++e) {
        const int c = e - w;
        const int o = c - firstChunk;
        if (o >= 0 && o <= 35) {
            const int T0 = c << 5;
            if (o == 0) {   // prime D queue (8 steps)
#pragma unroll
                for (int s = 0; s < 8; ++s) {
                    const ushort2 dv = *reinterpret_cast<const ushort2*>(
                        R + ((((T0 + s) & 1023) << 10) + off0));
                    dbuf[s][0] = b2f(dv.x);
                    dbuf[s][1] = b2f(dv.y);
                }
            }
            if (w > 0) {    // bot cols for the chunk's first group
                const int jb = T0 - (w << 7) - 1;
#pragma unroll
                for (int q = 0; q < 9; ++q) bb[q] = botp[(jb + q) & 511];
            }
            if (o < 4 || o >= 32)
                dtw_chunk<true>(R, botp, botw, w, lane, lane0, off0, T0,
                                cur0, cur1, prev0, prev1, upc, upp,
                                vmin, vmax, dbuf, bb);
            else
                dtw_chunk<false>(R, botp, botw, w, lane, lane0, off0, T0,
                                 cur0, cur1, prev0, prev1, upc, upp,
                                 vmin, vmax, dbuf, bb);
        }
        __syncthreads();
    }

    rmn[tid] = vmin;
    rmx[tid] = vmax;
    __syncthreads();
    for (int s2 = 256; s2 > 0; s2 >>= 1) {
        if (tid < s2) {
            rmn[tid] = fminf(rmn[tid], rmn[tid + s2]);
            rmx[tid] = fmaxf(rmx[tid], rmx[tid + s2]);
        }
        __syncthreads();
    }
    if (tid == 0) {
        minmax[2 * b] = rmn[0];
        minmax[2 * b + 1] = rmx[0];
    }
}

// ---------------- softmax row stats + in-place P = exp(s-max) --------------
__global__ __launch_bounds__(256) void smax_k(u16* __restrict__ S,
                                              float* __restrict__ rsuminv)
{
    long row = blockIdx.x;
    u16* rowp = S + row * L_SEQ;
    const ushort4 v4 = reinterpret_cast<const ushort4*>(rowp)[threadIdx.x];
    float a = b2f(v4.x), b = b2f(v4.y), c = b2f(v4.z), d = b2f(v4.w);
    int t = threadIdx.x;
    __shared__ float red[256];
    red[t] = fmaxf(fmaxf(a, b), fmaxf(c, d));
    __syncthreads();
    for (int s = 128; s > 0; s >>= 1) {
        if (t < s) red[t] = fmaxf(red[t], red[t + s]);
        __syncthreads();
    }
    float mx = red[0];
    __syncthreads();
    float ea = __expf(a - mx), eb = __expf(b - mx);
    float ec = __expf(c - mx), ed = __expf(d - mx);
    ushort4 pv;
    pv.x = f2b(ea); pv.y = f2b(eb); pv.z = f2b(ec); pv.w = f2b(ed);
    reinterpret_cast<ushort4*>(rowp)[t] = pv;
    red[t] = ea + eb + ec + ed;
    __syncthreads();
    for (int s = 128; s > 0; s >>= 1) {
        if (t < s) red[t] += red[t + s];
        __syncthreads();
    }
    if (t == 0) rsuminv[row] = 1.f / red[0];
}

// -------------------------- layernorm (wave/row) ---------------------------
__global__ __launch_bounds__(256) void ln_k(float* __restrict__ X,
                                            const float* __restrict__ g,
                                            const float* __restrict__ b)
{
    long row = (long)blockIdx.x * 4 + (threadIdx.x >> 6);
    int lane = threadIdx.x & 63;
    float2 x = *reinterpret_cast<float2*>(X + row * DM + lane * 2);
    float s = x.x + x.y;
    float q = x.x * x.x + x.y * x.y;
#pragma unroll
    for (int m = 1; m < 64; m <<= 1) {
        s += __shfl_xor(s, m);
        q += __shfl_xor(q, m);
    }
    float mean = s * (1.f / 128.f);
    float var = q * (1.f / 128.f) - mean * mean;
    float rstd = rsqrtf(var + 1e-5f);
    float2 o;
    o.x = (x.x - mean) * rstd * g[lane * 2 + 0] + b[lane * 2 + 0];
    o.y = (x.y - mean) * rstd * g[lane * 2 + 1] + b[lane * 2 + 1];
    *reinterpret_cast<float2*>(X + row * DM + lane * 2) = o;
}

// -------------------------------- lengths ----------------------------------
__global__ __launch_bounds__(256) void len_k(const float* __restrict__ mask,
                                             float* __restrict__ out)
{
    int b = blockIdx.x;
    int t = threadIdx.x;
    const float4 v = reinterpret_cast<const float4*>(mask + b * L_SEQ)[t];
    __shared__ float red[256];
    red[t] = v.x + v.y + v.z + v.w;
    __syncthreads();
    for (int s = 128; s > 0; s >>= 1) {
        if (t < s) red[t] += red[t + s];
        __syncthreads();
    }
    if (t == 0) out[b] = red[0];
}

// ------------------------------- launcher ----------------------------------
extern "C" void kernel_launch(void* const* d_in, const int* in_sizes, int n_in,
                              void* d_out, int out_size, void* d_ws, size_t ws_size,
                              hipStream_t stream)
{
    const float* x      = (const float*)d_in[0];
    const float* mask   = (const float*)d_in[1];
    const float* conv_w = (const float*)d_in[2];
    const float* conv_b = (const float*)d_in[3];
    const float* w_in   = (const float*)d_in[4];
    const float* b_in   = (const float*)d_in[5];
    const float* w_out  = (const float*)d_in[6];
    const float* b_out  = (const float*)d_in[7];
    const float* w_ff1  = (const float*)d_in[8];
    const float* b_ff1  = (const float*)d_in[9];
    const float* w_ff2  = (const float*)d_in[10];
    const float* b_ff2  = (const float*)d_in[11];
    const float* ln1_g  = (const float*)d_in[12];
    const float* ln1_b  = (const float*)d_in[13];
    const float* ln2_g  = (const float*)d_in[14];
    const float* ln2_b  = (const float*)d_in[15];
    const float* w_lin  = (const float*)d_in[16];
    float* out = (float*)d_out;

    float* ws    = (float*)d_ws;
    float* h     = ws;
    u16*   qb    = (u16*)(ws + 4194304L);
    u16*   kb    = qb + 4194304L;
    u16*   vb    = qb + 8388608L;
    u16*   vt    = qb + 12582912L;
    float* t0    = ws + 16777216L;
    float* t1    = ws + 20971520L;
    float* t2    = ws + 25165824L;
    u16*   hbf   = (u16*)t2;                 // free until FF1
    float* norms = ws + 29360128L;
    float* rsum  = ws + 29425664L;
    float* mnmx  = ws + 29458432L;
    u16*   Db    = (u16*)(ws + 29458496L);   // skewed D/R bf16
    u16*   Sb    = (u16*)(ws + 46235712L);   // scores -> P bf16, std layout

    conv_k<<<dim3(32, 128), 128, 0, stream>>>(x, conv_w, conv_b, mask, h, hbf, norms);
    mgemm_k<G_D2><<<dim3(16, 16, 32), 256, 0, stream>>>(
        hbf, hbf, Db, norms, nullptr);
    // dtw (32 blocks) + qkv backfill (1536 blocks)
    dtw_qkv_k<<<1568, 512, 0, stream>>>(Db, mnmx, h, w_in, b_in, qb);
    // V-transpose (1024 blocks) + scores (8192 blocks)
    sc_tr_k<<<9216, 256, 0, stream>>>(qb, kb, Sb, mnmx, mask, Db, vb, vt);
    smax_k<<<32768, 256, 0, stream>>>(Sb, rsum);
    mgemm_k<G_AV><<<dim3(16, 2, 32), 256, 0, stream>>>(
        Sb, vt, t0, nullptr, rsum);
    gemm_k<M_WOUT><<<dim3(512, 2), 256, 0, stream>>>(
        t0, w_out, t1, 128, 128, b_out, h);
    ln_k<<<8192, 256, 0, stream>>>(t1, ln1_g, ln1_b);
    gemm_k<M_FF1><<<dim3(512, 2), 256, 0, stream>>>(
        t1, w_ff1, t2, 128, 128, b_ff1, nullptr);
    gemm_k<M_FF2><<<dim3(512, 2), 256, 0, stream>>>(
        t2, w_ff2, t0, 128, 128, b_ff2, t1);
    ln_k<<<8192, 256, 0, stream>>>(t0, ln2_g, ln2_b);
    gemm_k<M_LIN><<<dim3(512, 1), 256, 0, stream>>>(
        t0, w_lin, out, 16, 16, mask, nullptr);
    len_k<<<32, 256, 0, stream>>>(mask, out + 32768L * 16);
}

// Round 10
// 1253.488 us; speedup vs baseline: 2.2317x; 1.0620x over previous
//
#include <hip/hip_runtime.h>
#include <math.h>

// ---------------------------------------------------------------------------
// DsDTW pipeline (round 10): soft-DTW split across 2 CUs per sample (64 blocks,
// 8 waves x 64 lanes x 1 row/lane each) with device-scope global ring + flags
// for the row-511 -> 512 handoff. QKV backfill kept. Wave-per-row smax.
// B=32, C_IN=12, T=4095, D=128, L=1024, GAMMA=5.
//
// ws layout (float offsets):
//   h      @ 0          4,194,304   [32,1024,128] fp32
//   qkvb   @ 4194304    qb/kb/vb/vt bf16, 4x 4,194,304 ushorts
//   t0     @ 16777216   4,194,304
//   t1     @ 20971520   4,194,304
//   t2     @ 25165824   4,194,304   (head doubles as hbf bf16; tail: gbot/flags/
//                                    mnmx — all dead once FF1 writes t2)
//   gbot   @ 27262976   32,768      f32 row-511 ring per sample
//   flags  @ 27295744   2,048       uint chunk-completion flags
//   mnmx   @ 27297792   128         per (sample, half) min/max
//   norms  @ 29360128   32,768
//   rsum   @ 29425664   32,768
//   Db/Rb  @ 29458496   (bf16) skewed D -> R in place
//   Sb     @ 46235712   (bf16) scores -> P (exp'd in smax_k), std layout
// ---------------------------------------------------------------------------

#define L_SEQ 1024
#define DM 128
#define INF_F __builtin_inff()

typedef short s16x8 __attribute__((ext_vector_type(8)));
typedef float f32x4 __attribute__((ext_vector_type(4)));
typedef unsigned short u16;

__device__ __forceinline__ float b2f(u16 u) {
    return __uint_as_float(((unsigned)u) << 16);
}
__device__ __forceinline__ u16 f2b(float f) {  // RNE
    unsigned u = __float_as_uint(f);
    return (u16)((u + 0x7FFFu + ((u >> 16) & 1u)) >> 16);
}
__device__ __forceinline__ u16 f2bt(float f) {  // truncate (cheap)
    return (u16)(__float_as_uint(f) >> 16);
}

// ---------------- conv + pool + relu + mask + row norms --------------------
__global__ __launch_bounds__(128) void conv_k(
    const float* __restrict__ x, const float* __restrict__ w,
    const float* __restrict__ cb, const float* __restrict__ mask,
    float* __restrict__ h, u16* __restrict__ hbf, float* __restrict__ norms)
{
    int b = blockIdx.x;
    int l0 = blockIdx.y * 8;
    int d = threadIdx.x;
    __shared__ float xs[12][36];
    __shared__ float red2[8][2];
    for (int v = d; v < 12 * 35; v += 128) {
        int c = v / 35, off = v % 35;
        int gi = 4 * l0 - 2 + off;
        xs[c][off] = (gi >= 0 && gi < 4095) ? x[((long)b * 12 + c) * 4095 + gi] : 0.f;
    }
    __syncthreads();
    float s[8];
#pragma unroll
    for (int l = 0; l < 8; ++l) s[l] = 0.f;
    for (int c = 0; c < 12; ++c) {
        const float* wp = w + (d * 12 + c) * 4;
        float w0 = wp[0], w1 = wp[1], w2 = wp[2], w3 = wp[3];
        float e0 = w0, e1 = w0 + w1, e2 = w0 + w1 + w2, e3 = w0 + w1 + w2 + w3;
        float e4 = w1 + w2 + w3, e5 = w2 + w3, e6 = w3;
#pragma unroll
        for (int l = 0; l < 8; ++l) {
            int ba = 4 * l;
            s[l] += xs[c][ba] * e0 + xs[c][ba + 1] * e1 + xs[c][ba + 2] * e2 +
                    xs[c][ba + 3] * e3 + xs[c][ba + 4] * e4 + xs[c][ba + 5] * e5 +
                    xs[c][ba + 6] * e6;
        }
    }
    float cbd = cb[d];
#pragma unroll
    for (int l = 0; l < 8; ++l) {
        int gl = l0 + l;
        float val = fmaxf(cbd + 0.25f * s[l], 0.f) * mask[b * L_SEQ + gl];
        long idx = ((long)(b * L_SEQ + gl)) * DM + d;
        h[idx] = val;
        hbf[idx] = f2b(val);
        float vsq = val * val;
#pragma unroll
        for (int m = 1; m < 64; m <<= 1) vsq += __shfl_xor(vsq, m);
        if ((d & 63) == 0) red2[l][d >> 6] = vsq;
    }
    __syncthreads();
    if (d < 8) norms[(long)b * L_SEQ + l0 + d] = red2[d][0] + red2[d][1];
}

// --------------------------- MFMA bf16 GEMMs -------------------------------
enum MGMode { G_D2, G_AV };

template <int MODE>
__global__ __launch_bounds__(256) void mgemm_k(
    const u16* __restrict__ A0, const u16* __restrict__ B0, void* __restrict__ C0,
    const float* __restrict__ e0, const float* __restrict__ rsum)
{
    constexpr int LDK = (MODE == G_AV) ? 1024 : 128;
    constexpr int KK = LDK / 32;
    const int z = blockIdx.z;
    const u16* A = A0 + (MODE == G_D2 ? 0L : (long)z * 1048576L);
    const u16* B = B0 + (long)z * 131072L;
    const int tid = threadIdx.x, wv = tid >> 6, lane = tid & 63;
    const int m0 = blockIdx.x * 64, n0 = blockIdx.y * 64;
    const int co = lane & 15;
    const int q8 = (lane >> 4) << 3;
    const int mrow = m0 + 16 * wv + co;

    f32x4 acc[4];
#pragma unroll
    for (int tn = 0; tn < 4; ++tn) acc[tn] = 0.f;

    for (int kk = 0; kk < KK; ++kk) {
        const int k0 = kk * 32 + q8;
        const s16x8 a = *reinterpret_cast<const s16x8*>(A + (long)mrow * LDK + k0);
#pragma unroll
        for (int tn = 0; tn < 4; ++tn) {
            const s16x8 b = *reinterpret_cast<const s16x8*>(
                B + (long)(n0 + 16 * tn + co) * LDK + k0);
            acc[tn] = __builtin_amdgcn_mfma_f32_16x16x32_bf16(a, b, acc[tn], 0, 0, 0);
        }
    }

    const int li0 = 16 * wv + ((lane >> 4) << 2);

    if (MODE == G_D2) {
        __shared__ float Cs[64][66];
        float ni[4];
#pragma unroll
        for (int r = 0; r < 4; ++r) ni[r] = e0[m0 + li0 + r];
#pragma unroll
        for (int tn = 0; tn < 4; ++tn) {
            float nj = e0[(long)z * L_SEQ + n0 + 16 * tn + co];
#pragma unroll
            for (int r = 0; r < 4; ++r)
                Cs[li0 + r][16 * tn + co] = ni[r] + nj - 2.f * acc[tn][r];
        }
        __syncthreads();
        u16* Cu = (u16*)C0 + (long)z * 1048576L;
        for (int q = 0; q < 32; ++q) {
            int dd = wv * 32 + q;
            if (dd < 127) {
                int d = m0 + n0 + dd;
                int ilo = max(m0, d - n0 - 63);
                int ihi = min(m0 + 63, d - n0);
                int i = ilo + lane;
                if (i <= ihi)
                    Cu[(long)(((d & 1023) << 10) + i)] = f2b(Cs[i - m0][d - n0 - i]);
            }
        }
        return;
    }
    // G_AV: out = (P . V) * rsuminv[row], fp32
    {
        float* Cf = (float*)C0 + (long)z * 131072L;
        float rsv[4];
#pragma unroll
        for (int r = 0; r < 4; ++r) rsv[r] = rsum[(long)z * L_SEQ + m0 + li0 + r];
#pragma unroll
        for (int tn = 0; tn < 4; ++tn)
#pragma unroll
            for (int r = 0; r < 4; ++r)
                Cf[(long)(m0 + li0 + r) * 128 + n0 + 16 * tn + co] =
                    acc[tn][r] * rsv[r];
    }
}

// ---------------- SC (MFMA scores) + V-transpose, one launch ---------------
__global__ __launch_bounds__(256) void sc_tr_k(
    const u16* __restrict__ qb, const u16* __restrict__ kb, u16* __restrict__ Sb,
    const float* __restrict__ mnmx, const float* __restrict__ mask,
    const u16* __restrict__ Rb, const u16* __restrict__ vb, u16* __restrict__ vt)
{
    const int bid = blockIdx.x;
    const int tid = threadIdx.x;
    __shared__ float Rs[64][66];

    if (bid < 1024) {    // V transpose
        const int z = bid >> 5;
        const int l0 = (bid & 15) * 64, d0 = ((bid >> 4) & 1) * 64;
        const u16* src = vb + (long)z * 131072L;
        u16* dst = vt + (long)z * 131072L;
        u16* T = (u16*)Rs;
#pragma unroll
        for (int i = 0; i < 16; ++i) {
            int idx = tid + 256 * i;
            int li = idx >> 6, dj = idx & 63;
            T[dj * 65 + li] = src[(long)(l0 + li) * 128 + d0 + dj];
        }
        __syncthreads();
#pragma unroll
        for (int i = 0; i < 16; ++i) {
            int idx = tid + 256 * i;
            int dj = idx >> 6, li = idx & 63;
            dst[(long)(d0 + dj) * 1024 + l0 + li] = T[dj * 65 + li];
        }
        return;
    }
    const int s = bid - 1024;
    const int z = s >> 8;
    const int m0 = (s & 15) * 64, n0 = ((s >> 4) & 15) * 64;
    const u16* A = qb + (long)z * 131072L;
    const u16* B = kb + (long)z * 131072L;
    const int wv = tid >> 6, lane = tid & 63;
    const int co = lane & 15;
    const int q8 = (lane >> 4) << 3;
    const int mrow = m0 + 16 * wv + co;

    f32x4 acc[4];
#pragma unroll
    for (int tn = 0; tn < 4; ++tn) acc[tn] = 0.f;
    for (int kk = 0; kk < 4; ++kk) {
        const int k0 = kk * 32 + q8;
        const s16x8 a = *reinterpret_cast<const s16x8*>(A + (long)mrow * 128 + k0);
#pragma unroll
        for (int tn = 0; tn < 4; ++tn) {
            const s16x8 b = *reinterpret_cast<const s16x8*>(
                B + (long)(n0 + 16 * tn + co) * 128 + k0);
            acc[tn] = __builtin_amdgcn_mfma_f32_16x16x32_bf16(a, b, acc[tn], 0, 0, 0);
        }
    }
    const int li0 = 16 * wv + ((lane >> 4) << 2);
    const u16* Rz = Rb + (long)z * 1048576L;
    for (int q = 0; q < 32; ++q) {
        int dd = wv * 32 + q;
        if (dd < 127) {
            int d = m0 + n0 + dd;
            int ilo = max(m0, d - n0 - 63);
            int ihi = min(m0 + 63, d - n0);
            int i = ilo + lane;
            if (i <= ihi)
                Rs[i - m0][d - n0 - i] = b2f(Rz[(long)(((d & 1023) << 10) + i)]);
        }
    }
    __syncthreads();
    float mn = fminf(mnmx[4 * z + 0], mnmx[4 * z + 2]);
    float mx = fmaxf(mnmx[4 * z + 1], mnmx[4 * z + 3]);
    float inv = 1.f / (mx - mn);
    u16* Cu = Sb + (long)z * 1048576L;
#pragma unroll
    for (int tn = 0; tn < 4; ++tn) {
        int gj = n0 + 16 * tn + co;
        float kp = (mask[(long)z * L_SEQ + gj] > 0.f) ? 0.f : -INF_F;
#pragma unroll
        for (int r = 0; r < 4; ++r) {
            float val = acc[tn][r] * 0.08838834764831845f +
                        (Rs[li0 + r][16 * tn + co] - mn) * inv + 1.f + kp;
            Cu[(long)(m0 + li0 + r) * 1024 + gj] = f2b(val);
        }
    }
}

// ------------------------------ fp32 GEMMs ---------------------------------
enum GMode { M_WOUT, M_FF1, M_FF2, M_LIN };

template <int MODE>
__global__ __launch_bounds__(256) void gemm_k(
    const float* __restrict__ A, const float* __restrict__ B, float* __restrict__ C,
    int N, int ldc,
    const float* __restrict__ e0, const float* __restrict__ e1)
{
    __shared__ float As[16][65];
    __shared__ float Bs[16][65];
    int tid = threadIdx.x;
    int tx = tid & 15, ty = tid >> 4;
    int m0 = blockIdx.x * 64, n0 = blockIdx.y * 64;
    float acc[4][4] = {};
    int am = tid >> 2;
    int ak = (tid & 3) << 2;

    for (int kk = 0; kk < 128; kk += 16) {
        {
            const float4 av =
                *reinterpret_cast<const float4*>(A + (long)(m0 + am) * 128 + kk + ak);
            As[ak + 0][am] = av.x;
            As[ak + 1][am] = av.y;
            As[ak + 2][am] = av.z;
            As[ak + 3][am] = av.w;
        }
        {
            int n = n0 + am;
            float4 bv = {0.f, 0.f, 0.f, 0.f};
            if (n < N)
                bv = *reinterpret_cast<const float4*>(B + (long)n * 128 + kk + ak);
            Bs[ak + 0][am] = bv.x;
            Bs[ak + 1][am] = bv.y;
            Bs[ak + 2][am] = bv.z;
            Bs[ak + 3][am] = bv.w;
        }
        __syncthreads();
#pragma unroll
        for (int kc = 0; kc < 16; ++kc) {
            float a0 = As[kc][ty * 4 + 0], a1 = As[kc][ty * 4 + 1];
            float a2 = As[kc][ty * 4 + 2], a3 = As[kc][ty * 4 + 3];
            float b0 = Bs[kc][tx * 4 + 0], b1 = Bs[kc][tx * 4 + 1];
            float b2 = Bs[kc][tx * 4 + 2], b3 = Bs[kc][tx * 4 + 3];
            acc[0][0] += a0 * b0; acc[0][1] += a0 * b1; acc[0][2] += a0 * b2; acc[0][3] += a0 * b3;
            acc[1][0] += a1 * b0; acc[1][1] += a1 * b1; acc[1][2] += a1 * b2; acc[1][3] += a1 * b3;
            acc[2][0] += a2 * b0; acc[2][1] += a2 * b1; acc[2][2] += a2 * b2; acc[2][3] += a2 * b3;
            acc[3][0] += a3 * b0; acc[3][1] += a3 * b1; acc[3][2] += a3 * b2; acc[3][3] += a3 * b3;
        }
        __syncthreads();
    }

#pragma unroll
    for (int i = 0; i < 4; ++i) {
        int gi = m0 + ty * 4 + i;
#pragma unroll
        for (int j = 0; j < 4; ++j) {
            int gj = n0 + tx * 4 + j;
            float v = acc[i][j];
            long idx = (long)gi * ldc + gj;
            if (MODE == M_WOUT) {
                C[idx] = v + e0[gj] + e1[idx];
            } else if (MODE == M_FF1) {
                C[idx] = fmaxf(v + e0[gj], 0.f);
            } else if (MODE == M_FF2) {
                C[idx] = v + e0[gj] + e1[idx];
            } else if (MODE == M_LIN) {
                if (gj < N) C[idx] = v * e0[gi];
            }
        }
    }
}

// ------------------------------- soft-DTW ----------------------------------
// 2 blocks/sample; global wave W = 8*hb + w owns rows [64W, 64W+64), lane i
// owns row 64W+i with skew 1. Intra-block ring via LDS; the 511->512 handoff
// via gbot (device-scope float atomics) + per-chunk flags. Chunk = 32 steps;
// wave W runs chunk c at epoch c+W; chunks per wave = 34 (o in [0,33]);
// EDGE when o<2 or o>=32.
__device__ __forceinline__ float softmin3(float d, float rl, float ru, float rul)
{
    float mn = fminf(rul, fminf(ru, rl));
    float md = fmaxf(fminf(rul, ru), fminf(fmaxf(rul, ru), rl));
    float mx = fmaxf(rul, fmaxf(ru, rl));
    float s = 1.f + __expf((mn - md) * 0.2f) + __expf((mn - mx) * 0.2f);
    return d + mn - 5.0f * __logf(s);
}

template <bool EDGE>
__device__ __forceinline__ void dtw_chunk1(
    u16* __restrict__ R, const float* __restrict__ botp, float* __restrict__ botw,
    float* __restrict__ gb, int W, int lane, bool lane0, int rowbase, int row,
    int T0, bool useG,
    float& cur, float& upc, float& upp, float& vmin, float& vmax,
    float (&dbuf)[8], float (&bb)[9])
{
    u16* rp = R + (((T0 & 1023) << 10) + row);
    for (int g = 0; g < 4; ++g) {
        const int tg = T0 + (g << 3);
        float dn[8];
#pragma unroll
        for (int s = 0; s < 8; ++s)
            dn[s] = b2f(R[((((tg + 8 + s) & 1023) << 10) + row)]);
        float bn[9];
        if (W > 0 && g < 3) {
            const int jn = tg + 7 - rowbase;
            if (useG) {
                if (lane0) {
#pragma unroll
                    for (int q = 0; q < 9; ++q)
                        bn[q] = atomicAdd(gb + min(max(jn + q, 0), 1023), 0.f);
                }
            } else {
#pragma unroll
                for (int q = 0; q < 9; ++q) bn[q] = botp[(jn + q) & 511];
            }
        }
#pragma unroll
        for (int s = 0; s < 8; ++s) {
            const int t = tg + s;
            const int j = t - row;
            float ru = upc, rul = upp;
            if (lane0) {
                if (W == 0) {
                    ru = INF_F;
                    rul = (EDGE && j == 0) ? 0.f : INF_F;
                } else {
                    ru = bb[s + 1];
                    if (EDGE && j < 1) rul = INF_F;
                }
            }
            float n = softmin3(dbuf[s], cur, ru, rul);
            if (EDGE) {
                bool v = ((unsigned)j < 1024u);
                n = v ? n : INF_F;
                vmin = fminf(vmin, n);
                vmax = v ? fmaxf(vmax, n) : vmax;
                if (v) rp[0] = f2bt(n);
                if (lane == 63 && v) {
                    if (W == 7) atomicExch(gb + j, n);
                    else if ((W & 7) != 7) botw[j & 511] = n;
                }
            } else {
                vmin = fminf(vmin, n);
                vmax = fmaxf(vmax, n);
                rp[0] = f2bt(n);
                if (lane == 63) {
                    if (W == 7) atomicExch(gb + j, n);
                    else if ((W & 7) != 7) botw[j & 511] = n;
                }
            }
            upp = ru;
            cur = n;
            upc = __shfl_up(n, 1);
            rp += 1024;
        }
#pragma unroll
        for (int s = 0; s < 8; ++s) dbuf[s] = dn[s];
        if (W > 0 && g < 3) {
#pragma unroll
            for (int q = 0; q < 9; ++q) bb[q] = bn[q];
        }
    }
}

// dtw (blocks 0..63: 2 per sample) + QKV backfill (blocks 64..1599)
__global__ __launch_bounds__(512) void dtw_qkv_k(
    u16* __restrict__ Rb, float* __restrict__ minmax,
    float* __restrict__ gbot, unsigned* __restrict__ flags,
    const float* __restrict__ h, const float* __restrict__ w_in,
    const float* __restrict__ b_in, u16* __restrict__ qb)
{
    __shared__ float bot[7][512];
    __shared__ float rmn[512];
    __shared__ float rmx[512];
    __shared__ float As[2][16][65];
    __shared__ float Bs[2][16][65];

    if (blockIdx.x >= 64) {
        // ---- QKV backfill: two 64x64 tiles per 512-thread block ----
        const int half = threadIdx.x >> 8;
        const int tid = threadIdx.x & 255;
        const int t = ((blockIdx.x - 64) << 1) + half;   // 0..3071
        const int m0 = (t & 511) << 6;
        const int n0 = (t >> 9) << 6;
        int tx = tid & 15, ty = tid >> 4;
        float acc[4][4] = {};
        int am = tid >> 2;
        int ak = (tid & 3) << 2;
        for (int kk = 0; kk < 128; kk += 16) {
            {
                const float4 av = *reinterpret_cast<const float4*>(
                    h + (long)(m0 + am) * 128 + kk + ak);
                As[half][ak + 0][am] = av.x;
                As[half][ak + 1][am] = av.y;
                As[half][ak + 2][am] = av.z;
                As[half][ak + 3][am] = av.w;
            }
            {
                const float4 bv = *reinterpret_cast<const float4*>(
                    w_in + (long)(n0 + am) * 128 + kk + ak);
                Bs[half][ak + 0][am] = bv.x;
                Bs[half][ak + 1][am] = bv.y;
                Bs[half][ak + 2][am] = bv.z;
                Bs[half][ak + 3][am] = bv.w;
            }
            __syncthreads();
#pragma unroll
            for (int kc = 0; kc < 16; ++kc) {
                float a0 = As[half][kc][ty * 4 + 0], a1 = As[half][kc][ty * 4 + 1];
                float a2 = As[half][kc][ty * 4 + 2], a3 = As[half][kc][ty * 4 + 3];
                float b0 = Bs[half][kc][tx * 4 + 0], b1 = Bs[half][kc][tx * 4 + 1];
                float b2 = Bs[half][kc][tx * 4 + 2], b3 = Bs[half][kc][tx * 4 + 3];
                acc[0][0] += a0 * b0; acc[0][1] += a0 * b1; acc[0][2] += a0 * b2; acc[0][3] += a0 * b3;
                acc[1][0] += a1 * b0; acc[1][1] += a1 * b1; acc[1][2] += a1 * b2; acc[1][3] += a1 * b3;
                acc[2][0] += a2 * b0; acc[2][1] += a2 * b1; acc[2][2] += a2 * b2; acc[2][3] += a2 * b3;
                acc[3][0] += a3 * b0; acc[3][1] += a3 * b1; acc[3][2] += a3 * b2; acc[3][3] += a3 * b3;
            }
            __syncthreads();
        }
        u16* Cu = qb + ((long)(n0 >> 7)) * 4194304L;
        int cb = (n0 & 127) + tx * 4;
#pragma unroll
        for (int i = 0; i < 4; ++i) {
            int gi = m0 + ty * 4 + i;
            ushort4 sv;
            u16* svp = &sv.x;
#pragma unroll
            for (int j = 0; j < 4; ++j)
                svp[j] = f2b(acc[i][j] + b_in[n0 + tx * 4 + j]);
            *reinterpret_cast<ushort4*>(Cu + (long)gi * 128 + cb) = sv;
        }
        return;
    }

    // ------------------------------- dtw ---------------------------------
    const int z = blockIdx.x >> 1;
    const int hb = blockIdx.x & 1;
    u16* R = Rb + (long)z * 1048576L;
    float* gb = gbot + z * 1024;
    unsigned* flag = flags + z * 64;
    const int tid = threadIdx.x;
    const int w = tid >> 6;
    const int lane = tid & 63;
    const bool lane0 = (lane == 0);
    const int W = 8 * hb + w;
    const int rowbase = 64 * W;
    const int row = rowbase + lane;
    const bool useG = (hb == 1 && w == 0);

    float* botw = (w < 7) ? bot[w] : bot[0];
    const float* botp = (w > 0) ? bot[w - 1] : bot[0];

    float cur = INF_F, upc = INF_F, upp = INF_F;
    float vmin = INF_F, vmax = -INF_F;
    float dbuf[8];
    float bb[9];
#pragma unroll
    for (int q = 0; q < 9; ++q) bb[q] = 0.f;

    const int fc = 2 * W;
    for (int e = 0; e < 79; ++e) {
        const int c = e - W;
        const int o = c - fc;
        if (o >= 0 && o <= 33) {
            const int T0 = c << 5;
            if (useG && c <= 47) {   // wait for b0 wave7 to finish chunk c
                unsigned fv = 0;
                do {
                    unsigned t0v = 1;
                    if (lane0) t0v = atomicAdd(&flag[c], 0u);
                    fv = (unsigned)__shfl((int)t0v, 0);
                } while (fv == 0);
            }
            if (o == 0) {   // prime D queue (8 steps)
#pragma unroll
                for (int s = 0; s < 8; ++s)
                    dbuf[s] = b2f(R[((((T0 + s) & 1023) << 10) + row)]);
            }
            if (W > 0) {    // bot columns for the chunk's first group
                const int jb = T0 - rowbase - 1;
                if (useG) {
                    if (lane0) {
#pragma unroll
                        for (int q = 0; q < 9; ++q)
                            bb[q] = atomicAdd(gb + min(max(jb + q, 0), 1023), 0.f);
                    }
                } else {
#pragma unroll
                    for (int q = 0; q < 9; ++q) bb[q] = botp[(jb + q) & 511];
                }
            }
            if (o < 2 || o >= 32)
                dtw_chunk1<true>(R, botp, botw, gb, W, lane, lane0, rowbase, row,
                                 T0, useG, cur, upc, upp, vmin, vmax, dbuf, bb);
            else
                dtw_chunk1<false>(R, botp, botw, gb, W, lane, lane0, rowbase, row,
                                  T0, useG, cur, upc, upp, vmin, vmax, dbuf, bb);
        }
        __syncthreads();
        if (hb == 0 && tid == 0) {
            int c7 = e - 7;
            if (c7 >= 14 && c7 <= 47) {
                __threadfence();
                atomicExch(&flag[c7], 1u);
            }
        }
    }

    rmn[tid] = vmin;
    rmx[tid] = vmax;
    __syncthreads();
    for (int s2 = 256; s2 > 0; s2 >>= 1) {
        if (tid < s2) {
            rmn[tid] = fminf(rmn[tid], rmn[tid + s2]);
            rmx[tid] = fmaxf(rmx[tid], rmx[tid + s2]);
        }
        __syncthreads();
    }
    if (tid == 0) {
        minmax[z * 4 + hb * 2 + 0] = rmn[0];
        minmax[z * 4 + hb * 2 + 1] = rmx[0];
    }
}

// ---------- softmax row stats + in-place P = exp(s-max), wave/row ----------
__global__ __launch_bounds__(256) void smax_k(u16* __restrict__ S,
                                              float* __restrict__ rsuminv)
{
    long row = (long)blockIdx.x * 4 + (threadIdx.x >> 6);
    int lane = threadIdx.x & 63;
    u16* p = S + row * L_SEQ + lane * 16;
    ushort4 v[4];
#pragma unroll
    for (int q = 0; q < 4; ++q) v[q] = reinterpret_cast<ushort4*>(p)[q];
    float f[16];
#pragma unroll
    for (int q = 0; q < 4; ++q) {
        f[4 * q + 0] = b2f(v[q].x);
        f[4 * q + 1] = b2f(v[q].y);
        f[4 * q + 2] = b2f(v[q].z);
        f[4 * q + 3] = b2f(v[q].w);
    }
    float m = f[0];
#pragma unroll
    for (int i = 1; i < 16; ++i) m = fmaxf(m, f[i]);
#pragma unroll
    for (int d2 = 1; d2 < 64; d2 <<= 1) m = fmaxf(m, __shfl_xor(m, d2));
    float s = 0.f;
#pragma unroll
    for (int i = 0; i < 16; ++i) {
        f[i] = __expf(f[i] - m);
        s += f[i];
    }
#pragma unroll
    for (int q = 0; q < 4; ++q) {
        ushort4 pv;
        pv.x = f2b(f[4 * q + 0]);
        pv.y = f2b(f[4 * q + 1]);
        pv.z = f2b(f[4 * q + 2]);
        pv.w = f2b(f[4 * q + 3]);
        reinterpret_cast<ushort4*>(p)[q] = pv;
    }
#pragma unroll
    for (int d2 = 1; d2 < 64; d2 <<= 1) s += __shfl_xor(s, d2);
    if (lane == 0) rsuminv[row] = 1.f / s;
}

// -------------------------- layernorm (wave/row) ---------------------------
__global__ __launch_bounds__(256) void ln_k(float* __restrict__ X,
                                            const float* __restrict__ g,
                                            const float* __restrict__ b)
{
    long row = (long)blockIdx.x * 4 + (threadIdx.x >> 6);
    int lane = threadIdx.x & 63;
    float2 x = *reinterpret_cast<float2*>(X + row * DM + lane * 2);
    float s = x.x + x.y;
    float q = x.x * x.x + x.y * x.y;
#pragma unroll
    for (int m = 1; m < 64; m <<= 1) {
        s += __shfl_xor(s, m);
        q += __shfl_xor(q, m);
    }
    float mean = s * (1.f / 128.f);
    float var = q * (1.f / 128.f) - mean * mean;
    float rstd = rsqrtf(var + 1e-5f);
    float2 o;
    o.x = (x.x - mean) * rstd * g[lane * 2 + 0] + b[lane * 2 + 0];
    o.y = (x.y - mean) * rstd * g[lane * 2 + 1] + b[lane * 2 + 1];
    *reinterpret_cast<float2*>(X + row * DM + lane * 2) = o;
}

// -------------------------------- lengths ----------------------------------
__global__ __launch_bounds__(256) void len_k(const float* __restrict__ mask,
                                             float* __restrict__ out)
{
    int b = blockIdx.x;
    int t = threadIdx.x;
    const float4 v = reinterpret_cast<const float4*>(mask + b * L_SEQ)[t];
    __shared__ float red[256];
    red[t] = v.x + v.y + v.z + v.w;
    __syncthreads();
    for (int s = 128; s > 0; s >>= 1) {
        if (t < s) red[t] += red[t + s];
        __syncthreads();
    }
    if (t == 0) out[b] = red[0];
}

// ------------------------------- launcher ----------------------------------
extern "C" void kernel_launch(void* const* d_in, const int* in_sizes, int n_in,
                              void* d_out, int out_size, void* d_ws, size_t ws_size,
                              hipStream_t stream)
{
    const float* x      = (const float*)d_in[0];
    const float* mask   = (const float*)d_in[1];
    const float* conv_w = (const float*)d_in[2];
    const float* conv_b = (const float*)d_in[3];
    const float* w_in   = (const float*)d_in[4];
    const float* b_in   = (const float*)d_in[5];
    const float* w_out  = (const float*)d_in[6];
    const float* b_out  = (const float*)d_in[7];
    const float* w_ff1  = (const float*)d_in[8];
    const float* b_ff1  = (const float*)d_in[9];
    const float* w_ff2  = (const float*)d_in[10];
    const float* b_ff2  = (const float*)d_in[11];
    const float* ln1_g  = (const float*)d_in[12];
    const float* ln1_b  = (const float*)d_in[13];
    const float* ln2_g  = (const float*)d_in[14];
    const float* ln2_b  = (const float*)d_in[15];
    const float* w_lin  = (const float*)d_in[16];
    float* out = (float*)d_out;

    float* ws    = (float*)d_ws;
    float* h     = ws;
    u16*   qb    = (u16*)(ws + 4194304L);
    u16*   kb    = qb + 4194304L;
    u16*   vb    = qb + 8388608L;
    u16*   vt    = qb + 12582912L;
    float* t0    = ws + 16777216L;
    float* t1    = ws + 20971520L;
    float* t2    = ws + 25165824L;
    u16*   hbf   = (u16*)t2;                  // head of t2, free until FF1
    float* gbot  = ws + 27262976L;            // tail of t2, free until FF1
    unsigned* flags = (unsigned*)(ws + 27295744L);
    float* mnmx  = ws + 27297792L;
    float* norms = ws + 29360128L;
    float* rsum  = ws + 29425664L;
    u16*   Db    = (u16*)(ws + 29458496L);    // skewed D/R bf16
    u16*   Sb    = (u16*)(ws + 46235712L);    // scores -> P bf16, std layout

    conv_k<<<dim3(32, 128), 128, 0, stream>>>(x, conv_w, conv_b, mask, h, hbf, norms);
    mgemm_k<G_D2><<<dim3(16, 16, 32), 256, 0, stream>>>(
        hbf, hbf, Db, norms, nullptr);
    hipMemsetAsync(flags, 0, 2048 * sizeof(unsigned), stream);
    // dtw (64 blocks, 2/sample) + qkv backfill (1536 blocks)
    dtw_qkv_k<<<1600, 512, 0, stream>>>(Db, mnmx, gbot, flags, h, w_in, b_in, qb);
    // V-transpose (1024 blocks) + scores (8192 blocks)
    sc_tr_k<<<9216, 256, 0, stream>>>(qb, kb, Sb, mnmx, mask, Db, vb, vt);
    smax_k<<<8192, 256, 0, stream>>>(Sb, rsum);
    mgemm_k<G_AV><<<dim3(16, 2, 32), 256, 0, stream>>>(
        Sb, vt, t0, nullptr, rsum);
    gemm_k<M_WOUT><<<dim3(512, 2), 256, 0, stream>>>(
        t0, w_out, t1, 128, 128, b_out, h);
    ln_k<<<8192, 256, 0, stream>>>(t1, ln1_g, ln1_b);
    gemm_k<M_FF1><<<dim3(512, 2), 256, 0, stream>>>(
        t1, w_ff1, t2, 128, 128, b_ff1, nullptr);
    gemm_k<M_FF2><<<dim3(512, 2), 256, 0, stream>>>(
        t2, w_ff2, t0, 128, 128, b_ff2, t1);
    ln_k<<<8192, 256, 0, stream>>>(t0, ln2_g, ln2_b);
    gemm_k<M_LIN><<<dim3(512, 1), 256, 0, stream>>>(
        t0, w_lin, out, 16, 16, mask, nullptr);
    len_k<<<32, 256, 0, stream>>>(mask, out + 32768L * 16);
}

// Round 11
// 1187.830 us; speedup vs baseline: 2.3551x; 1.0553x over previous
//
#include <hip/hip_runtime.h>
#include <math.h>

// ---------------------------------------------------------------------------
// DsDTW pipeline (round 11): dtw cross-lane handoff via DPP wave_shr:1
// (VALU-latency) instead of ds_bpermute (~120cy) — cuts the per-step serial
// chain; branch-free lane0 fixups; V-transpose fused into the QKV backfill.
// B=32, C_IN=12, T=4095, D=128, L=1024, GAMMA=5.
//
// ws layout (float offsets):
//   h      @ 0          4,194,304   [32,1024,128] fp32
//   qkvb   @ 4194304    qb/kb/--/vt bf16, 4x 4,194,304 ushorts
//   t0     @ 16777216   4,194,304
//   t1     @ 20971520   4,194,304
//   t2     @ 25165824   4,194,304   (head doubles as hbf bf16; tail: gbot/
//                                    flags/mnmx — dead once FF1 writes t2)
//   gbot   @ 27262976   32,768      f32 row-511 ring per sample
//   flags  @ 27295744   2,048       uint chunk-completion flags
//   mnmx   @ 27297792   128         per (sample, half) min/max
//   norms  @ 29360128   32,768
//   rsum   @ 29425664   32,768
//   Db/Rb  @ 29458496   (bf16) skewed D -> R in place
//   Sb     @ 46235712   (bf16) scores -> P (exp'd in smax_k), std layout
// ---------------------------------------------------------------------------

#define L_SEQ 1024
#define DM 128
#define INF_F __builtin_inff()

typedef short s16x8 __attribute__((ext_vector_type(8)));
typedef float f32x4 __attribute__((ext_vector_type(4)));
typedef unsigned short u16;

__device__ __forceinline__ float b2f(u16 u) {
    return __uint_as_float(((unsigned)u) << 16);
}
__device__ __forceinline__ u16 f2b(float f) {  // RNE
    unsigned u = __float_as_uint(f);
    return (u16)((u + 0x7FFFu + ((u >> 16) & 1u)) >> 16);
}
__device__ __forceinline__ u16 f2bt(float f) {  // truncate (cheap)
    return (u16)(__float_as_uint(f) >> 16);
}

// lane i <- lane i-1, one VALU op (DPP wave_shr:1). Lane 0 result is
// unspecified (zero w/ bound_ctrl) — always overwritten by boundary fixup.
__device__ __forceinline__ float shup1(float x) {
#if __has_builtin(__builtin_amdgcn_mov_dpp)
    return __int_as_float(
        __builtin_amdgcn_mov_dpp(__float_as_int(x), 0x138, 0xF, 0xF, true));
#else
    return __shfl_up(x, 1);
#endif
}

// ---------------- conv + pool + relu + mask + row norms --------------------
__global__ __launch_bounds__(128) void conv_k(
    const float* __restrict__ x, const float* __restrict__ w,
    const float* __restrict__ cb, const float* __restrict__ mask,
    float* __restrict__ h, u16* __restrict__ hbf, float* __restrict__ norms)
{
    int b = blockIdx.x;
    int l0 = blockIdx.y * 8;
    int d = threadIdx.x;
    __shared__ float xs[12][36];
    __shared__ float red2[8][2];
    for (int v = d; v < 12 * 35; v += 128) {
        int c = v / 35, off = v % 35;
        int gi = 4 * l0 - 2 + off;
        xs[c][off] = (gi >= 0 && gi < 4095) ? x[((long)b * 12 + c) * 4095 + gi] : 0.f;
    }
    __syncthreads();
    float s[8];
#pragma unroll
    for (int l = 0; l < 8; ++l) s[l] = 0.f;
    for (int c = 0; c < 12; ++c) {
        const float* wp = w + (d * 12 + c) * 4;
        float w0 = wp[0], w1 = wp[1], w2 = wp[2], w3 = wp[3];
        float e0 = w0, e1 = w0 + w1, e2 = w0 + w1 + w2, e3 = w0 + w1 + w2 + w3;
        float e4 = w1 + w2 + w3, e5 = w2 + w3, e6 = w3;
#pragma unroll
        for (int l = 0; l < 8; ++l) {
            int ba = 4 * l;
            s[l] += xs[c][ba] * e0 + xs[c][ba + 1] * e1 + xs[c][ba + 2] * e2 +
                    xs[c][ba + 3] * e3 + xs[c][ba + 4] * e4 + xs[c][ba + 5] * e5 +
                    xs[c][ba + 6] * e6;
        }
    }
    float cbd = cb[d];
#pragma unroll
    for (int l = 0; l < 8; ++l) {
        int gl = l0 + l;
        float val = fmaxf(cbd + 0.25f * s[l], 0.f) * mask[b * L_SEQ + gl];
        long idx = ((long)(b * L_SEQ + gl)) * DM + d;
        h[idx] = val;
        hbf[idx] = f2b(val);
        float vsq = val * val;
#pragma unroll
        for (int m = 1; m < 64; m <<= 1) vsq += __shfl_xor(vsq, m);
        if ((d & 63) == 0) red2[l][d >> 6] = vsq;
    }
    __syncthreads();
    if (d < 8) norms[(long)b * L_SEQ + l0 + d] = red2[d][0] + red2[d][1];
}

// --------------------------- MFMA bf16 GEMMs -------------------------------
enum MGMode { G_D2, G_AV };

template <int MODE>
__global__ __launch_bounds__(256) void mgemm_k(
    const u16* __restrict__ A0, const u16* __restrict__ B0, void* __restrict__ C0,
    const float* __restrict__ e0, const float* __restrict__ rsum)
{
    constexpr int LDK = (MODE == G_AV) ? 1024 : 128;
    constexpr int KK = LDK / 32;
    const int z = blockIdx.z;
    const u16* A = A0 + (MODE == G_D2 ? 0L : (long)z * 1048576L);
    const u16* B = B0 + (long)z * 131072L;
    const int tid = threadIdx.x, wv = tid >> 6, lane = tid & 63;
    const int m0 = blockIdx.x * 64, n0 = blockIdx.y * 64;
    const int co = lane & 15;
    const int q8 = (lane >> 4) << 3;
    const int mrow = m0 + 16 * wv + co;

    f32x4 acc[4];
#pragma unroll
    for (int tn = 0; tn < 4; ++tn) acc[tn] = 0.f;

    for (int kk = 0; kk < KK; ++kk) {
        const int k0 = kk * 32 + q8;
        const s16x8 a = *reinterpret_cast<const s16x8*>(A + (long)mrow * LDK + k0);
#pragma unroll
        for (int tn = 0; tn < 4; ++tn) {
            const s16x8 b = *reinterpret_cast<const s16x8*>(
                B + (long)(n0 + 16 * tn + co) * LDK + k0);
            acc[tn] = __builtin_amdgcn_mfma_f32_16x16x32_bf16(a, b, acc[tn], 0, 0, 0);
        }
    }

    const int li0 = 16 * wv + ((lane >> 4) << 2);

    if (MODE == G_D2) {
        __shared__ float Cs[64][66];
        float ni[4];
#pragma unroll
        for (int r = 0; r < 4; ++r) ni[r] = e0[m0 + li0 + r];
#pragma unroll
        for (int tn = 0; tn < 4; ++tn) {
            float nj = e0[(long)z * L_SEQ + n0 + 16 * tn + co];
#pragma unroll
            for (int r = 0; r < 4; ++r)
                Cs[li0 + r][16 * tn + co] = ni[r] + nj - 2.f * acc[tn][r];
        }
        __syncthreads();
        u16* Cu = (u16*)C0 + (long)z * 1048576L;
        for (int q = 0; q < 32; ++q) {
            int dd = wv * 32 + q;
            if (dd < 127) {
                int d = m0 + n0 + dd;
                int ilo = max(m0, d - n0 - 63);
                int ihi = min(m0 + 63, d - n0);
                int i = ilo + lane;
                if (i <= ihi)
                    Cu[(long)(((d & 1023) << 10) + i)] = f2b(Cs[i - m0][d - n0 - i]);
            }
        }
        return;
    }
    // G_AV: out = (P . V) * rsuminv[row], fp32
    {
        float* Cf = (float*)C0 + (long)z * 131072L;
        float rsv[4];
#pragma unroll
        for (int r = 0; r < 4; ++r) rsv[r] = rsum[(long)z * L_SEQ + m0 + li0 + r];
#pragma unroll
        for (int tn = 0; tn < 4; ++tn)
#pragma unroll
            for (int r = 0; r < 4; ++r)
                Cf[(long)(m0 + li0 + r) * 128 + n0 + 16 * tn + co] =
                    acc[tn][r] * rsv[r];
    }
}

// ---------------------- SC (MFMA scores), one launch -----------------------
__global__ __launch_bounds__(256) void sc_k(
    const u16* __restrict__ qb, const u16* __restrict__ kb, u16* __restrict__ Sb,
    const float* __restrict__ mnmx, const float* __restrict__ mask,
    const u16* __restrict__ Rb)
{
    const int s = blockIdx.x;
    const int tid = threadIdx.x;
    __shared__ float Rs[64][66];

    const int z = s >> 8;
    const int m0 = (s & 15) * 64, n0 = ((s >> 4) & 15) * 64;
    const u16* A = qb + (long)z * 131072L;
    const u16* B = kb + (long)z * 131072L;
    const int wv = tid >> 6, lane = tid & 63;
    const int co = lane & 15;
    const int q8 = (lane >> 4) << 3;
    const int mrow = m0 + 16 * wv + co;

    f32x4 acc[4];
#pragma unroll
    for (int tn = 0; tn < 4; ++tn) acc[tn] = 0.f;
    for (int kk = 0; kk < 4; ++kk) {
        const int k0 = kk * 32 + q8;
        const s16x8 a = *reinterpret_cast<const s16x8*>(A + (long)mrow * 128 + k0);
#pragma unroll
        for (int tn = 0; tn < 4; ++tn) {
            const s16x8 b = *reinterpret_cast<const s16x8*>(
                B + (long)(n0 + 16 * tn + co) * 128 + k0);
            acc[tn] = __builtin_amdgcn_mfma_f32_16x16x32_bf16(a, b, acc[tn], 0, 0, 0);
        }
    }
    const int li0 = 16 * wv + ((lane >> 4) << 2);
    const u16* Rz = Rb + (long)z * 1048576L;
    for (int q = 0; q < 32; ++q) {   // destage skewed R -> LDS
        int dd = wv * 32 + q;
        if (dd < 127) {
            int d = m0 + n0 + dd;
            int ilo = max(m0, d - n0 - 63);
            int ihi = min(m0 + 63, d - n0);
            int i = ilo + lane;
            if (i <= ihi)
                Rs[i - m0][d - n0 - i] = b2f(Rz[(long)(((d & 1023) << 10) + i)]);
        }
    }
    __syncthreads();
    float mn = fminf(mnmx[4 * z + 0], mnmx[4 * z + 2]);
    float mx = fmaxf(mnmx[4 * z + 1], mnmx[4 * z + 3]);
    float inv = 1.f / (mx - mn);
    u16* Cu = Sb + (long)z * 1048576L;
#pragma unroll
    for (int tn = 0; tn < 4; ++tn) {
        int gj = n0 + 16 * tn + co;
        float kp = (mask[(long)z * L_SEQ + gj] > 0.f) ? 0.f : -INF_F;
#pragma unroll
        for (int r = 0; r < 4; ++r) {
            float val = acc[tn][r] * 0.08838834764831845f +
                        (Rs[li0 + r][16 * tn + co] - mn) * inv + 1.f + kp;
            Cu[(long)(m0 + li0 + r) * 1024 + gj] = f2b(val);
        }
    }
}

// ------------------------------ fp32 GEMMs ---------------------------------
enum GMode { M_WOUT, M_FF1, M_FF2, M_LIN };

template <int MODE>
__global__ __launch_bounds__(256) void gemm_k(
    const float* __restrict__ A, const float* __restrict__ B, float* __restrict__ C,
    int N, int ldc,
    const float* __restrict__ e0, const float* __restrict__ e1)
{
    __shared__ float As[16][65];
    __shared__ float Bs[16][65];
    int tid = threadIdx.x;
    int tx = tid & 15, ty = tid >> 4;
    int m0 = blockIdx.x * 64, n0 = blockIdx.y * 64;
    float acc[4][4] = {};
    int am = tid >> 2;
    int ak = (tid & 3) << 2;

    for (int kk = 0; kk < 128; kk += 16) {
        {
            const float4 av =
                *reinterpret_cast<const float4*>(A + (long)(m0 + am) * 128 + kk + ak);
            As[ak + 0][am] = av.x;
            As[ak + 1][am] = av.y;
            As[ak + 2][am] = av.z;
            As[ak + 3][am] = av.w;
        }
        {
            int n = n0 + am;
            float4 bv = {0.f, 0.f, 0.f, 0.f};
            if (n < N)
                bv = *reinterpret_cast<const float4*>(B + (long)n * 128 + kk + ak);
            Bs[ak + 0][am] = bv.x;
            Bs[ak + 1][am] = bv.y;
            Bs[ak + 2][am] = bv.z;
            Bs[ak + 3][am] = bv.w;
        }
        __syncthreads();
#pragma unroll
        for (int kc = 0; kc < 16; ++kc) {
            float a0 = As[kc][ty * 4 + 0], a1 = As[kc][ty * 4 + 1];
            float a2 = As[kc][ty * 4 + 2], a3 = As[kc][ty * 4 + 3];
            float b0 = Bs[kc][tx * 4 + 0], b1 = Bs[kc][tx * 4 + 1];
            float b2 = Bs[kc][tx * 4 + 2], b3 = Bs[kc][tx * 4 + 3];
            acc[0][0] += a0 * b0; acc[0][1] += a0 * b1; acc[0][2] += a0 * b2; acc[0][3] += a0 * b3;
            acc[1][0] += a1 * b0; acc[1][1] += a1 * b1; acc[1][2] += a1 * b2; acc[1][3] += a1 * b3;
            acc[2][0] += a2 * b0; acc[2][1] += a2 * b1; acc[2][2] += a2 * b2; acc[2][3] += a2 * b3;
            acc[3][0] += a3 * b0; acc[3][1] += a3 * b1; acc[3][2] += a3 * b2; acc[3][3] += a3 * b3;
        }
        __syncthreads();
    }

#pragma unroll
    for (int i = 0; i < 4; ++i) {
        int gi = m0 + ty * 4 + i;
#pragma unroll
        for (int j = 0; j < 4; ++j) {
            int gj = n0 + tx * 4 + j;
            float v = acc[i][j];
            long idx = (long)gi * ldc + gj;
            if (MODE == M_WOUT) {
                C[idx] = v + e0[gj] + e1[idx];
            } else if (MODE == M_FF1) {
                C[idx] = fmaxf(v + e0[gj], 0.f);
            } else if (MODE == M_FF2) {
                C[idx] = v + e0[gj] + e1[idx];
            } else if (MODE == M_LIN) {
                if (gj < N) C[idx] = v * e0[gi];
            }
        }
    }
}

// ------------------------------- soft-DTW ----------------------------------
// 2 blocks/sample; global wave W = 8*hb + w owns rows [64W, 64W+64), lane i
// owns row 64W+i (skew 1). Cross-lane via DPP wave_shr:1; cross-wave via LDS
// ring; cross-block (511->512) via gbot + flags (device-scope atomics).
// Chunk = 32 steps; wave W runs chunk c at epoch c+W.
__device__ __forceinline__ float softmin3(float d, float rl, float ru, float rul)
{
    float mn = fminf(rul, fminf(ru, rl));
    float md = fmaxf(fminf(rul, ru), fminf(fmaxf(rul, ru), rl));
    float mx = fmaxf(rul, fmaxf(ru, rl));
    float s = 1.f + __expf((mn - md) * 0.2f) + __expf((mn - mx) * 0.2f);
    return d + mn - 5.0f * __logf(s);
}

template <bool EDGE>
__device__ __forceinline__ void dtw_chunk1(
    u16* __restrict__ R, const float* __restrict__ botp, float* __restrict__ botw,
    float* __restrict__ gb, int W, int lane, bool lane0, int rowbase, int row,
    int T0, bool useG,
    float& cur, float& upc, float& upp, float& vmin, float& vmax,
    float (&dbuf)[8], float (&bb)[9])
{
    u16* rp = R + (((T0 & 1023) << 10) + row);
    const bool w0 = (W == 0);
    for (int g = 0; g < 4; ++g) {
        const int tg = T0 + (g << 3);
        float dn[8];
#pragma unroll
        for (int s = 0; s < 8; ++s)
            dn[s] = b2f(R[((((tg + 8 + s) & 1023) << 10) + row)]);
        float bn[9];
        if (W > 0 && g < 3) {
            const int jn = tg + 7 - rowbase;
            if (useG) {
                if (lane0) {
#pragma unroll
                    for (int q = 0; q < 9; ++q)
                        bn[q] = atomicAdd(gb + min(max(jn + q, 0), 1023), 0.f);
                }
            } else {
#pragma unroll
                for (int q = 0; q < 9; ++q) bn[q] = botp[(jn + q) & 511];
            }
        }
#pragma unroll
        for (int s = 0; s < 8; ++s) {
            const int t = tg + s;
            const int j = t - row;
            // branch-free lane0 boundary fixups
            float ru = lane0 ? (w0 ? INF_F : bb[s + 1]) : upc;
            float rul = upp;
            if (EDGE) {
                rul = lane0 ? (w0 ? ((j == 0) ? 0.f : INF_F)
                                  : ((j < 1) ? INF_F : upp))
                            : upp;
            } else {
                rul = (lane0 && w0) ? INF_F : rul;
            }
            float n = softmin3(dbuf[s], cur, ru, rul);
            if (EDGE) {
                bool v = ((unsigned)j < 1024u);
                n = v ? n : INF_F;
                vmin = fminf(vmin, n);
                vmax = v ? fmaxf(vmax, n) : vmax;
                if (v) rp[0] = f2bt(n);
                if (lane == 63 && v) {
                    if (W == 7) atomicExch(gb + j, n);
                    else if ((W & 7) != 7) botw[j & 511] = n;
                }
            } else {
                vmin = fminf(vmin, n);
                vmax = fmaxf(vmax, n);
                rp[0] = f2bt(n);
                if (lane == 63) {
                    if (W == 7) atomicExch(gb + j, n);
                    else if ((W & 7) != 7) botw[j & 511] = n;
                }
            }
            upp = ru;
            cur = n;
            upc = shup1(n);     // DPP wave_shr:1 — VALU latency, no LDS wait
            rp += 1024;
        }
#pragma unroll
        for (int s = 0; s < 8; ++s) dbuf[s] = dn[s];
        if (W > 0 && g < 3) {
#pragma unroll
            for (int q = 0; q < 9; ++q) bb[q] = bn[q];
        }
    }
}

// dtw (blocks 0..63: 2 per sample) + QKV backfill (blocks 64..1599)
__global__ __launch_bounds__(512) void dtw_qkv_k(
    u16* __restrict__ Rb, float* __restrict__ minmax,
    float* __restrict__ gbot, unsigned* __restrict__ flags,
    const float* __restrict__ h, const float* __restrict__ w_in,
    const float* __restrict__ b_in, u16* __restrict__ qb, u16* __restrict__ vt)
{
    __shared__ float bot[7][512];
    __shared__ float rmn[512];
    __shared__ float rmx[512];
    __shared__ float As[2][16][65];
    __shared__ float Bs[2][16][65];
    __shared__ u16 Tt[2][64][65];

    if (blockIdx.x >= 64) {
        // ---- QKV backfill: two 64x64 tiles per 512-thread block ----
        const int half = threadIdx.x >> 8;
        const int tid = threadIdx.x & 255;
        const int t = ((blockIdx.x - 64) << 1) + half;   // 0..3071
        const int m0 = (t & 511) << 6;
        const int n0 = (t >> 9) << 6;                    // block-uniform
        int tx = tid & 15, ty = tid >> 4;
        float acc[4][4] = {};
        int am = tid >> 2;
        int ak = (tid & 3) << 2;
        for (int kk = 0; kk < 128; kk += 16) {
            {
                const float4 av = *reinterpret_cast<const float4*>(
                    h + (long)(m0 + am) * 128 + kk + ak);
                As[half][ak + 0][am] = av.x;
                As[half][ak + 1][am] = av.y;
                As[half][ak + 2][am] = av.z;
                As[half][ak + 3][am] = av.w;
            }
            {
                const float4 bv = *reinterpret_cast<const float4*>(
                    w_in + (long)(n0 + am) * 128 + kk + ak);
                Bs[half][ak + 0][am] = bv.x;
                Bs[half][ak + 1][am] = bv.y;
                Bs[half][ak + 2][am] = bv.z;
                Bs[half][ak + 3][am] = bv.w;
            }
            __syncthreads();
#pragma unroll
            for (int kc = 0; kc < 16; ++kc) {
                float a0 = As[half][kc][ty * 4 + 0], a1 = As[half][kc][ty * 4 + 1];
                float a2 = As[half][kc][ty * 4 + 2], a3 = As[half][kc][ty * 4 + 3];
                float b0 = Bs[half][kc][tx * 4 + 0], b1 = Bs[half][kc][tx * 4 + 1];
                float b2 = Bs[half][kc][tx * 4 + 2], b3 = Bs[half][kc][tx * 4 + 3];
                acc[0][0] += a0 * b0; acc[0][1] += a0 * b1; acc[0][2] += a0 * b2; acc[0][3] += a0 * b3;
                acc[1][0] += a1 * b0; acc[1][1] += a1 * b1; acc[1][2] += a1 * b2; acc[1][3] += a1 * b3;
                acc[2][0] += a2 * b0; acc[2][1] += a2 * b1; acc[2][2] += a2 * b2; acc[2][3] += a2 * b3;
                acc[3][0] += a3 * b0; acc[3][1] += a3 * b1; acc[3][2] += a3 * b2; acc[3][3] += a3 * b3;
            }
            __syncthreads();
        }
        if (n0 >= 256) {
            // v-tile: write TRANSPOSED into vt [d,1024] via LDS
#pragma unroll
            for (int i = 0; i < 4; ++i)
#pragma unroll
                for (int j = 0; j < 4; ++j)
                    Tt[half][tx * 4 + j][ty * 4 + i] =
                        f2b(acc[i][j] + b_in[n0 + tx * 4 + j]);
            __syncthreads();
            const int z = m0 >> 10;
            const int lbase = m0 & 1023;
            const int dbase = n0 - 256;
            u16* dst = vt + (long)z * 131072L;
#pragma unroll
            for (int i = 0; i < 16; ++i) {
                int idx = tid + 256 * i;
                int dj = idx >> 6, li = idx & 63;
                dst[(long)(dbase + dj) * 1024 + lbase + li] = Tt[half][dj][li];
            }
            return;
        }
        u16* Cu = qb + ((long)(n0 >> 7)) * 4194304L;
        int cb = (n0 & 127) + tx * 4;
#pragma unroll
        for (int i = 0; i < 4; ++i) {
            int gi = m0 + ty * 4 + i;
            ushort4 sv;
            u16* svp = &sv.x;
#pragma unroll
            for (int j = 0; j < 4; ++j)
                svp[j] = f2b(acc[i][j] + b_in[n0 + tx * 4 + j]);
            *reinterpret_cast<ushort4*>(Cu + (long)gi * 128 + cb) = sv;
        }
        return;
    }

    // ------------------------------- dtw ---------------------------------
    const int z = blockIdx.x >> 1;
    const int hb = blockIdx.x & 1;
    u16* R = Rb + (long)z * 1048576L;
    float* gb = gbot + z * 1024;
    unsigned* flag = flags + z * 64;
    const int tid = threadIdx.x;
    const int w = tid >> 6;
    const int lane = tid & 63;
    const bool lane0 = (lane == 0);
    const int W = 8 * hb + w;
    const int rowbase = 64 * W;
    const int row = rowbase + lane;
    const bool useG = (hb == 1 && w == 0);

    float* botw = (w < 7) ? bot[w] : bot[0];
    const float* botp = (w > 0) ? bot[w - 1] : bot[0];

    float cur = INF_F, upc = INF_F, upp = INF_F;
    float vmin = INF_F, vmax = -INF_F;
    float dbuf[8];
    float bb[9];
#pragma unroll
    for (int q = 0; q < 9; ++q) bb[q] = 0.f;

    const int fc = 2 * W;
    for (int e = 0; e < 79; ++e) {
        const int c = e - W;
        const int o = c - fc;
        if (o >= 0 && o <= 33) {
            const int T0 = c << 5;
            if (useG && c <= 47) {   // wait for b0 wave7 to finish chunk c
                unsigned fv = 0;
                do {
                    unsigned t0v = 1;
                    if (lane0) t0v = atomicAdd(&flag[c], 0u);
                    fv = (unsigned)__shfl((int)t0v, 0);
                } while (fv == 0);
            }
            if (o == 0) {   // prime D queue (8 steps)
#pragma unroll
                for (int s = 0; s < 8; ++s)
                    dbuf[s] = b2f(R[((((T0 + s) & 1023) << 10) + row)]);
            }
            if (W > 0) {    // bot columns for the chunk's first group
                const int jb = T0 - rowbase - 1;
                if (useG) {
                    if (lane0) {
#pragma unroll
                        for (int q = 0; q < 9; ++q)
                            bb[q] = atomicAdd(gb + min(max(jb + q, 0), 1023), 0.f);
                    }
                } else {
#pragma unroll
                    for (int q = 0; q < 9; ++q) bb[q] = botp[(jb + q) & 511];
                }
            }
            if (o < 2 || o >= 32)
                dtw_chunk1<true>(R, botp, botw, gb, W, lane, lane0, rowbase, row,
                                 T0, useG, cur, upc, upp, vmin, vmax, dbuf, bb);
            else
                dtw_chunk1<false>(R, botp, botw, gb, W, lane, lane0, rowbase, row,
                                  T0, useG, cur, upc, upp, vmin, vmax, dbuf, bb);
        }
        __syncthreads();
        if (hb == 0 && tid == 0) {
            int c7 = e - 7;
            if (c7 >= 14 && c7 <= 47) {
                __threadfence();
                atomicExch(&flag[c7], 1u);
            }
        }
    }

    rmn[tid] = vmin;
    rmx[tid] = vmax;
    __syncthreads();
    for (int s2 = 256; s2 > 0; s2 >>= 1) {
        if (tid < s2) {
            rmn[tid] = fminf(rmn[tid], rmn[tid + s2]);
            rmx[tid] = fmaxf(rmx[tid], rmx[tid + s2]);
        }
        __syncthreads();
    }
    if (tid == 0) {
        minmax[z * 4 + hb * 2 + 0] = rmn[0];
        minmax[z * 4 + hb * 2 + 1] = rmx[0];
    }
}

// ---------- softmax row stats + in-place P = exp(s-max), wave/row ----------
__global__ __launch_bounds__(256) void smax_k(u16* __restrict__ S,
                                              float* __restrict__ rsuminv)
{
    long row = (long)blockIdx.x * 4 + (threadIdx.x >> 6);
    int lane = threadIdx.x & 63;
    u16* p = S + row * L_SEQ + lane * 16;
    ushort4 v[4];
#pragma unroll
    for (int q = 0; q < 4; ++q) v[q] = reinterpret_cast<ushort4*>(p)[q];
    float f[16];
#pragma unroll
    for (int q = 0; q < 4; ++q) {
        f[4 * q + 0] = b2f(v[q].x);
        f[4 * q + 1] = b2f(v[q].y);
        f[4 * q + 2] = b2f(v[q].z);
        f[4 * q + 3] = b2f(v[q].w);
    }
    float m = f[0];
#pragma unroll
    for (int i = 1; i < 16; ++i) m = fmaxf(m, f[i]);
#pragma unroll
    for (int d2 = 1; d2 < 64; d2 <<= 1) m = fmaxf(m, __shfl_xor(m, d2));
    float s = 0.f;
#pragma unroll
    for (int i = 0; i < 16; ++i) {
        f[i] = __expf(f[i] - m);
        s += f[i];
    }
#pragma unroll
    for (int q = 0; q < 4; ++q) {
        ushort4 pv;
        pv.x = f2b(f[4 * q + 0]);
        pv.y = f2b(f[4 * q + 1]);
        pv.z = f2b(f[4 * q + 2]);
        pv.w = f2b(f[4 * q + 3]);
        reinterpret_cast<ushort4*>(p)[q] = pv;
    }
#pragma unroll
    for (int d2 = 1; d2 < 64; d2 <<= 1) s += __shfl_xor(s, d2);
    if (lane == 0) rsuminv[row] = 1.f / s;
}

// -------------------------- layernorm (wave/row) ---------------------------
__global__ __launch_bounds__(256) void ln_k(float* __restrict__ X,
                                            const float* __restrict__ g,
                                            const float* __restrict__ b)
{
    long row = (long)blockIdx.x * 4 + (threadIdx.x >> 6);
    int lane = threadIdx.x & 63;
    float2 x = *reinterpret_cast<float2*>(X + row * DM + lane * 2);
    float s = x.x + x.y;
    float q = x.x * x.x + x.y * x.y;
#pragma unroll
    for (int m = 1; m < 64; m <<= 1) {
        s += __shfl_xor(s, m);
        q += __shfl_xor(q, m);
    }
    float mean = s * (1.f / 128.f);
    float var = q * (1.f / 128.f) - mean * mean;
    float rstd = rsqrtf(var + 1e-5f);
    float2 o;
    o.x = (x.x - mean) * rstd * g[lane * 2 + 0] + b[lane * 2 + 0];
    o.y = (x.y - mean) * rstd * g[lane * 2 + 1] + b[lane * 2 + 1];
    *reinterpret_cast<float2*>(X + row * DM + lane * 2) = o;
}

// -------------------------------- lengths ----------------------------------
__global__ __launch_bounds__(256) void len_k(const float* __restrict__ mask,
                                             float* __restrict__ out)
{
    int b = blockIdx.x;
    int t = threadIdx.x;
    const float4 v = reinterpret_cast<const float4*>(mask + b * L_SEQ)[t];
    __shared__ float red[256];
    red[t] = v.x + v.y + v.z + v.w;
    __syncthreads();
    for (int s = 128; s > 0; s >>= 1) {
        if (t < s) red[t] += red[t + s];
        __syncthreads();
    }
    if (t == 0) out[b] = red[0];
}

// ------------------------------- launcher ----------------------------------
extern "C" void kernel_launch(void* const* d_in, const int* in_sizes, int n_in,
                              void* d_out, int out_size, void* d_ws, size_t ws_size,
                              hipStream_t stream)
{
    const float* x      = (const float*)d_in[0];
    const float* mask   = (const float*)d_in[1];
    const float* conv_w = (const float*)d_in[2];
    const float* conv_b = (const float*)d_in[3];
    const float* w_in   = (const float*)d_in[4];
    const float* b_in   = (const float*)d_in[5];
    const float* w_out  = (const float*)d_in[6];
    const float* b_out  = (const float*)d_in[7];
    const float* w_ff1  = (const float*)d_in[8];
    const float* b_ff1  = (const float*)d_in[9];
    const float* w_ff2  = (const float*)d_in[10];
    const float* b_ff2  = (const float*)d_in[11];
    const float* ln1_g  = (const float*)d_in[12];
    const float* ln1_b  = (const float*)d_in[13];
    const float* ln2_g  = (const float*)d_in[14];
    const float* ln2_b  = (const float*)d_in[15];
    const float* w_lin  = (const float*)d_in[16];
    float* out = (float*)d_out;

    float* ws    = (float*)d_ws;
    float* h     = ws;
    u16*   qb    = (u16*)(ws + 4194304L);
    u16*   kb    = qb + 4194304L;
    u16*   vt    = qb + 12582912L;
    float* t0    = ws + 16777216L;
    float* t1    = ws + 20971520L;
    float* t2    = ws + 25165824L;
    u16*   hbf   = (u16*)t2;                  // head of t2, free until FF1
    float* gbot  = ws + 27262976L;            // tail of t2, free until FF1
    unsigned* flags = (unsigned*)(ws + 27295744L);
    float* mnmx  = ws + 27297792L;
    float* norms = ws + 29360128L;
    float* rsum  = ws + 29425664L;
    u16*   Db    = (u16*)(ws + 29458496L);    // skewed D/R bf16
    u16*   Sb    = (u16*)(ws + 46235712L);    // scores -> P bf16, std layout

    conv_k<<<dim3(32, 128), 128, 0, stream>>>(x, conv_w, conv_b, mask, h, hbf, norms);
    mgemm_k<G_D2><<<dim3(16, 16, 32), 256, 0, stream>>>(
        hbf, hbf, Db, norms, nullptr);
    hipMemsetAsync(flags, 0, 2048 * sizeof(unsigned), stream);
    // dtw (64 blocks, 2/sample) + qkv backfill (1536 blocks, writes qb/kb/vt)
    dtw_qkv_k<<<1600, 512, 0, stream>>>(Db, mnmx, gbot, flags, h, w_in, b_in,
                                        qb, vt);
    sc_k<<<8192, 256, 0, stream>>>(qb, kb, Sb, mnmx, mask, Db);
    smax_k<<<8192, 256, 0, stream>>>(Sb, rsum);
    mgemm_k<G_AV><<<dim3(16, 2, 32), 256, 0, stream>>>(
        Sb, vt, t0, nullptr, rsum);
    gemm_k<M_WOUT><<<dim3(512, 2), 256, 0, stream>>>(
        t0, w_out, t1, 128, 128, b_out, h);
    ln_k<<<8192, 256, 0, stream>>>(t1, ln1_g, ln1_b);
    gemm_k<M_FF1><<<dim3(512, 2), 256, 0, stream>>>(
        t1, w_ff1, t2, 128, 128, b_ff1, nullptr);
    gemm_k<M_FF2><<<dim3(512, 2), 256, 0, stream>>>(
        t2, w_ff2, t0, 128, 128, b_ff2, t1);
    ln_k<<<8192, 256, 0, stream>>>(t0, ln2_g, ln2_b);
    gemm_k<M_LIN><<<dim3(512, 1), 256, 0, stream>>>(
        t0, w_lin, out, 16, 16, mask, nullptr);
    len_k<<<32, 256, 0, stream>>>(mask, out + 32768L * 16);
}

// Round 12
// 1090.330 us; speedup vs baseline: 2.5657x; 1.0894x over previous
//
#include <hip/hip_runtime.h>
#include <math.h>

// ---------------------------------------------------------------------------
// DsDTW pipeline (round 12):
//  - dtw cross-block handoff: acquire-flag spin + parallel agent-scope loads
//    into LDS window (replaces 9x serialized atomicAdd RMWs per group).
//  - weight GEMMs (wout/ff1/ff2/lin) converted to bf16 MFMA; AV + LN emit
//    bf16 shadows; weights converted once into the dead norms region.
// B=32, C_IN=12, T=4095, D=128, L=1024, GAMMA=5.
//
// ws (float offsets):
//   h     @ 0         [32,1024,128] f32 (dead after wout)
//   qkvb  @ 4194304   u16 slots: qb / kb / t0b / vt (4x 4,194,304 u16)
//   t0    @ 16777216  f32 (ff2 out, ln2 in-place)
//   t1    @ 20971520  f32 (wout out, ln1 in-place, ff2 residual)
//   t1b   @ 25165824  u16 (ln1 bf16; overlaps dead hbf)
//   t2b   @ 27262976  u16 (ff1 bf16; overlaps dead gbot/flags/mnmx)
//   gbot  @ 27262976  f32 ring (dead after dtw)      | flags @ 27295744
//   mnmx  @ 27297792  (dead after sc)                |
//   norms @ 29360128  f32 (D2 only) -> then woutb/wff1b/wff2b/wlinb u16
//   rsum  @ 29425664
//   Db    @ 29458496  u16 skewed D->R     Sb @ 46235712 u16 scores->P
// ---------------------------------------------------------------------------

#define L_SEQ 1024
#define DM 128
#define INF_F __builtin_inff()

typedef short s16x8 __attribute__((ext_vector_type(8)));
typedef float f32x4 __attribute__((ext_vector_type(4)));
typedef unsigned short u16;

__device__ __forceinline__ float b2f(u16 u) {
    return __uint_as_float(((unsigned)u) << 16);
}
__device__ __forceinline__ u16 f2b(float f) {  // RNE
    unsigned u = __float_as_uint(f);
    return (u16)((u + 0x7FFFu + ((u >> 16) & 1u)) >> 16);
}
__device__ __forceinline__ u16 f2bt(float f) {  // truncate (cheap)
    return (u16)(__float_as_uint(f) >> 16);
}

__device__ __forceinline__ float shup1(float x) {
#if __has_builtin(__builtin_amdgcn_mov_dpp)
    return __int_as_float(
        __builtin_amdgcn_mov_dpp(__float_as_int(x), 0x138, 0xF, 0xF, true));
#else
    return __shfl_up(x, 1);
#endif
}

// ---------------- conv + pool + relu + mask + row norms --------------------
__global__ __launch_bounds__(128) void conv_k(
    const float* __restrict__ x, const float* __restrict__ w,
    const float* __restrict__ cb, const float* __restrict__ mask,
    float* __restrict__ h, u16* __restrict__ hbf, float* __restrict__ norms)
{
    int b = blockIdx.x;
    int l0 = blockIdx.y * 8;
    int d = threadIdx.x;
    __shared__ float xs[12][36];
    __shared__ float red2[8][2];
    for (int v = d; v < 12 * 35; v += 128) {
        int c = v / 35, off = v % 35;
        int gi = 4 * l0 - 2 + off;
        xs[c][off] = (gi >= 0 && gi < 4095) ? x[((long)b * 12 + c) * 4095 + gi] : 0.f;
    }
    __syncthreads();
    float s[8];
#pragma unroll
    for (int l = 0; l < 8; ++l) s[l] = 0.f;
    for (int c = 0; c < 12; ++c) {
        const float* wp = w + (d * 12 + c) * 4;
        float w0 = wp[0], w1 = wp[1], w2 = wp[2], w3 = wp[3];
        float e0 = w0, e1 = w0 + w1, e2 = w0 + w1 + w2, e3 = w0 + w1 + w2 + w3;
        float e4 = w1 + w2 + w3, e5 = w2 + w3, e6 = w3;
#pragma unroll
        for (int l = 0; l < 8; ++l) {
            int ba = 4 * l;
            s[l] += xs[c][ba] * e0 + xs[c][ba + 1] * e1 + xs[c][ba + 2] * e2 +
                    xs[c][ba + 3] * e3 + xs[c][ba + 4] * e4 + xs[c][ba + 5] * e5 +
                    xs[c][ba + 6] * e6;
        }
    }
    float cbd = cb[d];
#pragma unroll
    for (int l = 0; l < 8; ++l) {
        int gl = l0 + l;
        float val = fmaxf(cbd + 0.25f * s[l], 0.f) * mask[b * L_SEQ + gl];
        long idx = ((long)(b * L_SEQ + gl)) * DM + d;
        h[idx] = val;
        hbf[idx] = f2b(val);
        float vsq = val * val;
#pragma unroll
        for (int m = 1; m < 64; m <<= 1) vsq += __shfl_xor(vsq, m);
        if ((d & 63) == 0) red2[l][d >> 6] = vsq;
    }
    __syncthreads();
    if (d < 8) norms[(long)b * L_SEQ + l0 + d] = red2[d][0] + red2[d][1];
}

// ----------------------- weight fp32 -> bf16 convert -----------------------
__global__ __launch_bounds__(256) void wcvt_k(
    const float* __restrict__ w1, const float* __restrict__ w2,
    const float* __restrict__ w3, const float* __restrict__ w4,
    u16* __restrict__ o)
{
    int i = blockIdx.x * 256 + threadIdx.x;   // grid 200 -> 51200
    float v;
    if (i < 16384) v = w1[i];
    else if (i < 32768) v = w2[i - 16384];
    else if (i < 49152) v = w3[i - 32768];
    else v = w4[i - 49152];
    o[i] = f2b(v);
}

// --------------------------- MFMA bf16 GEMMs -------------------------------
enum MGMode { G_D2, G_AV };

template <int MODE>
__global__ __launch_bounds__(256) void mgemm_k(
    const u16* __restrict__ A0, const u16* __restrict__ B0, void* __restrict__ C0,
    const float* __restrict__ e0, const float* __restrict__ rsum)
{
    constexpr int LDK = (MODE == G_AV) ? 1024 : 128;
    constexpr int KK = LDK / 32;
    const int z = blockIdx.z;
    const u16* A = A0 + (MODE == G_D2 ? 0L : (long)z * 1048576L);
    const u16* B = B0 + (long)z * 131072L;
    const int tid = threadIdx.x, wv = tid >> 6, lane = tid & 63;
    const int m0 = blockIdx.x * 64, n0 = blockIdx.y * 64;
    const int co = lane & 15;
    const int q8 = (lane >> 4) << 3;
    const int mrow = m0 + 16 * wv + co;

    f32x4 acc[4];
#pragma unroll
    for (int tn = 0; tn < 4; ++tn) acc[tn] = 0.f;

    for (int kk = 0; kk < KK; ++kk) {
        const int k0 = kk * 32 + q8;
        const s16x8 a = *reinterpret_cast<const s16x8*>(A + (long)mrow * LDK + k0);
#pragma unroll
        for (int tn = 0; tn < 4; ++tn) {
            const s16x8 b = *reinterpret_cast<const s16x8*>(
                B + (long)(n0 + 16 * tn + co) * LDK + k0);
            acc[tn] = __builtin_amdgcn_mfma_f32_16x16x32_bf16(a, b, acc[tn], 0, 0, 0);
        }
    }

    const int li0 = 16 * wv + ((lane >> 4) << 2);

    if (MODE == G_D2) {
        __shared__ float Cs[64][66];
        float ni[4];
#pragma unroll
        for (int r = 0; r < 4; ++r) ni[r] = e0[m0 + li0 + r];
#pragma unroll
        for (int tn = 0; tn < 4; ++tn) {
            float nj = e0[(long)z * L_SEQ + n0 + 16 * tn + co];
#pragma unroll
            for (int r = 0; r < 4; ++r)
                Cs[li0 + r][16 * tn + co] = ni[r] + nj - 2.f * acc[tn][r];
        }
        __syncthreads();
        u16* Cu = (u16*)C0 + (long)z * 1048576L;
        for (int q = 0; q < 32; ++q) {
            int dd = wv * 32 + q;
            if (dd < 127) {
                int d = m0 + n0 + dd;
                int ilo = max(m0, d - n0 - 63);
                int ihi = min(m0 + 63, d - n0);
                int i = ilo + lane;
                if (i <= ihi)
                    Cu[(long)(((d & 1023) << 10) + i)] = f2b(Cs[i - m0][d - n0 - i]);
            }
        }
        return;
    }
    // G_AV: t0b (bf16) = (P . V) * rsuminv[row]
    {
        u16* Cb = (u16*)C0 + (long)z * 131072L;
        float rsv[4];
#pragma unroll
        for (int r = 0; r < 4; ++r) rsv[r] = rsum[(long)z * L_SEQ + m0 + li0 + r];
#pragma unroll
        for (int tn = 0; tn < 4; ++tn)
#pragma unroll
            for (int r = 0; r < 4; ++r)
                Cb[(long)(m0 + li0 + r) * 128 + n0 + 16 * tn + co] =
                    f2b(acc[tn][r] * rsv[r]);
    }
}

// ---------------------- SC (MFMA scores), one launch -----------------------
__global__ __launch_bounds__(256) void sc_k(
    const u16* __restrict__ qb, const u16* __restrict__ kb, u16* __restrict__ Sb,
    const float* __restrict__ mnmx, const float* __restrict__ mask,
    const u16* __restrict__ Rb)
{
    const int s = blockIdx.x;
    const int tid = threadIdx.x;
    __shared__ float Rs[64][66];

    const int z = s >> 8;
    const int m0 = (s & 15) * 64, n0 = ((s >> 4) & 15) * 64;
    const u16* A = qb + (long)z * 131072L;
    const u16* B = kb + (long)z * 131072L;
    const int wv = tid >> 6, lane = tid & 63;
    const int co = lane & 15;
    const int q8 = (lane >> 4) << 3;
    const int mrow = m0 + 16 * wv + co;

    f32x4 acc[4];
#pragma unroll
    for (int tn = 0; tn < 4; ++tn) acc[tn] = 0.f;
    for (int kk = 0; kk < 4; ++kk) {
        const int k0 = kk * 32 + q8;
        const s16x8 a = *reinterpret_cast<const s16x8*>(A + (long)mrow * 128 + k0);
#pragma unroll
        for (int tn = 0; tn < 4; ++tn) {
            const s16x8 b = *reinterpret_cast<const s16x8*>(
                B + (long)(n0 + 16 * tn + co) * 128 + k0);
            acc[tn] = __builtin_amdgcn_mfma_f32_16x16x32_bf16(a, b, acc[tn], 0, 0, 0);
        }
    }
    const int li0 = 16 * wv + ((lane >> 4) << 2);
    const u16* Rz = Rb + (long)z * 1048576L;
    for (int q = 0; q < 32; ++q) {
        int dd = wv * 32 + q;
        if (dd < 127) {
            int d = m0 + n0 + dd;
            int ilo = max(m0, d - n0 - 63);
            int ihi = min(m0 + 63, d - n0);
            int i = ilo + lane;
            if (i <= ihi)
                Rs[i - m0][d - n0 - i] = b2f(Rz[(long)(((d & 1023) << 10) + i)]);
        }
    }
    __syncthreads();
    float mn = fminf(mnmx[4 * z + 0], mnmx[4 * z + 2]);
    float mx = fmaxf(mnmx[4 * z + 1], mnmx[4 * z + 3]);
    float inv = 1.f / (mx - mn);
    u16* Cu = Sb + (long)z * 1048576L;
#pragma unroll
    for (int tn = 0; tn < 4; ++tn) {
        int gj = n0 + 16 * tn + co;
        float kp = (mask[(long)z * L_SEQ + gj] > 0.f) ? 0.f : -INF_F;
#pragma unroll
        for (int r = 0; r < 4; ++r) {
            float val = acc[tn][r] * 0.08838834764831845f +
                        (Rs[li0 + r][16 * tn + co] - mn) * inv + 1.f + kp;
            Cu[(long)(m0 + li0 + r) * 1024 + gj] = f2b(val);
        }
    }
}

// ----------------- MFMA weight GEMMs (M=32768, K=128) ----------------------
enum WMode { W2_WOUT, W2_FF1, W2_FF2, W2_LIN };

template <int MODE, int NT>
__global__ __launch_bounds__(256) void wgemm_k(
    const u16* __restrict__ A, const u16* __restrict__ Bw, void* __restrict__ Cv,
    const float* __restrict__ bias, const float* __restrict__ e1)
{
    const int tid = threadIdx.x, wv = tid >> 6, lane = tid & 63;
    const int m0 = blockIdx.x * 64, n0 = blockIdx.y * 64;
    const int co = lane & 15;
    const int q8 = (lane >> 4) << 3;
    const int mrow = m0 + 16 * wv + co;

    f32x4 acc[NT];
#pragma unroll
    for (int tn = 0; tn < NT; ++tn) acc[tn] = 0.f;
    for (int kk = 0; kk < 4; ++kk) {
        const int k0 = kk * 32 + q8;
        const s16x8 a = *reinterpret_cast<const s16x8*>(A + (long)mrow * 128 + k0);
#pragma unroll
        for (int tn = 0; tn < NT; ++tn) {
            const s16x8 b = *reinterpret_cast<const s16x8*>(
                Bw + (long)(n0 + 16 * tn + co) * 128 + k0);
            acc[tn] = __builtin_amdgcn_mfma_f32_16x16x32_bf16(a, b, acc[tn], 0, 0, 0);
        }
    }
    const int li0 = 16 * wv + ((lane >> 4) << 2);
#pragma unroll
    for (int tn = 0; tn < NT; ++tn) {
        int gj = n0 + 16 * tn + co;
#pragma unroll
        for (int r = 0; r < 4; ++r) {
            int gi = m0 + li0 + r;
            long idx = (long)gi * 128 + gj;
            float v = acc[tn][r];
            if (MODE == W2_WOUT) {
                ((float*)Cv)[idx] = v + bias[gj] + e1[idx];
            } else if (MODE == W2_FF1) {
                ((u16*)Cv)[idx] = f2b(fmaxf(v + bias[gj], 0.f));
            } else if (MODE == W2_FF2) {
                ((float*)Cv)[idx] = v + bias[gj] + e1[idx];
            } else if (MODE == W2_LIN) {
                ((float*)Cv)[(long)gi * 16 + gj] = v * e1[gi];
            }
        }
    }
}

// ------------------------------- soft-DTW ----------------------------------
__device__ __forceinline__ float softmin3(float d, float rl, float ru, float rul)
{
    float mn = fminf(rul, fminf(ru, rl));
    float md = fmaxf(fminf(rul, ru), fminf(fmaxf(rul, ru), rl));
    float mx = fmaxf(rul, fmaxf(ru, rl));
    float s = 1.f + __expf((mn - md) * 0.2f) + __expf((mn - mx) * 0.2f);
    return d + mn - 5.0f * __logf(s);
}

template <bool EDGE>
__device__ __forceinline__ void dtw_chunk1(
    u16* __restrict__ R, const float* __restrict__ botp, float* __restrict__ botw,
    float* __restrict__ gb, const float* __restrict__ gwin,
    int W, int lane, bool lane0, int rowbase, int row, int T0, bool useG,
    float& cur, float& upc, float& upp, float& vmin, float& vmax,
    float (&dbuf)[8], float (&bb)[9])
{
    u16* rp = R + (((T0 & 1023) << 10) + row);
    const bool w0 = (W == 0);
    for (int g = 0; g < 4; ++g) {
        const int tg = T0 + (g << 3);
        float dn[8];
#pragma unroll
        for (int s = 0; s < 8; ++s)
            dn[s] = b2f(R[((((tg + 8 + s) & 1023) << 10) + row)]);
        float bn[9];
        if (W > 0 && g < 3) {
            if (useG) {
                if (lane0) {
                    const int base = 8 * (g + 1);
#pragma unroll
                    for (int q = 0; q < 9; ++q) bn[q] = gwin[base + q];
                }
            } else {
                const int jn = tg + 7 - rowbase;
#pragma unroll
                for (int q = 0; q < 9; ++q) bn[q] = botp[(jn + q) & 511];
            }
        }
#pragma unroll
        for (int s = 0; s < 8; ++s) {
            const int t = tg + s;
            const int j = t - row;
            float ru = lane0 ? (w0 ? INF_F : bb[s + 1]) : upc;
            float rul = upp;
            if (EDGE) {
                rul = lane0 ? (w0 ? ((j == 0) ? 0.f : INF_F)
                                  : ((j < 1) ? INF_F : upp))
                            : upp;
            } else {
                rul = (lane0 && w0) ? INF_F : rul;
            }
            float n = softmin3(dbuf[s], cur, ru, rul);
            if (EDGE) {
                bool v = ((unsigned)j < 1024u);
                n = v ? n : INF_F;
                vmin = fminf(vmin, n);
                vmax = v ? fmaxf(vmax, n) : vmax;
                if (v) rp[0] = f2bt(n);
                if (lane == 63 && v) {
                    if (W == 7)
                        __hip_atomic_store(gb + j, n, __ATOMIC_RELAXED,
                                           __HIP_MEMORY_SCOPE_AGENT);
                    else if ((W & 7) != 7) botw[j & 511] = n;
                }
            } else {
                vmin = fminf(vmin, n);
                vmax = fmaxf(vmax, n);
                rp[0] = f2bt(n);
                if (lane == 63) {
                    if (W == 7)
                        __hip_atomic_store(gb + j, n, __ATOMIC_RELAXED,
                                           __HIP_MEMORY_SCOPE_AGENT);
                    else if ((W & 7) != 7) botw[j & 511] = n;
                }
            }
            upp = ru;
            cur = n;
            upc = shup1(n);
            rp += 1024;
        }
#pragma unroll
        for (int s = 0; s < 8; ++s) dbuf[s] = dn[s];
        if (W > 0 && g < 3) {
#pragma unroll
            for (int q = 0; q < 9; ++q) bb[q] = bn[q];
        }
    }
}

// dtw (blocks 0..63: 2 per sample) + QKV backfill (blocks 64..1599)
__global__ __launch_bounds__(512) void dtw_qkv_k(
    u16* __restrict__ Rb, float* __restrict__ minmax,
    float* __restrict__ gbot, unsigned* __restrict__ flags,
    const float* __restrict__ h, const float* __restrict__ w_in,
    const float* __restrict__ b_in, u16* __restrict__ qb, u16* __restrict__ vt)
{
    __shared__ float bot[7][512];
    __shared__ float rmn[512];
    __shared__ float rmx[512];
    __shared__ float gwin[48];
    __shared__ float As[2][16][65];
    __shared__ float Bs[2][16][65];
    __shared__ u16 Tt[2][64][65];

    if (blockIdx.x >= 64) {
        // ---- QKV backfill: two 64x64 tiles per 512-thread block ----
        const int half = threadIdx.x >> 8;
        const int tid = threadIdx.x & 255;
        const int t = ((blockIdx.x - 64) << 1) + half;   // 0..3071
        const int m0 = (t & 511) << 6;
        const int n0 = (t >> 9) << 6;                    // block-uniform
        int tx = tid & 15, ty = tid >> 4;
        float acc[4][4] = {};
        int am = tid >> 2;
        int ak = (tid & 3) << 2;
        for (int kk = 0; kk < 128; kk += 16) {
            {
                const float4 av = *reinterpret_cast<const float4*>(
                    h + (long)(m0 + am) * 128 + kk + ak);
                As[half][ak + 0][am] = av.x;
                As[half][ak + 1][am] = av.y;
                As[half][ak + 2][am] = av.z;
                As[half][ak + 3][am] = av.w;
            }
            {
                const float4 bv = *reinterpret_cast<const float4*>(
                    w_in + (long)(n0 + am) * 128 + kk + ak);
                Bs[half][ak + 0][am] = bv.x;
                Bs[half][ak + 1][am] = bv.y;
                Bs[half][ak + 2][am] = bv.z;
                Bs[half][ak + 3][am] = bv.w;
            }
            __syncthreads();
#pragma unroll
            for (int kc = 0; kc < 16; ++kc) {
                float a0 = As[half][kc][ty * 4 + 0], a1 = As[half][kc][ty * 4 + 1];
                float a2 = As[half][kc][ty * 4 + 2], a3 = As[half][kc][ty * 4 + 3];
                float b0 = Bs[half][kc][tx * 4 + 0], b1 = Bs[half][kc][tx * 4 + 1];
                float b2 = Bs[half][kc][tx * 4 + 2], b3 = Bs[half][kc][tx * 4 + 3];
                acc[0][0] += a0 * b0; acc[0][1] += a0 * b1; acc[0][2] += a0 * b2; acc[0][3] += a0 * b3;
                acc[1][0] += a1 * b0; acc[1][1] += a1 * b1; acc[1][2] += a1 * b2; acc[1][3] += a1 * b3;
                acc[2][0] += a2 * b0; acc[2][1] += a2 * b1; acc[2][2] += a2 * b2; acc[2][3] += a2 * b3;
                acc[3][0] += a3 * b0; acc[3][1] += a3 * b1; acc[3][2] += a3 * b2; acc[3][3] += a3 * b3;
            }
            __syncthreads();
        }
        if (n0 >= 256) {
            // v-tile: write TRANSPOSED into vt [d,1024] via LDS
#pragma unroll
            for (int i = 0; i < 4; ++i)
#pragma unroll
                for (int j = 0; j < 4; ++j)
                    Tt[half][tx * 4 + j][ty * 4 + i] =
                        f2b(acc[i][j] + b_in[n0 + tx * 4 + j]);
            __syncthreads();
            const int z = m0 >> 10;
            const int lbase = m0 & 1023;
            const int dbase = n0 - 256;
            u16* dst = vt + (long)z * 131072L;
#pragma unroll
            for (int i = 0; i < 16; ++i) {
                int idx = tid + 256 * i;
                int dj = idx >> 6, li = idx & 63;
                dst[(long)(dbase + dj) * 1024 + lbase + li] = Tt[half][dj][li];
            }
            return;
        }
        u16* Cu = qb + ((long)(n0 >> 7)) * 4194304L;
        int cb = (n0 & 127) + tx * 4;
#pragma unroll
        for (int i = 0; i < 4; ++i) {
            int gi = m0 + ty * 4 + i;
            ushort4 sv;
            u16* svp = &sv.x;
#pragma unroll
            for (int j = 0; j < 4; ++j)
                svp[j] = f2b(acc[i][j] + b_in[n0 + tx * 4 + j]);
            *reinterpret_cast<ushort4*>(Cu + (long)gi * 128 + cb) = sv;
        }
        return;
    }

    // ------------------------------- dtw ---------------------------------
    const int z = blockIdx.x >> 1;
    const int hb = blockIdx.x & 1;
    u16* R = Rb + (long)z * 1048576L;
    float* gb = gbot + z * 1024;
    unsigned* flag = flags + z * 64;
    const int tid = threadIdx.x;
    const int w = tid >> 6;
    const int lane = tid & 63;
    const bool lane0 = (lane == 0);
    const int W = 8 * hb + w;
    const int rowbase = 64 * W;
    const int row = rowbase + lane;
    const bool useG = (hb == 1 && w == 0);

    float* botw = (w < 7) ? bot[w] : bot[0];
    const float* botp = (w > 0) ? bot[w - 1] : bot[0];

    float cur = INF_F, upc = INF_F, upp = INF_F;
    float vmin = INF_F, vmax = -INF_F;
    float dbuf[8];
    float bb[9];
#pragma unroll
    for (int q = 0; q < 9; ++q) bb[q] = 0.f;

    const int fc = 2 * W;
    for (int e = 0; e < 79; ++e) {
        const int c = e - W;
        const int o = c - fc;
        if (o >= 0 && o <= 33) {
            const int T0 = c << 5;
            if (useG) {
                if (c <= 47) {   // acquire-spin: all lanes load the flag
                    unsigned fv;
                    do {
                        fv = __hip_atomic_load(&flag[c], __ATOMIC_ACQUIRE,
                                               __HIP_MEMORY_SCOPE_AGENT);
                    } while (fv == 0);
                }
                // parallel coherent load of the chunk's gbot window -> LDS
                const int jb = T0 - rowbase - 1;
                if (lane < 48) {
                    int col = min(max(jb + lane, 0), 1023);
                    gwin[lane] = __hip_atomic_load(gb + col, __ATOMIC_RELAXED,
                                                   __HIP_MEMORY_SCOPE_AGENT);
                }
            }
            if (o == 0) {   // prime D queue (8 steps)
#pragma unroll
                for (int s = 0; s < 8; ++s)
                    dbuf[s] = b2f(R[((((T0 + s) & 1023) << 10) + row)]);
            }
            if (W > 0) {    // bot columns for the chunk's first group
                if (useG) {
                    if (lane0) {
#pragma unroll
                        for (int q = 0; q < 9; ++q) bb[q] = gwin[q];
                    }
                } else {
                    const int jb = T0 - rowbase - 1;
#pragma unroll
                    for (int q = 0; q < 9; ++q) bb[q] = botp[(jb + q) & 511];
                }
            }
            if (o < 2 || o >= 32)
                dtw_chunk1<true>(R, botp, botw, gb, gwin, W, lane, lane0,
                                 rowbase, row, T0, useG,
                                 cur, upc, upp, vmin, vmax, dbuf, bb);
            else
                dtw_chunk1<false>(R, botp, botw, gb, gwin, W, lane, lane0,
                                  rowbase, row, T0, useG,
                                  cur, upc, upp, vmin, vmax, dbuf, bb);
        }
        __syncthreads();
        if (hb == 0 && tid == 0) {
            int c7 = e - 7;
            if (c7 >= 14 && c7 <= 47) {
                __threadfence();
                __hip_atomic_store(&flag[c7], 1u, __ATOMIC_RELEASE,
                                   __HIP_MEMORY_SCOPE_AGENT);
            }
        }
    }

    rmn[tid] = vmin;
    rmx[tid] = vmax;
    __syncthreads();
    for (int s2 = 256; s2 > 0; s2 >>= 1) {
        if (tid < s2) {
            rmn[tid] = fminf(rmn[tid], rmn[tid + s2]);
            rmx[tid] = fmaxf(rmx[tid], rmx[tid + s2]);
        }
        __syncthreads();
    }
    if (tid == 0) {
        minmax[z * 4 + hb * 2 + 0] = rmn[0];
        minmax[z * 4 + hb * 2 + 1] = rmx[0];
    }
}

// ---------- softmax row stats + in-place P = exp(s-max), wave/row ----------
__global__ __launch_bounds__(256) void smax_k(u16* __restrict__ S,
                                              float* __restrict__ rsuminv)
{
    long row = (long)blockIdx.x * 4 + (threadIdx.x >> 6);
    int lane = threadIdx.x & 63;
    u16* p = S + row * L_SEQ + lane * 16;
    ushort4 v[4];
#pragma unroll
    for (int q = 0; q < 4; ++q) v[q] = reinterpret_cast<ushort4*>(p)[q];
    float f[16];
#pragma unroll
    for (int q = 0; q < 4; ++q) {
        f[4 * q + 0] = b2f(v[q].x);
        f[4 * q + 1] = b2f(v[q].y);
        f[4 * q + 2] = b2f(v[q].z);
        f[4 * q + 3] = b2f(v[q].w);
    }
    float m = f[0];
#pragma unroll
    for (int i = 1; i < 16; ++i) m = fmaxf(m, f[i]);
#pragma unroll
    for (int d2 = 1; d2 < 64; d2 <<= 1) m = fmaxf(m, __shfl_xor(m, d2));
    float s = 0.f;
#pragma unroll
    for (int i = 0; i < 16; ++i) {
        f[i] = __expf(f[i] - m);
        s += f[i];
    }
#pragma unroll
    for (int q = 0; q < 4; ++q) {
        ushort4 pv;
        pv.x = f2b(f[4 * q + 0]);
        pv.y = f2b(f[4 * q + 1]);
        pv.z = f2b(f[4 * q + 2]);
        pv.w = f2b(f[4 * q + 3]);
        reinterpret_cast<ushort4*>(p)[q] = pv;
    }
#pragma unroll
    for (int d2 = 1; d2 < 64; d2 <<= 1) s += __shfl_xor(s, d2);
    if (lane == 0) rsuminv[row] = 1.f / s;
}

// ------------------ layernorm (wave/row), fp32 + bf16 out ------------------
__global__ __launch_bounds__(256) void ln_k(float* __restrict__ X,
                                            u16* __restrict__ Xb,
                                            const float* __restrict__ g,
                                            const float* __restrict__ b)
{
    long row = (long)blockIdx.x * 4 + (threadIdx.x >> 6);
    int lane = threadIdx.x & 63;
    float2 x = *reinterpret_cast<float2*>(X + row * DM + lane * 2);
    float s = x.x + x.y;
    float q = x.x * x.x + x.y * x.y;
#pragma unroll
    for (int m = 1; m < 64; m <<= 1) {
        s += __shfl_xor(s, m);
        q += __shfl_xor(q, m);
    }
    float mean = s * (1.f / 128.f);
    float var = q * (1.f / 128.f) - mean * mean;
    float rstd = rsqrtf(var + 1e-5f);
    float2 o;
    o.x = (x.x - mean) * rstd * g[lane * 2 + 0] + b[lane * 2 + 0];
    o.y = (x.y - mean) * rstd * g[lane * 2 + 1] + b[lane * 2 + 1];
    *reinterpret_cast<float2*>(X + row * DM + lane * 2) = o;
    ushort2 ob;
    ob.x = f2b(o.x);
    ob.y = f2b(o.y);
    *reinterpret_cast<ushort2*>(Xb + row * DM + lane * 2) = ob;
}

// -------------------------------- lengths ----------------------------------
__global__ __launch_bounds__(256) void len_k(const float* __restrict__ mask,
                                             float* __restrict__ out)
{
    int b = blockIdx.x;
    int t = threadIdx.x;
    const float4 v = reinterpret_cast<const float4*>(mask + b * L_SEQ)[t];
    __shared__ float red[256];
    red[t] = v.x + v.y + v.z + v.w;
    __syncthreads();
    for (int s = 128; s > 0; s >>= 1) {
        if (t < s) red[t] += red[t + s];
        __syncthreads();
    }
    if (t == 0) out[b] = red[0];
}

// ------------------------------- launcher ----------------------------------
extern "C" void kernel_launch(void* const* d_in, const int* in_sizes, int n_in,
                              void* d_out, int out_size, void* d_ws, size_t ws_size,
                              hipStream_t stream)
{
    const float* x      = (const float*)d_in[0];
    const float* mask   = (const float*)d_in[1];
    const float* conv_w = (const float*)d_in[2];
    const float* conv_b = (const float*)d_in[3];
    const float* w_in   = (const float*)d_in[4];
    const float* b_in   = (const float*)d_in[5];
    const float* w_out  = (const float*)d_in[6];
    const float* b_out  = (const float*)d_in[7];
    const float* w_ff1  = (const float*)d_in[8];
    const float* b_ff1  = (const float*)d_in[9];
    const float* w_ff2  = (const float*)d_in[10];
    const float* b_ff2  = (const float*)d_in[11];
    const float* ln1_g  = (const float*)d_in[12];
    const float* ln1_b  = (const float*)d_in[13];
    const float* ln2_g  = (const float*)d_in[14];
    const float* ln2_b  = (const float*)d_in[15];
    const float* w_lin  = (const float*)d_in[16];
    float* out = (float*)d_out;

    float* ws    = (float*)d_ws;
    float* h     = ws;
    u16*   qb    = (u16*)(ws + 4194304L);
    u16*   kb    = qb + 4194304L;
    u16*   t0b   = qb + 8388608L;
    u16*   vt    = qb + 12582912L;
    float* t0    = ws + 16777216L;
    float* t1    = ws + 20971520L;
    u16*   t1b   = (u16*)(ws + 25165824L);    // overlaps hbf (dead after D2)
    u16*   hbf   = (u16*)(ws + 25165824L);
    u16*   t2b   = t1b + 4194304L;            // overlaps gbot/flags/mnmx (dead)
    float* gbot  = ws + 27262976L;
    unsigned* flags = (unsigned*)(ws + 27295744L);
    float* mnmx  = ws + 27297792L;
    float* norms = ws + 29360128L;
    u16*   woutb = (u16*)norms;               // weights after D2 consumed norms
    u16*   wff1b = woutb + 16384;
    u16*   wff2b = woutb + 32768;
    u16*   wlinb = woutb + 49152;
    float* rsum  = ws + 29425664L;
    u16*   Db    = (u16*)(ws + 29458496L);
    u16*   Sb    = (u16*)(ws + 46235712L);

    conv_k<<<dim3(32, 128), 128, 0, stream>>>(x, conv_w, conv_b, mask, h, hbf, norms);
    mgemm_k<G_D2><<<dim3(16, 16, 32), 256, 0, stream>>>(
        hbf, hbf, Db, norms, nullptr);
    wcvt_k<<<200, 256, 0, stream>>>(w_out, w_ff1, w_ff2, w_lin, woutb);
    hipMemsetAsync(flags, 0, 2048 * sizeof(unsigned), stream);
    // dtw (64 blocks, 2/sample) + qkv backfill (1536 blocks, writes qb/kb/vt)
    dtw_qkv_k<<<1600, 512, 0, stream>>>(Db, mnmx, gbot, flags, h, w_in, b_in,
                                        qb, vt);
    sc_k<<<8192, 256, 0, stream>>>(qb, kb, Sb, mnmx, mask, Db);
    smax_k<<<8192, 256, 0, stream>>>(Sb, rsum);
    mgemm_k<G_AV><<<dim3(16, 2, 32), 256, 0, stream>>>(
        Sb, vt, t0b, nullptr, rsum);
    wgemm_k<W2_WOUT, 4><<<dim3(512, 2), 256, 0, stream>>>(
        t0b, woutb, t1, b_out, h);
    ln_k<<<8192, 256, 0, stream>>>(t1, t1b, ln1_g, ln1_b);
    wgemm_k<W2_FF1, 4><<<dim3(512, 2), 256, 0, stream>>>(
        t1b, wff1b, t2b, b_ff1, nullptr);
    wgemm_k<W2_FF2, 4><<<dim3(512, 2), 256, 0, stream>>>(
        t2b, wff2b, t0, b_ff2, t1);
    ln_k<<<8192, 256, 0, stream>>>(t0, t0b, ln2_g, ln2_b);
    wgemm_k<W2_LIN, 1><<<dim3(512, 1), 256, 0, stream>>>(
        t0b, wlinb, out, nullptr, mask);
    len_k<<<32, 256, 0, stream>>>(mask, out + 32768L * 16);
}